// Round 13
// baseline (219.695 us; speedup 1.0000x reference)
//
#include <hip/hip_runtime.h>
#include <math.h>

#define B_ 2
#define L_ 1024
#define K_ 128
#define DM 256
#define DI 512
#define NH 8
#define HD 64
#define CC 514
#define ZCOLS 1034
#define NC 16
#define TC 64

// ---------------------------------------------------------------- utilities
__device__ __forceinline__ float wave_sum(float v) {
    v += __shfl_xor(v, 1);  v += __shfl_xor(v, 2);  v += __shfl_xor(v, 4);
    v += __shfl_xor(v, 8);  v += __shfl_xor(v, 16); v += __shfl_xor(v, 32);
    return v;
}

// sum across each 16-lane DPP row via row_ror — VALU pipe, NOT the DS pipe.
__device__ __forceinline__ float dpp_row_reduce16(float v) {
    int t;
    t = __builtin_amdgcn_update_dpp(0, __float_as_int(v), 0x128, 0xF, 0xF, true); // row_ror:8
    v += __int_as_float(t);
    t = __builtin_amdgcn_update_dpp(0, __float_as_int(v), 0x124, 0xF, 0xF, true); // row_ror:4
    v += __int_as_float(t);
    t = __builtin_amdgcn_update_dpp(0, __float_as_int(v), 0x122, 0xF, 0xF, true); // row_ror:2
    v += __int_as_float(t);
    t = __builtin_amdgcn_update_dpp(0, __float_as_int(v), 0x121, 0xF, 0xF, true); // row_ror:1
    v += __int_as_float(t);
    return v;
}

__device__ __forceinline__ float silu_f(float x) {
    return x / (1.f + expf(-x));
}

// ---------------------------------------------------------------- pipelined NT GEMM (device body)
// C[M][N] = sum over k in [koff, koff+Kt) of A[M][ld] * B[N][ld]; one barrier per
// k-tile: staging writes go to the OTHER LDS buffer, so no pre-write barrier needed.
__device__ void gemm_dev(const float* __restrict__ A, const float* __restrict__ Bm,
                         float* __restrict__ C, int M, int N, int Kt, int ld, int koff,
                         int bm, int bn) {
    __shared__ float As[2][16][68];
    __shared__ float Bs[2][16][68];
    const int tid = threadIdx.x;
    const int sr = tid >> 2;          // stage row 0..63
    const int sk = (tid & 3) * 4;     // stage k 0,4,8,12
    const int tx = tid & 15, ty = tid >> 4;
    const int NT = Kt >> 4;
    const float* Arow = A + (size_t)(bm + sr) * ld + koff + sk;
    const float* Brow = Bm + (size_t)(bn + sr) * ld + koff + sk;
    const bool bok = (bn + sr) < N;

    float4 av = *(const float4*)Arow;
    float4 bv = bok ? *(const float4*)Brow : make_float4(0.f, 0.f, 0.f, 0.f);
    As[0][sk + 0][sr] = av.x; As[0][sk + 1][sr] = av.y;
    As[0][sk + 2][sr] = av.z; As[0][sk + 3][sr] = av.w;
    Bs[0][sk + 0][sr] = bv.x; Bs[0][sk + 1][sr] = bv.y;
    Bs[0][sk + 2][sr] = bv.z; Bs[0][sk + 3][sr] = bv.w;
    __syncthreads();

    float acc[4][4] = {};
    for (int t = 0; t < NT; ++t) {
        if (t + 1 < NT) {             // issue next tile's loads early
            av = *(const float4*)(Arow + (t + 1) * 16);
            bv = bok ? *(const float4*)(Brow + (t + 1) * 16) : make_float4(0.f, 0.f, 0.f, 0.f);
        }
        const int bi = t & 1;
#pragma unroll
        for (int kk = 0; kk < 16; ++kk) {
            float4 a = *(const float4*)&As[bi][kk][ty * 4];
            float4 b = *(const float4*)&Bs[bi][kk][tx * 4];
            acc[0][0] = fmaf(a.x, b.x, acc[0][0]); acc[0][1] = fmaf(a.x, b.y, acc[0][1]);
            acc[0][2] = fmaf(a.x, b.z, acc[0][2]); acc[0][3] = fmaf(a.x, b.w, acc[0][3]);
            acc[1][0] = fmaf(a.y, b.x, acc[1][0]); acc[1][1] = fmaf(a.y, b.y, acc[1][1]);
            acc[1][2] = fmaf(a.y, b.z, acc[1][2]); acc[1][3] = fmaf(a.y, b.w, acc[1][3]);
            acc[2][0] = fmaf(a.z, b.x, acc[2][0]); acc[2][1] = fmaf(a.z, b.y, acc[2][1]);
            acc[2][2] = fmaf(a.z, b.z, acc[2][2]); acc[2][3] = fmaf(a.z, b.w, acc[2][3]);
            acc[3][0] = fmaf(a.w, b.x, acc[3][0]); acc[3][1] = fmaf(a.w, b.y, acc[3][1]);
            acc[3][2] = fmaf(a.w, b.z, acc[3][2]); acc[3][3] = fmaf(a.w, b.w, acc[3][3]);
        }
        if (t + 1 < NT) {             // write OTHER buffer; safe before barrier
            const int ni = (t + 1) & 1;
            As[ni][sk + 0][sr] = av.x; As[ni][sk + 1][sr] = av.y;
            As[ni][sk + 2][sr] = av.z; As[ni][sk + 3][sr] = av.w;
            Bs[ni][sk + 0][sr] = bv.x; Bs[ni][sk + 1][sr] = bv.y;
            Bs[ni][sk + 2][sr] = bv.z; Bs[ni][sk + 3][sr] = bv.w;
        }
        __syncthreads();              // single barrier per tile
    }
    // epilogue: float2 stores (N=1034 rows are only 8B-aligned)
#pragma unroll
    for (int i = 0; i < 4; ++i) {
        int m = bm + ty * 4 + i;
        int n0 = bn + tx * 4;
        if (n0 + 3 < N) {
            float* cp = &C[(size_t)m * N + n0];
            *(float2*)cp = make_float2(acc[i][0], acc[i][1]);
            *(float2*)(cp + 2) = make_float2(acc[i][2], acc[i][3]);
        } else {
#pragma unroll
            for (int j = 0; j < 4; ++j)
                if (n0 + j < N) C[(size_t)m * N + n0 + j] = acc[i][j];
        }
    }
}

// ---------------------------------------------------------------- front: K-split zx GEMM + h0 GEMM
// blocks 0..1087: zx halves — base=bid>>1 (tile), half=bid&1 (K 0..127 / 128..255)
// blocks 1088..1119: h0 = in_query @ Wq^T (256x512x256)
__global__ __launch_bounds__(256) void front_k(
    const float* __restrict__ in_key, const float* __restrict__ Wkey,
    float* __restrict__ zxA, float* __restrict__ zxB,
    const float* __restrict__ in_query, const float* __restrict__ Wq,
    float* __restrict__ h0b) {
    int bid = blockIdx.x;
    if (bid < 1088) {
        int base = bid >> 1, half = bid & 1;
        float* outp = half ? zxB : zxA;
        gemm_dev(in_key, Wkey, outp, 2048, ZCOLS, 128, 256, half * 128,
                 (base & 31) * 64, (base >> 5) * 64);
    } else {
        int r = bid - 1088;
        gemm_dev(in_query, Wq, h0b, 256, 512, 256, 256, 0,
                 (r & 3) * 64, (r >> 2) * 64);
    }
}

// ---------------------------------------------------------------- setup: corners (blocks 0-7) + cpb table (blocks 8-11)
__global__ __launch_bounds__(256) void setup_k(
    const float* __restrict__ qxyz, const float* __restrict__ qsize,
    const float* __restrict__ qang, const float* __restrict__ w1,
    const float* __restrict__ b1, const float* __restrict__ w2,
    float* __restrict__ cb, float* __restrict__ tbl) {
    int bid = blockIdx.x, tid = threadIdx.x;
    if (bid < 8) {
        int idx = bid * 256 + tid;            // < 2048 = B_*K_*8
        int b = idx >> 10;
        int q = idx & 1023;
        int k = q >> 3;
        int c = q & 7;
        const float sx[8] = {1, 1, -1, -1, 1, 1, -1, -1};
        const float sy[8] = {1, 1, 1, 1, -1, -1, -1, -1};
        const float sz[8] = {1, -1, -1, 1, 1, -1, -1, 1};
        float cx = qxyz[(b * K_ + k) * 3 + 0];
        float cy = qxyz[(b * K_ + k) * 3 + 1];
        float cz = qxyz[(b * K_ + k) * 3 + 2];
        float lv = qsize[(b * K_ + k) * 3 + 0];
        float wv = qsize[(b * K_ + k) * 3 + 1];
        float hv = qsize[(b * K_ + k) * 3 + 2];
        float ang = qang[b * K_ + k];
        float ca = cosf(ang), sa = sinf(ang);
        float ccx = cx, ccy = -cz, ccz = cy;
        float l0 = lv * sx[c] * 0.5f;
        float l1 = hv * sy[c] * 0.5f;
        float l2 = wv * sz[c] * 0.5f;
        float m0 = ca * l0 + sa * l2 + ccx;
        float m1 = l1 + ccy;
        float m2 = -sa * l0 + ca * l2 + ccz;
        // rotation for the distance transform uses angle[b, q % K] (jnp.tile semantics)
        float angr = qang[b * K_ + (q & (K_ - 1))];
        float4* o = (float4*)(cb + (size_t)idx * 8);
        o[0] = make_float4(m0, m2, -m1, cosf(angr));
        o[1] = make_float4(sinf(angr), 0.f, 0.f, 0.f);
    } else {
        int p = (bid - 8) * 256 + tid;
        if (p >= 1000) return;
        int i = p / 100, j = (p / 10) % 10, k = p % 10;
        float c0 = (8.f / 9.f) * i - 4.f;
        float c1 = (8.f / 9.f) * j - 4.f;
        float c2 = (8.f / 9.f) * k - 4.f;
        float a0 = 0.f, a1 = 0.f, a2 = 0.f, a3 = 0.f;
        for (int m = 0; m < 128; ++m) {
            float t = fmaf(c0, w1[m * 3 + 0], fmaf(c1, w1[m * 3 + 1], fmaf(c2, w1[m * 3 + 2], b1[m])));
            t = fmaxf(t, 0.f);
            a0 = fmaf(t, w2[m], a0);
            a1 = fmaf(t, w2[128 + m], a1);
            a2 = fmaf(t, w2[256 + m], a2);
            a3 = fmaf(t, w2[384 + m], a3);
        }
        tbl[p * 4 + 0] = a0; tbl[p * 4 + 1] = a1;
        tbl[p * 4 + 2] = a2; tbl[p * 4 + 3] = a3;
    }
}

// ---------------------------------------------------------------- depthwise conv7 + silu (sum of two input halves)
__global__ void dwconv_silu2(const float* __restrict__ xa, const float* __restrict__ xbp,
                             const float* __restrict__ w, const float* __restrict__ bias,
                             float* __restrict__ out) {
    int c = blockIdx.y * blockDim.x + threadIdx.x;
    if (c >= CC) return;
    int row = blockIdx.x;                 // b*L + l
    int l = row & (L_ - 1);
    const float* ra = xa + (size_t)row * ZCOLS + 512 + c;
    const float* rb = xbp + (size_t)row * ZCOLS + 512 + c;
    float acc = bias[c];
#pragma unroll
    for (int j = 0; j < 7; ++j) {
        int ll = l + j - 3;
        if (ll >= 0 && ll < L_) {
            ptrdiff_t o = (ptrdiff_t)(j - 3) * ZCOLS;
            acc = fmaf(ra[o] + rb[o], w[c * 7 + j], acc);
        }
    }
    out[(size_t)row * CC + c] = silu_f(acc);
}

// ---------------------------------------------------------------- depthwise conv7 + silu (single input)
__global__ void dwconv_silu(const float* __restrict__ xin, int in_stride, int in_off,
                            const float* __restrict__ w, const float* __restrict__ bias,
                            float* __restrict__ out) {
    int c = blockIdx.y * blockDim.x + threadIdx.x;
    if (c >= CC) return;
    int row = blockIdx.x;                 // b*L + l
    int l = row & (L_ - 1);
    const float* xr = xin + (size_t)row * in_stride + in_off + c;
    float acc = bias[c];
#pragma unroll
    for (int j = 0; j < 7; ++j) {
        int ll = l + j - 3;
        if (ll >= 0 && ll < L_) acc = fmaf(xr[(ptrdiff_t)(j - 3) * in_stride], w[c * 7 + j], acc);
    }
    out[(size_t)row * CC + c] = silu_f(acc);
}

// ---------------------------------------------------------------- fused dist + dA/dB/C
__global__ __launch_bounds__(128) void geo_k(
    const float* __restrict__ kxyz, const float* __restrict__ cb,
    const float* __restrict__ tbl, const float* __restrict__ zxA,
    const float* __restrict__ zxB,
    const float* __restrict__ xf, const float* __restrict__ xb,
    const float* __restrict__ wbc, const float* __restrict__ wdt,
    const float* __restrict__ dtb, const float* __restrict__ alog,
    float* __restrict__ dA, float* __restrict__ dBf, float* __restrict__ dBb,
    float* __restrict__ Cf, float* __restrict__ Cb) {
    __shared__ float t_s[4000];
    int row = blockIdx.x;                 // b*L + l
    int b = row >> 10;
    int l = row & 1023;
    int k = threadIdx.x;
    for (int i = threadIdx.x; i < 4000; i += 128) t_s[i] = tbl[i];
    __syncthreads();
    float kx = kxyz[(size_t)row * 3 + 0];
    float ky = kxyz[(size_t)row * 3 + 1];
    float kz = kxyz[(size_t)row * 3 + 2];
    float acc0 = 0.f, acc1 = 0.f, acc2 = 0.f, acc3 = 0.f;
#pragma unroll
    for (int c = 0; c < 8; ++c) {
        int q = k * 8 + c;
        const float4* p = (const float4*)(cb + (size_t)(b * 1024 + q) * 8);
        float4 v0 = p[0], v1 = p[1];
        float d0 = v0.x - kx, d1 = v0.y - ky, d2 = v0.z - kz;
        float rc = v0.w, rs = v1.x;
        float e0 = d0, e1 = -d2, e2 = d1;
        float f0 = rc * e0 - rs * e2;
        float f1 = e1;
        float f2 = rs * e0 + rc * e2;
        float g0 = f0, g1 = f2, g2 = -f1;
        g0 = copysignf(log2f(fabsf(g0) * 512.f + 1.f) * (1.f / 12.f), g0);
        g1 = copysignf(log2f(fabsf(g1) * 512.f + 1.f) * (1.f / 12.f), g1);
        g2 = copysignf(log2f(fabsf(g2) * 512.f + 1.f) * (1.f / 12.f), g2);
        // table axis0 <- g2, axis1 <- g1, axis2 <- g0
        float iq = 5.f * g2 + 4.5f;
        float jq = 5.f * g1 + 4.5f;
        float kq = 5.f * g0 + 4.5f;
        float i0f = floorf(iq), j0f = floorf(jq), k0f = floorf(kq);
        float wi = iq - i0f, wj = jq - j0f, wk = kq - k0f;
        int i0 = (int)i0f, j0 = (int)j0f, k0 = (int)k0f;
#pragma unroll
        for (int a = 0; a < 2; ++a) {
#pragma unroll
            for (int bb = 0; bb < 2; ++bb) {
#pragma unroll
                for (int cc = 0; cc < 2; ++cc) {
                    int ii = i0 + a, jj = j0 + bb, kk = k0 + cc;
                    if ((unsigned)ii < 10u && (unsigned)jj < 10u && (unsigned)kk < 10u) {
                        float wgt = (a ? wi : 1.f - wi) * (bb ? wj : 1.f - wj) * (cc ? wk : 1.f - wk);
                        const float* tp = &t_s[((ii * 10 + jj) * 10 + kk) * 4];
                        acc0 = fmaf(wgt, tp[0], acc0);
                        acc1 = fmaf(wgt, tp[1], acc1);
                        acc2 = fmaf(wgt, tp[2], acc2);
                        acc3 = fmaf(wgt, tp[3], acc3);
                    }
                }
            }
        }
    }
    // ---- fused precomp tail
    float B0 = acc0 * wbc[0] + acc1 * wbc[1] + acc2 * wbc[2] + acc3 * wbc[3];
    float C0 = acc0 * wbc[4] + acc1 * wbc[5] + acc2 * wbc[6] + acc3 * wbc[7];
    float bbf = xf[(size_t)row * CC + 512], cbf = xf[(size_t)row * CC + 513];
    float bbb = xb[(size_t)row * CC + 512], cbb = xb[(size_t)row * CC + 513];
    Cf[(size_t)row * K_ + k] = C0 + cbf;
    Cb[(size_t)row * K_ + k] = C0 + cbb;
    float Bf = B0 + bbf, Bb = B0 + bbb;
#pragma unroll
    for (int hh = 0; hh < NH; ++hh) {
        float s = acc0 * wdt[hh * 4 + 0] + acc1 * wdt[hh * 4 + 1] +
                  acc2 * wdt[hh * 4 + 2] + acc3 * wdt[hh * 4 + 3];
        s += zxA[(size_t)row * ZCOLS + 1026 + hh] + zxB[(size_t)row * ZCOLS + 1026 + hh] + dtb[hh];
        float dtv = (s > 20.f) ? s : log1pf(expf(s));
        float Av = -expf(alog[hh]);
        size_t o = ((size_t)(b * NH + hh) * L_ + l) * K_ + k;
        dA[o] = expf(dtv * Av);
        dBf[o] = dtv * Bf;
        dBb[o] = dtv * Bb;
    }
}

// ---------------------------------------------------------------- chunked ISSM scan, LDS-fed
// block = 256 thr (4 waves) = one (dir,b,hh,chunk); lane owns 8 k x 4 d (d = dloc+{0,16,32,48}).
// dir==0 blocks also carry the chunk cumprod P. One barrier per 8-step tile.
__global__ __launch_bounds__(256) void scan_part6(
    const float* __restrict__ dA, const float* __restrict__ dBf, const float* __restrict__ dBb,
    const float* __restrict__ Cf, const float* __restrict__ Cb,
    const float* __restrict__ xf, const float* __restrict__ xb,
    float* __restrict__ Sbuf, float* __restrict__ Pbuf,
    float* __restrict__ yf, float* __restrict__ yb) {
    __shared__ float lds[2][3584];
    int bid = blockIdx.x;
    int c = bid & 15;
    int hh = (bid >> 4) & 7;
    int b = (bid >> 7) & 1;
    int dir = bid >> 8;
    int tid = threadIdx.x;             // 0..255
    int lane = tid & 63;
    int w = tid >> 6;                  // 0..3
    int dg = lane >> 4, kg = lane & 15;
    int dloc = w * 4 + dg;             // 0..15; lane owns d = dloc + 16*{0,1,2,3}
    int klo = kg * 4, khi = 64 + kg * 4;

    const float* Bsrc = dir ? dBb : dBf;
    const float* Csrc = dir ? Cb : Cf;
    const float* Xsrc = dir ? xb : xf;
    float* Ydst = dir ? yb : yf;
    int t0 = dir ? (L_ - 1 - c * TC) : c * TC;
    int stp = dir ? -1 : 1;

    const float* Abase = dA + ((size_t)(b * NH + hh) * L_) * K_;
    const float* Bbase = Bsrc + ((size_t)(b * NH + hh) * L_) * K_;
    const float* Cbase = Csrc + ((size_t)b * L_) * K_;
    const float* Xbase = Xsrc + ((size_t)b * L_) * CC + hh * HD;

    const bool hasx = (tid < 128);

    auto gaddr = [&](int v, int tb) -> const float* {
        if (v < 768) {
            int r = (v >> 5) & 7;
            int c4 = v & 31;
            int l = t0 + stp * (tb + r);
            const float* base = (v < 256) ? Abase : ((v < 512) ? Bbase : Cbase);
            return base + (size_t)l * K_ + c4 * 4;
        } else {
            int vv = v - 768;
            int r = vv >> 4, c4 = vv & 15;
            int l = t0 + stp * (tb + r);
            return Xbase + (size_t)l * CC + c4 * 4;
        }
    };

    float hA[8] = {0, 0, 0, 0, 0, 0, 0, 0};
    float hB[8] = {0, 0, 0, 0, 0, 0, 0, 0};
    float hC[8] = {0, 0, 0, 0, 0, 0, 0, 0};
    float hD[8] = {0, 0, 0, 0, 0, 0, 0, 0};
    float cum[8] = {1, 1, 1, 1, 1, 1, 1, 1};

    // prologue: stage tile 0 into buf 0
    float4 rA = *(const float4*)gaddr(tid, 0);
    float4 rB = *(const float4*)gaddr(256 + tid, 0);
    float4 rC = *(const float4*)gaddr(512 + tid, 0);
    float4 rX = hasx ? *(const float4*)gaddr(768 + tid, 0) : make_float4(0, 0, 0, 0);
    *(float4*)&lds[0][4 * tid] = rA;
    *(float4*)&lds[0][1024 + 4 * tid] = rB;
    *(float4*)&lds[0][2048 + 4 * tid] = rC;
    if (hasx) *(float4*)&lds[0][3072 + 4 * tid] = rX;
    __syncthreads();

    float* pY = Ydst + ((size_t)(b * L_ + t0)) * DI + hh * HD + dloc;
    const ptrdiff_t dY = (ptrdiff_t)stp * DI;

    for (int it = 0; it < TC / 8; ++it) {
        int tb = it * 8;
        if (it < TC / 8 - 1) {           // issue next tile's global loads early
            rA = *(const float4*)gaddr(tid, tb + 8);
            rB = *(const float4*)gaddr(256 + tid, tb + 8);
            rC = *(const float4*)gaddr(512 + tid, tb + 8);
            if (hasx) rX = *(const float4*)gaddr(768 + tid, tb + 8);
        }
        const float* Lb = lds[it & 1];
        // preload step 0
        float4 a0 = *(const float4*)&Lb[klo];
        float4 a1 = *(const float4*)&Lb[khi];
        float4 b0 = *(const float4*)&Lb[1024 + klo];
        float4 b1 = *(const float4*)&Lb[1024 + khi];
        float4 c0 = *(const float4*)&Lb[2048 + klo];
        float4 c1 = *(const float4*)&Lb[2048 + khi];
        float x0 = Lb[3072 + dloc];
        float x1 = Lb[3072 + 16 + dloc];
        float x2 = Lb[3072 + 32 + dloc];
        float x3 = Lb[3072 + 48 + dloc];
#pragma unroll
        for (int st = 0; st < 8; ++st) {
            float4 na0, na1, nb0, nb1, nc0, nc1;
            float nx0 = 0.f, nx1 = 0.f, nx2 = 0.f, nx3 = 0.f;
            if (st < 7) {                // issue step st+1's LDS reads before computing st
                int o = (st + 1) * 128;
                na0 = *(const float4*)&Lb[o + klo];
                na1 = *(const float4*)&Lb[o + khi];
                nb0 = *(const float4*)&Lb[1024 + o + klo];
                nb1 = *(const float4*)&Lb[1024 + o + khi];
                nc0 = *(const float4*)&Lb[2048 + o + klo];
                nc1 = *(const float4*)&Lb[2048 + o + khi];
                int xo = 3072 + (st + 1) * 64 + dloc;
                nx0 = Lb[xo]; nx1 = Lb[xo + 16]; nx2 = Lb[xo + 32]; nx3 = Lb[xo + 48];
            }
            cum[0] *= a0.x; cum[1] *= a0.y; cum[2] *= a0.z; cum[3] *= a0.w;
            cum[4] *= a1.x; cum[5] *= a1.y; cum[6] *= a1.z; cum[7] *= a1.w;
            float u0, u1, u2, u3;
            // d-block A (x0)
            hA[0] = fmaf(hA[0], a0.x, x0 * b0.x); u0 = hA[0] * c0.x;
            hA[1] = fmaf(hA[1], a0.y, x0 * b0.y); u1 = hA[1] * c0.y;
            hA[2] = fmaf(hA[2], a0.z, x0 * b0.z); u2 = hA[2] * c0.z;
            hA[3] = fmaf(hA[3], a0.w, x0 * b0.w); u3 = hA[3] * c0.w;
            hA[4] = fmaf(hA[4], a1.x, x0 * b1.x); u0 = fmaf(hA[4], c1.x, u0);
            hA[5] = fmaf(hA[5], a1.y, x0 * b1.y); u1 = fmaf(hA[5], c1.y, u1);
            hA[6] = fmaf(hA[6], a1.z, x0 * b1.z); u2 = fmaf(hA[6], c1.z, u2);
            hA[7] = fmaf(hA[7], a1.w, x0 * b1.w); u3 = fmaf(hA[7], c1.w, u3);
            float rrA = dpp_row_reduce16((u0 + u1) + (u2 + u3));
            // d-block B (x1)
            hB[0] = fmaf(hB[0], a0.x, x1 * b0.x); u0 = hB[0] * c0.x;
            hB[1] = fmaf(hB[1], a0.y, x1 * b0.y); u1 = hB[1] * c0.y;
            hB[2] = fmaf(hB[2], a0.z, x1 * b0.z); u2 = hB[2] * c0.z;
            hB[3] = fmaf(hB[3], a0.w, x1 * b0.w); u3 = hB[3] * c0.w;
            hB[4] = fmaf(hB[4], a1.x, x1 * b1.x); u0 = fmaf(hB[4], c1.x, u0);
            hB[5] = fmaf(hB[5], a1.y, x1 * b1.y); u1 = fmaf(hB[5], c1.y, u1);
            hB[6] = fmaf(hB[6], a1.z, x1 * b1.z); u2 = fmaf(hB[6], c1.z, u2);
            hB[7] = fmaf(hB[7], a1.w, x1 * b1.w); u3 = fmaf(hB[7], c1.w, u3);
            float rrB = dpp_row_reduce16((u0 + u1) + (u2 + u3));
            // d-block C (x2)
            hC[0] = fmaf(hC[0], a0.x, x2 * b0.x); u0 = hC[0] * c0.x;
            hC[1] = fmaf(hC[1], a0.y, x2 * b0.y); u1 = hC[1] * c0.y;
            hC[2] = fmaf(hC[2], a0.z, x2 * b0.z); u2 = hC[2] * c0.z;
            hC[3] = fmaf(hC[3], a0.w, x2 * b0.w); u3 = hC[3] * c0.w;
            hC[4] = fmaf(hC[4], a1.x, x2 * b1.x); u0 = fmaf(hC[4], c1.x, u0);
            hC[5] = fmaf(hC[5], a1.y, x2 * b1.y); u1 = fmaf(hC[5], c1.y, u1);
            hC[6] = fmaf(hC[6], a1.z, x2 * b1.z); u2 = fmaf(hC[6], c1.z, u2);
            hC[7] = fmaf(hC[7], a1.w, x2 * b1.w); u3 = fmaf(hC[7], c1.w, u3);
            float rrC = dpp_row_reduce16((u0 + u1) + (u2 + u3));
            // d-block D (x3)
            hD[0] = fmaf(hD[0], a0.x, x3 * b0.x); u0 = hD[0] * c0.x;
            hD[1] = fmaf(hD[1], a0.y, x3 * b0.y); u1 = hD[1] * c0.y;
            hD[2] = fmaf(hD[2], a0.z, x3 * b0.z); u2 = hD[2] * c0.z;
            hD[3] = fmaf(hD[3], a0.w, x3 * b0.w); u3 = hD[3] * c0.w;
            hD[4] = fmaf(hD[4], a1.x, x3 * b1.x); u0 = fmaf(hD[4], c1.x, u0);
            hD[5] = fmaf(hD[5], a1.y, x3 * b1.y); u1 = fmaf(hD[5], c1.y, u1);
            hD[6] = fmaf(hD[6], a1.z, x3 * b1.z); u2 = fmaf(hD[6], c1.z, u2);
            hD[7] = fmaf(hD[7], a1.w, x3 * b1.w); u3 = fmaf(hD[7], c1.w, u3);
            float rrD = dpp_row_reduce16((u0 + u1) + (u2 + u3));
            if (kg == 0) { pY[0] = rrA; pY[16] = rrB; pY[32] = rrC; pY[48] = rrD; }
            pY += dY;
            if (st < 7) {
                a0 = na0; a1 = na1; b0 = nb0; b1 = nb1; c0 = nc0; c1 = nc1;
                x0 = nx0; x1 = nx1; x2 = nx2; x3 = nx3;
            }
        }
        if (it < TC / 8 - 1) {           // write OTHER buffer; safe before barrier
            *(float4*)&lds[(it + 1) & 1][4 * tid] = rA;
            *(float4*)&lds[(it + 1) & 1][1024 + 4 * tid] = rB;
            *(float4*)&lds[(it + 1) & 1][2048 + 4 * tid] = rC;
            if (hasx) *(float4*)&lds[(it + 1) & 1][3072 + 4 * tid] = rX;
        }
        __syncthreads();                 // single barrier per tile
    }

    int ibh = (dir * B_ + b) * NH + hh;
    {
        float* Sp = Sbuf + (((size_t)ibh * NC + c) * HD + dloc) * K_;
        *(float4*)(Sp + klo) = make_float4(hA[0], hA[1], hA[2], hA[3]);
        *(float4*)(Sp + khi) = make_float4(hA[4], hA[5], hA[6], hA[7]);
        Sp += (size_t)16 * K_;
        *(float4*)(Sp + klo) = make_float4(hB[0], hB[1], hB[2], hB[3]);
        *(float4*)(Sp + khi) = make_float4(hB[4], hB[5], hB[6], hB[7]);
        Sp += (size_t)16 * K_;
        *(float4*)(Sp + klo) = make_float4(hC[0], hC[1], hC[2], hC[3]);
        *(float4*)(Sp + khi) = make_float4(hC[4], hC[5], hC[6], hC[7]);
        Sp += (size_t)16 * K_;
        *(float4*)(Sp + klo) = make_float4(hD[0], hD[1], hD[2], hD[3]);
        *(float4*)(Sp + khi) = make_float4(hD[4], hD[5], hD[6], hD[7]);
    }
    if (dir == 0 && tid < 16) {          // w==0, dg==0, kg==tid: cum identical across d
        float* Pp = Pbuf + ((size_t)((b * NH + hh) * NC + c)) * K_;
        *(float4*)(Pp + klo) = make_float4(cum[0], cum[1], cum[2], cum[3]);
        *(float4*)(Pp + khi) = make_float4(cum[4], cum[5], cum[6], cum[7]);
    }
}

// phase 2: sequential combine across NC chunks; overwrites Sbuf with incoming state Hin;
// writes final state hfin. grid = 128 x 256: bid = ((dir*2+b)*8+hh)*4 + dq; wave w: dsl=dq*4+w
__global__ __launch_bounds__(256) void scan_combine(
    const float* __restrict__ h0buf, float* __restrict__ Sbuf,
    const float* __restrict__ Pbuf, float* __restrict__ hfin) {
    int bid = blockIdx.x;
    int dq = bid & 3;
    int hh = (bid >> 2) & 7;
    int b = (bid >> 5) & 1;
    int dir = bid >> 6;
    int tid = threadIdx.x;
    int w = tid >> 6;
    int lane = tid & 63;
    int dsl = dq * 4 + w;
    int dg = lane >> 4, kg = lane & 15;
    int d = dsl * 4 + dg;
    int k0 = kg * 8;

    float H[8];
#pragma unroll
    for (int j = 0; j < 8; ++j)
        H[j] = h0buf[(size_t)(b * K_ + k0 + j) * DI + hh * HD + d];

    int ibh = (dir * B_ + b) * NH + hh;
    for (int c = 0; c < NC; ++c) {
        float* Sp = Sbuf + (((size_t)ibh * NC + c) * HD + d) * K_ + k0;
        int cF = dir ? (NC - 1 - c) : c;   // P computed on fwd chunk row-sets
        const float* Pp = Pbuf + ((size_t)((b * NH + hh) * NC + cF)) * K_ + k0;
        float4 sA = *(const float4*)(Sp + 0);
        float4 sB = *(const float4*)(Sp + 4);
        float4 pA = *(const float4*)(Pp + 0);
        float4 pB = *(const float4*)(Pp + 4);
        // store incoming state for this chunk (overwrites S)
        *(float4*)(Sp + 0) = make_float4(H[0], H[1], H[2], H[3]);
        *(float4*)(Sp + 4) = make_float4(H[4], H[5], H[6], H[7]);
        H[0] = fmaf(H[0], pA.x, sA.x); H[1] = fmaf(H[1], pA.y, sA.y);
        H[2] = fmaf(H[2], pA.z, sA.z); H[3] = fmaf(H[3], pA.w, sA.w);
        H[4] = fmaf(H[4], pB.x, sB.x); H[5] = fmaf(H[5], pB.y, sB.y);
        H[6] = fmaf(H[6], pB.z, sB.z); H[7] = fmaf(H[7], pB.w, sB.w);
    }
    float* hf = hfin + ((((size_t)dir * B_ + b) * NH + hh) * HD + d) * K_ + k0;
    *(float4*)(hf + 0) = make_float4(H[0], H[1], H[2], H[3]);
    *(float4*)(hf + 4) = make_float4(H[4], H[5], H[6], H[7]);
}

// phase 3: y[t,d] += sum_k C[t,k]*cumA[t,k] * Hin[k,d]  (64x64x128 GEMM per instance)
// grid = 512 x 256: iid = ((dir*2+b)*8+hh)*16 + c
#define CP 72
#define WSWZ(k) ((((k) >> 3) & 3) << 2)
__global__ __launch_bounds__(256) void scan_corr(
    const float* __restrict__ dA, const float* __restrict__ Cf, const float* __restrict__ Cb,
    const float* __restrict__ Sbuf, float* __restrict__ yf, float* __restrict__ yb) {
    __shared__ float Wl[128][CP];   // [k][t] (t XOR-swizzled by WSWZ(k))
    __shared__ float Hl[128][CP];   // [k][d]
    int iid = blockIdx.x;
    int c = iid & 15;
    int hh = (iid >> 4) & 7;
    int b = (iid >> 7) & 1;
    int dir = iid >> 8;
    int tid = threadIdx.x;
    const float* Csrc = dir ? Cb : Cf;

    // phase A: W[k][t] = C[l(t),k] * cumA(t,k), scan order
    if (tid < 128) {
        int k = tid;
        float cum = 1.f;
        const float* pA = dA + ((size_t)(b * NH + hh) * L_) * K_ + k;
        const float* pC = Csrc + ((size_t)b * L_) * K_ + k;
        int sw = WSWZ(k);
#pragma unroll 4
        for (int t = 0; t < TC; ++t) {
            int l = dir ? (L_ - 1 - (c * TC + t)) : (c * TC + t);
            cum *= pA[(size_t)l * K_];
            Wl[k][t ^ sw] = cum * pC[(size_t)l * K_];
        }
    }
    // phase B: Hin [k][d] (transposed stage from Sbuf [d][k])
    {
        int d = tid & 63, kq = tid >> 6;   // kq 0..3
        int ibh = (dir * B_ + b) * NH + hh;
        const float* Hp = Sbuf + (((size_t)ibh * NC + c) * HD + d) * K_;
#pragma unroll
        for (int i = 0; i < 8; ++i) {
            int q = kq * 8 + i;            // float4 index 0..31
            float4 v = *(const float4*)(Hp + q * 4);
            Hl[q * 4 + 0][d] = v.x; Hl[q * 4 + 1][d] = v.y;
            Hl[q * 4 + 2][d] = v.z; Hl[q * 4 + 3][d] = v.w;
        }
    }
    __syncthreads();
    // phase C: GEMM 64t x 64d x 128k
    int a = tid >> 4;            // t-quad 0..15
    int bc = tid & 15;           // d-quad 0..15
    int t0v = a * 4, d0v = bc * 4;
    float acc[4][4] = {};
    for (int k = 0; k < 128; ++k) {
        float4 w4 = *(const float4*)&Wl[k][t0v ^ WSWZ(k)];
        float4 h4 = *(const float4*)&Hl[k][d0v];
        acc[0][0] = fmaf(w4.x, h4.x, acc[0][0]); acc[0][1] = fmaf(w4.x, h4.y, acc[0][1]);
        acc[0][2] = fmaf(w4.x, h4.z, acc[0][2]); acc[0][3] = fmaf(w4.x, h4.w, acc[0][3]);
        acc[1][0] = fmaf(w4.y, h4.x, acc[1][0]); acc[1][1] = fmaf(w4.y, h4.y, acc[1][1]);
        acc[1][2] = fmaf(w4.y, h4.z, acc[1][2]); acc[1][3] = fmaf(w4.y, h4.w, acc[1][3]);
        acc[2][0] = fmaf(w4.z, h4.x, acc[2][0]); acc[2][1] = fmaf(w4.z, h4.y, acc[2][1]);
        acc[2][2] = fmaf(w4.z, h4.z, acc[2][2]); acc[2][3] = fmaf(w4.z, h4.w, acc[2][3]);
        acc[3][0] = fmaf(w4.w, h4.x, acc[3][0]); acc[3][1] = fmaf(w4.w, h4.y, acc[3][1]);
        acc[3][2] = fmaf(w4.w, h4.z, acc[3][2]); acc[3][3] = fmaf(w4.w, h4.w, acc[3][3]);
    }
    float* Ydst = dir ? yb : yf;
#pragma unroll
    for (int i = 0; i < 4; ++i) {
        int t = t0v + i;
        int l = dir ? (L_ - 1 - (c * TC + t)) : (c * TC + t);
        float* yp = Ydst + ((size_t)(b * L_ + l)) * DI + hh * HD + d0v;
        float4 old = *(float4*)yp;
        old.x += acc[i][0]; old.y += acc[i][1];
        old.z += acc[i][2]; old.w += acc[i][3];
        *(float4*)yp = old;
    }
}

// ---------------------------------------------------------------- gate + RMSNorm
__global__ __launch_bounds__(256) void gated_k(
    const float* __restrict__ yf, const float* __restrict__ yb,
    const float* __restrict__ xf, const float* __restrict__ zxA,
    const float* __restrict__ zxB,
    const float* __restrict__ Dp, const float* __restrict__ knw,
    float* __restrict__ gated) {
    __shared__ float sb[4];
    int row = blockIdx.x;
    int tid = threadIdx.x;
    float g[2];
    float ss = 0.f;
#pragma unroll
    for (int u = 0; u < 2; ++u) {
        int c = tid + u * 256;
        float yv = yf[(size_t)row * DI + c] + yb[(size_t)row * DI + c] +
                   Dp[c >> 6] * xf[(size_t)row * CC + c];
        float z = zxA[(size_t)row * ZCOLS + c] + zxB[(size_t)row * ZCOLS + c];
        float gv = yv * silu_f(z);
        g[u] = gv;
        ss = fmaf(gv, gv, ss);
    }
    float wsum = wave_sum(ss);
    if ((tid & 63) == 0) sb[tid >> 6] = wsum;
    __syncthreads();
    float tot = sb[0] + sb[1] + sb[2] + sb[3];
    float rms = rsqrtf(tot * (1.f / 512.f) + 1e-5f);
#pragma unroll
    for (int u = 0; u < 2; ++u) {
        int c = tid + u * 256;
        gated[(size_t)row * DI + c] = g[u] * rms * knw[c];
    }
}

// ---------------------------------------------------------------- final: out GEMM + query path
// blocks 0..127: out = gated @ Wok^T (2048x256x512)
// blocks 128..383: query LN + GEMM (bk = bid-128)
__global__ __launch_bounds__(256) void final_k(
    const float* __restrict__ gated, const float* __restrict__ Wok, float* __restrict__ out,
    const float* __restrict__ hfin, const float* __restrict__ lnw,
    const float* __restrict__ lnb, const float* __restrict__ woq,
    float* __restrict__ outq) {
    int bid = blockIdx.x, tid = threadIdx.x;
    if (bid < 128) {
        gemm_dev(gated, Wok, out, 2048, 256, 512, 512, 0, (bid & 31) * 64, (bid >> 5) * 64);
        return;
    }
    __shared__ float sln[512];
    __shared__ float sb1[4];
    __shared__ float sb2[4];
    int bk = bid - 128;                   // b*K_ + k
    int b = bk >> 7;
    int k = bk & 127;
    float st[2];
    float ssum = 0.f;
#pragma unroll
    for (int u = 0; u < 2; ++u) {
        int c = tid + u * 256;
        int hh = c >> 6, d = c & 63;
        size_t o0 = (((size_t)(0 * B_ + b) * NH + hh) * HD + d) * K_ + k;
        size_t o1 = (((size_t)(1 * B_ + b) * NH + hh) * HD + d) * K_ + k;
        st[u] = 0.5f * (hfin[o0] + hfin[o1]);
        ssum += st[u];
    }
    float wsum = wave_sum(ssum);
    if ((tid & 63) == 0) sb1[tid >> 6] = wsum;
    __syncthreads();
    float mu = (sb1[0] + sb1[1] + sb1[2] + sb1[3]) * (1.f / 512.f);
    float vs = 0.f;
#pragma unroll
    for (int u = 0; u < 2; ++u) {
        float t = st[u] - mu;
        vs = fmaf(t, t, vs);
    }
    float wv = wave_sum(vs);
    if ((tid & 63) == 0) sb2[tid >> 6] = wv;
    __syncthreads();
    float var = (sb2[0] + sb2[1] + sb2[2] + sb2[3]) * (1.f / 512.f);
    float inv = rsqrtf(var + 1e-5f);
#pragma unroll
    for (int u = 0; u < 2; ++u) {
        int c = tid + u * 256;
        sln[c] = (st[u] - mu) * inv * lnw[c] + lnb[c];
    }
    __syncthreads();
    const float4* w4 = (const float4*)(woq + (size_t)tid * 512);
    float acc = 0.f;
#pragma unroll 4
    for (int i = 0; i < 128; ++i) {
        float4 wvv = w4[i];
        float4 sv = *(const float4*)&sln[i * 4];
        acc = fmaf(wvv.x, sv.x, acc);
        acc = fmaf(wvv.y, sv.y, acc);
        acc = fmaf(wvv.z, sv.z, acc);
        acc = fmaf(wvv.w, sv.w, acc);
    }
    outq[(size_t)bk * 256 + tid] = acc;
}

// ---------------------------------------------------------------- launcher
extern "C" void kernel_launch(void* const* d_in, const int* in_sizes, int n_in,
                              void* d_out, int out_size, void* d_ws, size_t ws_size,
                              hipStream_t stream) {
    const float* in_key      = (const float*)d_in[0];
    const float* in_query    = (const float*)d_in[1];
    const float* key_xyz     = (const float*)d_in[2];
    const float* query_xyz   = (const float*)d_in[3];
    const float* query_size  = (const float*)d_in[4];
    const float* query_angle = (const float*)d_in[5];
    const float* Wkey        = (const float*)d_in[6];
    const float* conv_w      = (const float*)d_in[7];
    const float* conv_b      = (const float*)d_in[8];
    const float* convb_w     = (const float*)d_in[9];
    const float* convb_b     = (const float*)d_in[10];
    const float* Wq          = (const float*)d_in[11];
    const float* Wbc         = (const float*)d_in[12];
    const float* Wdt         = (const float*)d_in[13];
    const float* dt_bias     = (const float*)d_in[14];
    const float* A_log       = (const float*)d_in[15];
    const float* Dp          = (const float*)d_in[16];
    const float* Wok         = (const float*)d_in[17];
    const float* Woq         = (const float*)d_in[18];
    const float* key_norm_w  = (const float*)d_in[19];
    const float* ln_w        = (const float*)d_in[20];
    const float* ln_b        = (const float*)d_in[21];
    const float* cpb_w1      = (const float*)d_in[22];
    const float* cpb_b1      = (const float*)d_in[23];
    const float* cpb_w2      = (const float*)d_in[24];
    float* out = (float*)d_out;

    float* wsf = (float*)d_ws;
    float* zxA   = wsf + 0;         // 2048*1034 (K half 0)
    float* xf    = wsf + 2117632;   // 2048*514
    float* xb    = wsf + 3170304;   // 2048*514
    float* tbl   = wsf + 4222976;   // 4000
    float* cbuf  = wsf + 4226976;   // 2*1024*8
    float* Pbuf  = wsf + 4243360;   // 2*8*16*128
    float* dAa   = wsf + 5291936;   // 2*8*1024*128
    float* dBf   = wsf + 7389088;
    float* dBb   = wsf + 9486240;
    float* Cfb   = wsf + 11583392;  // 2*1024*128
    float* Cbb   = wsf + 11845536;
    float* h0b   = wsf + 12107680;  // 256*512
    float* yfb   = wsf + 12238752;  // 2048*512
    float* ybb   = wsf + 13287328;
    float* hfin  = wsf + 14335904;  // 2*2*8*64*128
    float* gated = wsf + 14598048;  // 2048*512
    float* Sbuf  = wsf + 15646624;  // 4,194,304 floats
    float* zxB   = wsf + 19840928;  // 2048*1034 (K half 1)

    setup_k<<<12, 256, 0, stream>>>(query_xyz, query_size, query_angle,
                                    cpb_w1, cpb_b1, cpb_w2, cbuf, tbl);
    front_k<<<1120, 256, 0, stream>>>(in_key, Wkey, zxA, zxB, in_query, Wq, h0b);
    dwconv_silu2<<<dim3(2048, 3), 256, 0, stream>>>(zxA, zxB, conv_w, conv_b, xf);
    dwconv_silu<<<dim3(2048, 3), 256, 0, stream>>>(xf, CC, 0, convb_w, convb_b, xb);
    geo_k<<<2048, 128, 0, stream>>>(key_xyz, cbuf, tbl, zxA, zxB, xf, xb,
                                    Wbc, Wdt, dt_bias, A_log,
                                    dAa, dBf, dBb, Cfb, Cbb);
    scan_part6<<<512, 256, 0, stream>>>(dAa, dBf, dBb, Cfb, Cbb, xf, xb,
                                        Sbuf, Pbuf, yfb, ybb);
    scan_combine<<<128, 256, 0, stream>>>(h0b, Sbuf, Pbuf, hfin);
    scan_corr<<<512, 256, 0, stream>>>(dAa, Cfb, Cbb, Sbuf, yfb, ybb);
    gated_k<<<2048, 256, 0, stream>>>(yfb, ybb, xf, zxA, zxB, Dp, key_norm_w, gated);
    final_k<<<384, 256, 0, stream>>>(gated, Wok, out, hfin, ln_w, ln_b, Woq,
                                     out + 524288);
}

// Round 14
// 202.422 us; speedup vs baseline: 1.0853x; 1.0853x over previous
//
#include <hip/hip_runtime.h>
#include <math.h>

#define B_ 2
#define L_ 1024
#define K_ 128
#define DM 256
#define DI 512
#define NH 8
#define HD 64
#define CC 514
#define ZCOLS 1034
#define NC 16
#define TC 64

// ---------------------------------------------------------------- utilities
__device__ __forceinline__ float wave_sum(float v) {
    v += __shfl_xor(v, 1);  v += __shfl_xor(v, 2);  v += __shfl_xor(v, 4);
    v += __shfl_xor(v, 8);  v += __shfl_xor(v, 16); v += __shfl_xor(v, 32);
    return v;
}

// sum across each 16-lane DPP row via row_ror — VALU pipe, NOT the DS pipe.
__device__ __forceinline__ float dpp_row_reduce16(float v) {
    int t;
    t = __builtin_amdgcn_update_dpp(0, __float_as_int(v), 0x128, 0xF, 0xF, true); // row_ror:8
    v += __int_as_float(t);
    t = __builtin_amdgcn_update_dpp(0, __float_as_int(v), 0x124, 0xF, 0xF, true); // row_ror:4
    v += __int_as_float(t);
    t = __builtin_amdgcn_update_dpp(0, __float_as_int(v), 0x122, 0xF, 0xF, true); // row_ror:2
    v += __int_as_float(t);
    t = __builtin_amdgcn_update_dpp(0, __float_as_int(v), 0x121, 0xF, 0xF, true); // row_ror:1
    v += __int_as_float(t);
    return v;
}

__device__ __forceinline__ float silu_f(float x) {
    return x / (1.f + expf(-x));
}

// ---------------------------------------------------------------- pipelined NT GEMM (device body)
// C[M][N] = sum_k A[M][K] * B[N][K]; one barrier per k-tile (staging writes go to
// the OTHER LDS buffer, so no pre-write barrier needed).
__device__ void gemm_dev(const float* __restrict__ A, const float* __restrict__ Bm,
                         float* __restrict__ C, int M, int N, int K, int bm, int bn) {
    __shared__ float As[2][16][68];
    __shared__ float Bs[2][16][68];
    const int tid = threadIdx.x;
    const int sr = tid >> 2;          // stage row 0..63
    const int sk = (tid & 3) * 4;     // stage k 0,4,8,12
    const int tx = tid & 15, ty = tid >> 4;
    const int NT = K >> 4;
    const float* Arow = A + (size_t)(bm + sr) * K + sk;
    const float* Brow = Bm + (size_t)(bn + sr) * K + sk;
    const bool bok = (bn + sr) < N;

    float4 av = *(const float4*)Arow;
    float4 bv = bok ? *(const float4*)Brow : make_float4(0.f, 0.f, 0.f, 0.f);
    As[0][sk + 0][sr] = av.x; As[0][sk + 1][sr] = av.y;
    As[0][sk + 2][sr] = av.z; As[0][sk + 3][sr] = av.w;
    Bs[0][sk + 0][sr] = bv.x; Bs[0][sk + 1][sr] = bv.y;
    Bs[0][sk + 2][sr] = bv.z; Bs[0][sk + 3][sr] = bv.w;
    __syncthreads();

    float acc[4][4] = {};
    for (int t = 0; t < NT; ++t) {
        if (t + 1 < NT) {             // issue next tile's loads early
            av = *(const float4*)(Arow + (t + 1) * 16);
            bv = bok ? *(const float4*)(Brow + (t + 1) * 16) : make_float4(0.f, 0.f, 0.f, 0.f);
        }
        const int bi = t & 1;
#pragma unroll
        for (int kk = 0; kk < 16; ++kk) {
            float4 a = *(const float4*)&As[bi][kk][ty * 4];
            float4 b = *(const float4*)&Bs[bi][kk][tx * 4];
            acc[0][0] = fmaf(a.x, b.x, acc[0][0]); acc[0][1] = fmaf(a.x, b.y, acc[0][1]);
            acc[0][2] = fmaf(a.x, b.z, acc[0][2]); acc[0][3] = fmaf(a.x, b.w, acc[0][3]);
            acc[1][0] = fmaf(a.y, b.x, acc[1][0]); acc[1][1] = fmaf(a.y, b.y, acc[1][1]);
            acc[1][2] = fmaf(a.y, b.z, acc[1][2]); acc[1][3] = fmaf(a.y, b.w, acc[1][3]);
            acc[2][0] = fmaf(a.z, b.x, acc[2][0]); acc[2][1] = fmaf(a.z, b.y, acc[2][1]);
            acc[2][2] = fmaf(a.z, b.z, acc[2][2]); acc[2][3] = fmaf(a.z, b.w, acc[2][3]);
            acc[3][0] = fmaf(a.w, b.x, acc[3][0]); acc[3][1] = fmaf(a.w, b.y, acc[3][1]);
            acc[3][2] = fmaf(a.w, b.z, acc[3][2]); acc[3][3] = fmaf(a.w, b.w, acc[3][3]);
        }
        if (t + 1 < NT) {             // write OTHER buffer; safe before barrier
            const int ni = (t + 1) & 1;
            As[ni][sk + 0][sr] = av.x; As[ni][sk + 1][sr] = av.y;
            As[ni][sk + 2][sr] = av.z; As[ni][sk + 3][sr] = av.w;
            Bs[ni][sk + 0][sr] = bv.x; Bs[ni][sk + 1][sr] = bv.y;
            Bs[ni][sk + 2][sr] = bv.z; Bs[ni][sk + 3][sr] = bv.w;
        }
        __syncthreads();              // single barrier per tile
    }
    // epilogue: float2 stores (N=1034 rows are only 8B-aligned)
#pragma unroll
    for (int i = 0; i < 4; ++i) {
        int m = bm + ty * 4 + i;
        int n0 = bn + tx * 4;
        if (n0 + 3 < N) {
            float* cp = &C[(size_t)m * N + n0];
            *(float2*)cp = make_float2(acc[i][0], acc[i][1]);
            *(float2*)(cp + 2) = make_float2(acc[i][2], acc[i][3]);
        } else {
#pragma unroll
            for (int j = 0; j < 4; ++j)
                if (n0 + j < N) C[(size_t)m * N + n0 + j] = acc[i][j];
        }
    }
}

// ---------------------------------------------------------------- front: zx GEMM + h0 GEMM + setup
// blocks 0..543: zx = in_key @ Wkey^T (2048x1034x256), tiles (bid&31, bid>>5)
// blocks 544..575: h0 = in_query @ Wq^T (256x512x256)
// blocks 576..587: corners (8) + cpb table (4)
// launch_bounds(256,4): cap VGPR at 128 (was 132 -> 3 waves/SIMD band; 4 regs of
// squeeze is low spill risk and buys +33% resident waves for the GEMM).
__global__ __launch_bounds__(256, 4) void front_k(
    const float* __restrict__ in_key, const float* __restrict__ Wkey, float* __restrict__ zx,
    const float* __restrict__ in_query, const float* __restrict__ Wq, float* __restrict__ h0b,
    const float* __restrict__ qxyz, const float* __restrict__ qsize,
    const float* __restrict__ qang, const float* __restrict__ w1,
    const float* __restrict__ b1, const float* __restrict__ w2,
    float* __restrict__ cb, float* __restrict__ tbl) {
    int bid = blockIdx.x, tid = threadIdx.x;
    if (bid < 544) {
        gemm_dev(in_key, Wkey, zx, 2048, ZCOLS, 256, (bid & 31) * 64, (bid >> 5) * 64);
    } else if (bid < 576) {
        int r = bid - 544;
        gemm_dev(in_query, Wq, h0b, 256, 512, 256, (r & 3) * 64, (r >> 2) * 64);
    } else if (bid < 584) {
        int idx = (bid - 576) * 256 + tid;    // < 2048 = B_*K_*8
        int b = idx >> 10;
        int q = idx & 1023;
        int k = q >> 3;
        int c = q & 7;
        const float sx[8] = {1, 1, -1, -1, 1, 1, -1, -1};
        const float sy[8] = {1, 1, 1, 1, -1, -1, -1, -1};
        const float sz[8] = {1, -1, -1, 1, 1, -1, -1, 1};
        float cx = qxyz[(b * K_ + k) * 3 + 0];
        float cy = qxyz[(b * K_ + k) * 3 + 1];
        float cz = qxyz[(b * K_ + k) * 3 + 2];
        float lv = qsize[(b * K_ + k) * 3 + 0];
        float wv = qsize[(b * K_ + k) * 3 + 1];
        float hv = qsize[(b * K_ + k) * 3 + 2];
        float ang = qang[b * K_ + k];
        float ca = cosf(ang), sa = sinf(ang);
        float ccx = cx, ccy = -cz, ccz = cy;
        float l0 = lv * sx[c] * 0.5f;
        float l1 = hv * sy[c] * 0.5f;
        float l2 = wv * sz[c] * 0.5f;
        float m0 = ca * l0 + sa * l2 + ccx;
        float m1 = l1 + ccy;
        float m2 = -sa * l0 + ca * l2 + ccz;
        // rotation for the distance transform uses angle[b, q % K] (jnp.tile semantics)
        float angr = qang[b * K_ + (q & (K_ - 1))];
        float4* o = (float4*)(cb + (size_t)idx * 8);
        o[0] = make_float4(m0, m2, -m1, cosf(angr));
        o[1] = make_float4(sinf(angr), 0.f, 0.f, 0.f);
    } else {
        int p = (bid - 584) * 256 + tid;
        if (p >= 1000) return;
        int i = p / 100, j = (p / 10) % 10, k = p % 10;
        float c0 = (8.f / 9.f) * i - 4.f;
        float c1 = (8.f / 9.f) * j - 4.f;
        float c2 = (8.f / 9.f) * k - 4.f;
        float a0 = 0.f, a1 = 0.f, a2 = 0.f, a3 = 0.f;
        for (int m = 0; m < 128; ++m) {
            float t = fmaf(c0, w1[m * 3 + 0], fmaf(c1, w1[m * 3 + 1], fmaf(c2, w1[m * 3 + 2], b1[m])));
            t = fmaxf(t, 0.f);
            a0 = fmaf(t, w2[m], a0);
            a1 = fmaf(t, w2[128 + m], a1);
            a2 = fmaf(t, w2[256 + m], a2);
            a3 = fmaf(t, w2[384 + m], a3);
        }
        tbl[p * 4 + 0] = a0; tbl[p * 4 + 1] = a1;
        tbl[p * 4 + 2] = a2; tbl[p * 4 + 3] = a3;
    }
}

// ---------------------------------------------------------------- depthwise conv7 + silu
__global__ void dwconv_silu(const float* __restrict__ xin, int in_stride, int in_off,
                            const float* __restrict__ w, const float* __restrict__ bias,
                            float* __restrict__ out) {
    int c = blockIdx.y * blockDim.x + threadIdx.x;
    if (c >= CC) return;
    int row = blockIdx.x;                 // b*L + l
    int l = row & (L_ - 1);
    const float* xr = xin + (size_t)row * in_stride + in_off + c;
    float acc = bias[c];
#pragma unroll
    for (int j = 0; j < 7; ++j) {
        int ll = l + j - 3;
        if (ll >= 0 && ll < L_) acc = fmaf(xr[(ptrdiff_t)(j - 3) * in_stride], w[c * 7 + j], acc);
    }
    out[(size_t)row * CC + c] = silu_f(acc);
}

// ---------------------------------------------------------------- fused dist + dA/dB/C
__global__ __launch_bounds__(128) void geo_k(
    const float* __restrict__ kxyz, const float* __restrict__ cb,
    const float* __restrict__ tbl, const float* __restrict__ zx,
    const float* __restrict__ xf, const float* __restrict__ xb,
    const float* __restrict__ wbc, const float* __restrict__ wdt,
    const float* __restrict__ dtb, const float* __restrict__ alog,
    float* __restrict__ dA, float* __restrict__ dBf, float* __restrict__ dBb,
    float* __restrict__ Cf, float* __restrict__ Cb) {
    __shared__ float t_s[4000];
    int row = blockIdx.x;                 // b*L + l
    int b = row >> 10;
    int l = row & 1023;
    int k = threadIdx.x;
    for (int i = threadIdx.x; i < 4000; i += 128) t_s[i] = tbl[i];
    __syncthreads();
    float kx = kxyz[(size_t)row * 3 + 0];
    float ky = kxyz[(size_t)row * 3 + 1];
    float kz = kxyz[(size_t)row * 3 + 2];
    float acc0 = 0.f, acc1 = 0.f, acc2 = 0.f, acc3 = 0.f;
#pragma unroll
    for (int c = 0; c < 8; ++c) {
        int q = k * 8 + c;
        const float4* p = (const float4*)(cb + (size_t)(b * 1024 + q) * 8);
        float4 v0 = p[0], v1 = p[1];
        float d0 = v0.x - kx, d1 = v0.y - ky, d2 = v0.z - kz;
        float rc = v0.w, rs = v1.x;
        float e0 = d0, e1 = -d2, e2 = d1;
        float f0 = rc * e0 - rs * e2;
        float f1 = e1;
        float f2 = rs * e0 + rc * e2;
        float g0 = f0, g1 = f2, g2 = -f1;
        g0 = copysignf(log2f(fabsf(g0) * 512.f + 1.f) * (1.f / 12.f), g0);
        g1 = copysignf(log2f(fabsf(g1) * 512.f + 1.f) * (1.f / 12.f), g1);
        g2 = copysignf(log2f(fabsf(g2) * 512.f + 1.f) * (1.f / 12.f), g2);
        // table axis0 <- g2, axis1 <- g1, axis2 <- g0
        float iq = 5.f * g2 + 4.5f;
        float jq = 5.f * g1 + 4.5f;
        float kq = 5.f * g0 + 4.5f;
        float i0f = floorf(iq), j0f = floorf(jq), k0f = floorf(kq);
        float wi = iq - i0f, wj = jq - j0f, wk = kq - k0f;
        int i0 = (int)i0f, j0 = (int)j0f, k0 = (int)k0f;
#pragma unroll
        for (int a = 0; a < 2; ++a) {
#pragma unroll
            for (int bb = 0; bb < 2; ++bb) {
#pragma unroll
                for (int cc = 0; cc < 2; ++cc) {
                    int ii = i0 + a, jj = j0 + bb, kk = k0 + cc;
                    if ((unsigned)ii < 10u && (unsigned)jj < 10u && (unsigned)kk < 10u) {
                        float wgt = (a ? wi : 1.f - wi) * (bb ? wj : 1.f - wj) * (cc ? wk : 1.f - wk);
                        const float* tp = &t_s[((ii * 10 + jj) * 10 + kk) * 4];
                        acc0 = fmaf(wgt, tp[0], acc0);
                        acc1 = fmaf(wgt, tp[1], acc1);
                        acc2 = fmaf(wgt, tp[2], acc2);
                        acc3 = fmaf(wgt, tp[3], acc3);
                    }
                }
            }
        }
    }
    // ---- fused precomp tail
    float B0 = acc0 * wbc[0] + acc1 * wbc[1] + acc2 * wbc[2] + acc3 * wbc[3];
    float C0 = acc0 * wbc[4] + acc1 * wbc[5] + acc2 * wbc[6] + acc3 * wbc[7];
    float bbf = xf[(size_t)row * CC + 512], cbf = xf[(size_t)row * CC + 513];
    float bbb = xb[(size_t)row * CC + 512], cbb = xb[(size_t)row * CC + 513];
    Cf[(size_t)row * K_ + k] = C0 + cbf;
    Cb[(size_t)row * K_ + k] = C0 + cbb;
    float Bf = B0 + bbf, Bb = B0 + bbb;
#pragma unroll
    for (int hh = 0; hh < NH; ++hh) {
        float s = acc0 * wdt[hh * 4 + 0] + acc1 * wdt[hh * 4 + 1] +
                  acc2 * wdt[hh * 4 + 2] + acc3 * wdt[hh * 4 + 3];
        s += zx[(size_t)row * ZCOLS + 1026 + hh] + dtb[hh];
        float dtv = (s > 20.f) ? s : log1pf(expf(s));
        float Av = -expf(alog[hh]);
        size_t o = ((size_t)(b * NH + hh) * L_ + l) * K_ + k;
        dA[o] = expf(dtv * Av);
        dBf[o] = dtv * Bf;
        dBb[o] = dtv * Bb;
    }
}

// ---------------------------------------------------------------- chunked ISSM scan, LDS-fed
// block = 256 thr (4 waves) = one (dir,b,hh,chunk); lane owns 8 k x 4 d (d = dloc+{0,16,32,48}).
// dir==0 blocks also carry the chunk cumprod P. One barrier per 8-step tile.
__global__ __launch_bounds__(256) void scan_part6(
    const float* __restrict__ dA, const float* __restrict__ dBf, const float* __restrict__ dBb,
    const float* __restrict__ Cf, const float* __restrict__ Cb,
    const float* __restrict__ xf, const float* __restrict__ xb,
    float* __restrict__ Sbuf, float* __restrict__ Pbuf,
    float* __restrict__ yf, float* __restrict__ yb) {
    __shared__ float lds[2][3584];
    int bid = blockIdx.x;
    int c = bid & 15;
    int hh = (bid >> 4) & 7;
    int b = (bid >> 7) & 1;
    int dir = bid >> 8;
    int tid = threadIdx.x;             // 0..255
    int lane = tid & 63;
    int w = tid >> 6;                  // 0..3
    int dg = lane >> 4, kg = lane & 15;
    int dloc = w * 4 + dg;             // 0..15; lane owns d = dloc + 16*{0,1,2,3}
    int klo = kg * 4, khi = 64 + kg * 4;

    const float* Bsrc = dir ? dBb : dBf;
    const float* Csrc = dir ? Cb : Cf;
    const float* Xsrc = dir ? xb : xf;
    float* Ydst = dir ? yb : yf;
    int t0 = dir ? (L_ - 1 - c * TC) : c * TC;
    int stp = dir ? -1 : 1;

    const float* Abase = dA + ((size_t)(b * NH + hh) * L_) * K_;
    const float* Bbase = Bsrc + ((size_t)(b * NH + hh) * L_) * K_;
    const float* Cbase = Csrc + ((size_t)b * L_) * K_;
    const float* Xbase = Xsrc + ((size_t)b * L_) * CC + hh * HD;

    const bool hasx = (tid < 128);

    auto gaddr = [&](int v, int tb) -> const float* {
        if (v < 768) {
            int r = (v >> 5) & 7;
            int c4 = v & 31;
            int l = t0 + stp * (tb + r);
            const float* base = (v < 256) ? Abase : ((v < 512) ? Bbase : Cbase);
            return base + (size_t)l * K_ + c4 * 4;
        } else {
            int vv = v - 768;
            int r = vv >> 4, c4 = vv & 15;
            int l = t0 + stp * (tb + r);
            return Xbase + (size_t)l * CC + c4 * 4;
        }
    };

    float hA[8] = {0, 0, 0, 0, 0, 0, 0, 0};
    float hB[8] = {0, 0, 0, 0, 0, 0, 0, 0};
    float hC[8] = {0, 0, 0, 0, 0, 0, 0, 0};
    float hD[8] = {0, 0, 0, 0, 0, 0, 0, 0};
    float cum[8] = {1, 1, 1, 1, 1, 1, 1, 1};

    // prologue: stage tile 0 into buf 0
    float4 rA = *(const float4*)gaddr(tid, 0);
    float4 rB = *(const float4*)gaddr(256 + tid, 0);
    float4 rC = *(const float4*)gaddr(512 + tid, 0);
    float4 rX = hasx ? *(const float4*)gaddr(768 + tid, 0) : make_float4(0, 0, 0, 0);
    *(float4*)&lds[0][4 * tid] = rA;
    *(float4*)&lds[0][1024 + 4 * tid] = rB;
    *(float4*)&lds[0][2048 + 4 * tid] = rC;
    if (hasx) *(float4*)&lds[0][3072 + 4 * tid] = rX;
    __syncthreads();

    float* pY = Ydst + ((size_t)(b * L_ + t0)) * DI + hh * HD + dloc;
    const ptrdiff_t dY = (ptrdiff_t)stp * DI;

    for (int it = 0; it < TC / 8; ++it) {
        int tb = it * 8;
        if (it < TC / 8 - 1) {           // issue next tile's global loads early
            rA = *(const float4*)gaddr(tid, tb + 8);
            rB = *(const float4*)gaddr(256 + tid, tb + 8);
            rC = *(const float4*)gaddr(512 + tid, tb + 8);
            if (hasx) rX = *(const float4*)gaddr(768 + tid, tb + 8);
        }
        const float* Lb = lds[it & 1];
        // preload step 0
        float4 a0 = *(const float4*)&Lb[klo];
        float4 a1 = *(const float4*)&Lb[khi];
        float4 b0 = *(const float4*)&Lb[1024 + klo];
        float4 b1 = *(const float4*)&Lb[1024 + khi];
        float4 c0 = *(const float4*)&Lb[2048 + klo];
        float4 c1 = *(const float4*)&Lb[2048 + khi];
        float x0 = Lb[3072 + dloc];
        float x1 = Lb[3072 + 16 + dloc];
        float x2 = Lb[3072 + 32 + dloc];
        float x3 = Lb[3072 + 48 + dloc];
#pragma unroll
        for (int st = 0; st < 8; ++st) {
            float4 na0, na1, nb0, nb1, nc0, nc1;
            float nx0 = 0.f, nx1 = 0.f, nx2 = 0.f, nx3 = 0.f;
            if (st < 7) {                // issue step st+1's LDS reads before computing st
                int o = (st + 1) * 128;
                na0 = *(const float4*)&Lb[o + klo];
                na1 = *(const float4*)&Lb[o + khi];
                nb0 = *(const float4*)&Lb[1024 + o + klo];
                nb1 = *(const float4*)&Lb[1024 + o + khi];
                nc0 = *(const float4*)&Lb[2048 + o + klo];
                nc1 = *(const float4*)&Lb[2048 + o + khi];
                int xo = 3072 + (st + 1) * 64 + dloc;
                nx0 = Lb[xo]; nx1 = Lb[xo + 16]; nx2 = Lb[xo + 32]; nx3 = Lb[xo + 48];
            }
            cum[0] *= a0.x; cum[1] *= a0.y; cum[2] *= a0.z; cum[3] *= a0.w;
            cum[4] *= a1.x; cum[5] *= a1.y; cum[6] *= a1.z; cum[7] *= a1.w;
            float u0, u1, u2, u3;
            // d-block A (x0)
            hA[0] = fmaf(hA[0], a0.x, x0 * b0.x); u0 = hA[0] * c0.x;
            hA[1] = fmaf(hA[1], a0.y, x0 * b0.y); u1 = hA[1] * c0.y;
            hA[2] = fmaf(hA[2], a0.z, x0 * b0.z); u2 = hA[2] * c0.z;
            hA[3] = fmaf(hA[3], a0.w, x0 * b0.w); u3 = hA[3] * c0.w;
            hA[4] = fmaf(hA[4], a1.x, x0 * b1.x); u0 = fmaf(hA[4], c1.x, u0);
            hA[5] = fmaf(hA[5], a1.y, x0 * b1.y); u1 = fmaf(hA[5], c1.y, u1);
            hA[6] = fmaf(hA[6], a1.z, x0 * b1.z); u2 = fmaf(hA[6], c1.z, u2);
            hA[7] = fmaf(hA[7], a1.w, x0 * b1.w); u3 = fmaf(hA[7], c1.w, u3);
            float rrA = dpp_row_reduce16((u0 + u1) + (u2 + u3));
            // d-block B (x1)
            hB[0] = fmaf(hB[0], a0.x, x1 * b0.x); u0 = hB[0] * c0.x;
            hB[1] = fmaf(hB[1], a0.y, x1 * b0.y); u1 = hB[1] * c0.y;
            hB[2] = fmaf(hB[2], a0.z, x1 * b0.z); u2 = hB[2] * c0.z;
            hB[3] = fmaf(hB[3], a0.w, x1 * b0.w); u3 = hB[3] * c0.w;
            hB[4] = fmaf(hB[4], a1.x, x1 * b1.x); u0 = fmaf(hB[4], c1.x, u0);
            hB[5] = fmaf(hB[5], a1.y, x1 * b1.y); u1 = fmaf(hB[5], c1.y, u1);
            hB[6] = fmaf(hB[6], a1.z, x1 * b1.z); u2 = fmaf(hB[6], c1.z, u2);
            hB[7] = fmaf(hB[7], a1.w, x1 * b1.w); u3 = fmaf(hB[7], c1.w, u3);
            float rrB = dpp_row_reduce16((u0 + u1) + (u2 + u3));
            // d-block C (x2)
            hC[0] = fmaf(hC[0], a0.x, x2 * b0.x); u0 = hC[0] * c0.x;
            hC[1] = fmaf(hC[1], a0.y, x2 * b0.y); u1 = hC[1] * c0.y;
            hC[2] = fmaf(hC[2], a0.z, x2 * b0.z); u2 = hC[2] * c0.z;
            hC[3] = fmaf(hC[3], a0.w, x2 * b0.w); u3 = hC[3] * c0.w;
            hC[4] = fmaf(hC[4], a1.x, x2 * b1.x); u0 = fmaf(hC[4], c1.x, u0);
            hC[5] = fmaf(hC[5], a1.y, x2 * b1.y); u1 = fmaf(hC[5], c1.y, u1);
            hC[6] = fmaf(hC[6], a1.z, x2 * b1.z); u2 = fmaf(hC[6], c1.z, u2);
            hC[7] = fmaf(hC[7], a1.w, x2 * b1.w); u3 = fmaf(hC[7], c1.w, u3);
            float rrC = dpp_row_reduce16((u0 + u1) + (u2 + u3));
            // d-block D (x3)
            hD[0] = fmaf(hD[0], a0.x, x3 * b0.x); u0 = hD[0] * c0.x;
            hD[1] = fmaf(hD[1], a0.y, x3 * b0.y); u1 = hD[1] * c0.y;
            hD[2] = fmaf(hD[2], a0.z, x3 * b0.z); u2 = hD[2] * c0.z;
            hD[3] = fmaf(hD[3], a0.w, x3 * b0.w); u3 = hD[3] * c0.w;
            hD[4] = fmaf(hD[4], a1.x, x3 * b1.x); u0 = fmaf(hD[4], c1.x, u0);
            hD[5] = fmaf(hD[5], a1.y, x3 * b1.y); u1 = fmaf(hD[5], c1.y, u1);
            hD[6] = fmaf(hD[6], a1.z, x3 * b1.z); u2 = fmaf(hD[6], c1.z, u2);
            hD[7] = fmaf(hD[7], a1.w, x3 * b1.w); u3 = fmaf(hD[7], c1.w, u3);
            float rrD = dpp_row_reduce16((u0 + u1) + (u2 + u3));
            if (kg == 0) { pY[0] = rrA; pY[16] = rrB; pY[32] = rrC; pY[48] = rrD; }
            pY += dY;
            if (st < 7) {
                a0 = na0; a1 = na1; b0 = nb0; b1 = nb1; c0 = nc0; c1 = nc1;
                x0 = nx0; x1 = nx1; x2 = nx2; x3 = nx3;
            }
        }
        if (it < TC / 8 - 1) {           // write OTHER buffer; safe before barrier
            *(float4*)&lds[(it + 1) & 1][4 * tid] = rA;
            *(float4*)&lds[(it + 1) & 1][1024 + 4 * tid] = rB;
            *(float4*)&lds[(it + 1) & 1][2048 + 4 * tid] = rC;
            if (hasx) *(float4*)&lds[(it + 1) & 1][3072 + 4 * tid] = rX;
        }
        __syncthreads();                 // single barrier per tile
    }

    int ibh = (dir * B_ + b) * NH + hh;
    {
        float* Sp = Sbuf + (((size_t)ibh * NC + c) * HD + dloc) * K_;
        *(float4*)(Sp + klo) = make_float4(hA[0], hA[1], hA[2], hA[3]);
        *(float4*)(Sp + khi) = make_float4(hA[4], hA[5], hA[6], hA[7]);
        Sp += (size_t)16 * K_;
        *(float4*)(Sp + klo) = make_float4(hB[0], hB[1], hB[2], hB[3]);
        *(float4*)(Sp + khi) = make_float4(hB[4], hB[5], hB[6], hB[7]);
        Sp += (size_t)16 * K_;
        *(float4*)(Sp + klo) = make_float4(hC[0], hC[1], hC[2], hC[3]);
        *(float4*)(Sp + khi) = make_float4(hC[4], hC[5], hC[6], hC[7]);
        Sp += (size_t)16 * K_;
        *(float4*)(Sp + klo) = make_float4(hD[0], hD[1], hD[2], hD[3]);
        *(float4*)(Sp + khi) = make_float4(hD[4], hD[5], hD[6], hD[7]);
    }
    if (dir == 0 && tid < 16) {          // w==0, dg==0, kg==tid: cum identical across d
        float* Pp = Pbuf + ((size_t)((b * NH + hh) * NC + c)) * K_;
        *(float4*)(Pp + klo) = make_float4(cum[0], cum[1], cum[2], cum[3]);
        *(float4*)(Pp + khi) = make_float4(cum[4], cum[5], cum[6], cum[7]);
    }
}

// phase 2: sequential combine across NC chunks; overwrites Sbuf with incoming state Hin;
// writes final state hfin. grid = 128 x 256: bid = ((dir*2+b)*8+hh)*4 + dq; wave w: dsl=dq*4+w
__global__ __launch_bounds__(256) void scan_combine(
    const float* __restrict__ h0buf, float* __restrict__ Sbuf,
    const float* __restrict__ Pbuf, float* __restrict__ hfin) {
    int bid = blockIdx.x;
    int dq = bid & 3;
    int hh = (bid >> 2) & 7;
    int b = (bid >> 5) & 1;
    int dir = bid >> 6;
    int tid = threadIdx.x;
    int w = tid >> 6;
    int lane = tid & 63;
    int dsl = dq * 4 + w;
    int dg = lane >> 4, kg = lane & 15;
    int d = dsl * 4 + dg;
    int k0 = kg * 8;

    float H[8];
#pragma unroll
    for (int j = 0; j < 8; ++j)
        H[j] = h0buf[(size_t)(b * K_ + k0 + j) * DI + hh * HD + d];

    int ibh = (dir * B_ + b) * NH + hh;
    for (int c = 0; c < NC; ++c) {
        float* Sp = Sbuf + (((size_t)ibh * NC + c) * HD + d) * K_ + k0;
        int cF = dir ? (NC - 1 - c) : c;   // P computed on fwd chunk row-sets
        const float* Pp = Pbuf + ((size_t)((b * NH + hh) * NC + cF)) * K_ + k0;
        float4 sA = *(const float4*)(Sp + 0);
        float4 sB = *(const float4*)(Sp + 4);
        float4 pA = *(const float4*)(Pp + 0);
        float4 pB = *(const float4*)(Pp + 4);
        // store incoming state for this chunk (overwrites S)
        *(float4*)(Sp + 0) = make_float4(H[0], H[1], H[2], H[3]);
        *(float4*)(Sp + 4) = make_float4(H[4], H[5], H[6], H[7]);
        H[0] = fmaf(H[0], pA.x, sA.x); H[1] = fmaf(H[1], pA.y, sA.y);
        H[2] = fmaf(H[2], pA.z, sA.z); H[3] = fmaf(H[3], pA.w, sA.w);
        H[4] = fmaf(H[4], pB.x, sB.x); H[5] = fmaf(H[5], pB.y, sB.y);
        H[6] = fmaf(H[6], pB.z, sB.z); H[7] = fmaf(H[7], pB.w, sB.w);
    }
    float* hf = hfin + ((((size_t)dir * B_ + b) * NH + hh) * HD + d) * K_ + k0;
    *(float4*)(hf + 0) = make_float4(H[0], H[1], H[2], H[3]);
    *(float4*)(hf + 4) = make_float4(H[4], H[5], H[6], H[7]);
}

// phase 3: y[t,d] += sum_k C[t,k]*cumA[t,k] * Hin[k,d]  (64x64x128 GEMM per instance)
// grid = 512 x 256: iid = ((dir*2+b)*8+hh)*16 + c
#define CP 72
#define WSWZ(k) ((((k) >> 3) & 3) << 2)
__global__ __launch_bounds__(256) void scan_corr(
    const float* __restrict__ dA, const float* __restrict__ Cf, const float* __restrict__ Cb,
    const float* __restrict__ Sbuf, float* __restrict__ yf, float* __restrict__ yb) {
    __shared__ float Wl[128][CP];   // [k][t] (t XOR-swizzled by WSWZ(k))
    __shared__ float Hl[128][CP];   // [k][d]
    int iid = blockIdx.x;
    int c = iid & 15;
    int hh = (iid >> 4) & 7;
    int b = (iid >> 7) & 1;
    int dir = iid >> 8;
    int tid = threadIdx.x;
    const float* Csrc = dir ? Cb : Cf;

    // phase A: W[k][t] = C[l(t),k] * cumA(t,k), scan order
    if (tid < 128) {
        int k = tid;
        float cum = 1.f;
        const float* pA = dA + ((size_t)(b * NH + hh) * L_) * K_ + k;
        const float* pC = Csrc + ((size_t)b * L_) * K_ + k;
        int sw = WSWZ(k);
#pragma unroll 4
        for (int t = 0; t < TC; ++t) {
            int l = dir ? (L_ - 1 - (c * TC + t)) : (c * TC + t);
            cum *= pA[(size_t)l * K_];
            Wl[k][t ^ sw] = cum * pC[(size_t)l * K_];
        }
    }
    // phase B: Hin [k][d] (transposed stage from Sbuf [d][k])
    {
        int d = tid & 63, kq = tid >> 6;   // kq 0..3
        int ibh = (dir * B_ + b) * NH + hh;
        const float* Hp = Sbuf + (((size_t)ibh * NC + c) * HD + d) * K_;
#pragma unroll
        for (int i = 0; i < 8; ++i) {
            int q = kq * 8 + i;            // float4 index 0..31
            float4 v = *(const float4*)(Hp + q * 4);
            Hl[q * 4 + 0][d] = v.x; Hl[q * 4 + 1][d] = v.y;
            Hl[q * 4 + 2][d] = v.z; Hl[q * 4 + 3][d] = v.w;
        }
    }
    __syncthreads();
    // phase C: GEMM 64t x 64d x 128k
    int a = tid >> 4;            // t-quad 0..15
    int bc = tid & 15;           // d-quad 0..15
    int t0v = a * 4, d0v = bc * 4;
    float acc[4][4] = {};
    for (int k = 0; k < 128; ++k) {
        float4 w4 = *(const float4*)&Wl[k][t0v ^ WSWZ(k)];
        float4 h4 = *(const float4*)&Hl[k][d0v];
        acc[0][0] = fmaf(w4.x, h4.x, acc[0][0]); acc[0][1] = fmaf(w4.x, h4.y, acc[0][1]);
        acc[0][2] = fmaf(w4.x, h4.z, acc[0][2]); acc[0][3] = fmaf(w4.x, h4.w, acc[0][3]);
        acc[1][0] = fmaf(w4.y, h4.x, acc[1][0]); acc[1][1] = fmaf(w4.y, h4.y, acc[1][1]);
        acc[1][2] = fmaf(w4.y, h4.z, acc[1][2]); acc[1][3] = fmaf(w4.y, h4.w, acc[1][3]);
        acc[2][0] = fmaf(w4.z, h4.x, acc[2][0]); acc[2][1] = fmaf(w4.z, h4.y, acc[2][1]);
        acc[2][2] = fmaf(w4.z, h4.z, acc[2][2]); acc[2][3] = fmaf(w4.z, h4.w, acc[2][3]);
        acc[3][0] = fmaf(w4.w, h4.x, acc[3][0]); acc[3][1] = fmaf(w4.w, h4.y, acc[3][1]);
        acc[3][2] = fmaf(w4.w, h4.z, acc[3][2]); acc[3][3] = fmaf(w4.w, h4.w, acc[3][3]);
    }
    float* Ydst = dir ? yb : yf;
#pragma unroll
    for (int i = 0; i < 4; ++i) {
        int t = t0v + i;
        int l = dir ? (L_ - 1 - (c * TC + t)) : (c * TC + t);
        float* yp = Ydst + ((size_t)(b * L_ + l)) * DI + hh * HD + d0v;
        float4 old = *(float4*)yp;
        old.x += acc[i][0]; old.y += acc[i][1];
        old.z += acc[i][2]; old.w += acc[i][3];
        *(float4*)yp = old;
    }
}

// ---------------------------------------------------------------- gate + RMSNorm
__global__ __launch_bounds__(256) void gated_k(
    const float* __restrict__ yf, const float* __restrict__ yb,
    const float* __restrict__ xf, const float* __restrict__ zx,
    const float* __restrict__ Dp, const float* __restrict__ knw,
    float* __restrict__ gated) {
    __shared__ float sb[4];
    int row = blockIdx.x;
    int tid = threadIdx.x;
    float g[2];
    float ss = 0.f;
#pragma unroll
    for (int u = 0; u < 2; ++u) {
        int c = tid + u * 256;
        float yv = yf[(size_t)row * DI + c] + yb[(size_t)row * DI + c] +
                   Dp[c >> 6] * xf[(size_t)row * CC + c];
        float z = zx[(size_t)row * ZCOLS + c];
        float gv = yv * silu_f(z);
        g[u] = gv;
        ss = fmaf(gv, gv, ss);
    }
    float wsum = wave_sum(ss);
    if ((tid & 63) == 0) sb[tid >> 6] = wsum;
    __syncthreads();
    float tot = sb[0] + sb[1] + sb[2] + sb[3];
    float rms = rsqrtf(tot * (1.f / 512.f) + 1e-5f);
#pragma unroll
    for (int u = 0; u < 2; ++u) {
        int c = tid + u * 256;
        gated[(size_t)row * DI + c] = g[u] * rms * knw[c];
    }
}

// ---------------------------------------------------------------- final: out GEMM + query path
// blocks 0..127: out = gated @ Wok^T (2048x256x512)
// blocks 128..383: query LN + GEMM (bk = bid-128)
__global__ __launch_bounds__(256) void final_k(
    const float* __restrict__ gated, const float* __restrict__ Wok, float* __restrict__ out,
    const float* __restrict__ hfin, const float* __restrict__ lnw,
    const float* __restrict__ lnb, const float* __restrict__ woq,
    float* __restrict__ outq) {
    int bid = blockIdx.x, tid = threadIdx.x;
    if (bid < 128) {
        gemm_dev(gated, Wok, out, 2048, 256, 512, (bid & 31) * 64, (bid >> 5) * 64);
        return;
    }
    __shared__ float sln[512];
    __shared__ float sb1[4];
    __shared__ float sb2[4];
    int bk = bid - 128;                   // b*K_ + k
    int b = bk >> 7;
    int k = bk & 127;
    float st[2];
    float ssum = 0.f;
#pragma unroll
    for (int u = 0; u < 2; ++u) {
        int c = tid + u * 256;
        int hh = c >> 6, d = c & 63;
        size_t o0 = (((size_t)(0 * B_ + b) * NH + hh) * HD + d) * K_ + k;
        size_t o1 = (((size_t)(1 * B_ + b) * NH + hh) * HD + d) * K_ + k;
        st[u] = 0.5f * (hfin[o0] + hfin[o1]);
        ssum += st[u];
    }
    float wsum = wave_sum(ssum);
    if ((tid & 63) == 0) sb1[tid >> 6] = wsum;
    __syncthreads();
    float mu = (sb1[0] + sb1[1] + sb1[2] + sb1[3]) * (1.f / 512.f);
    float vs = 0.f;
#pragma unroll
    for (int u = 0; u < 2; ++u) {
        float t = st[u] - mu;
        vs = fmaf(t, t, vs);
    }
    float wv = wave_sum(vs);
    if ((tid & 63) == 0) sb2[tid >> 6] = wv;
    __syncthreads();
    float var = (sb2[0] + sb2[1] + sb2[2] + sb2[3]) * (1.f / 512.f);
    float inv = rsqrtf(var + 1e-5f);
#pragma unroll
    for (int u = 0; u < 2; ++u) {
        int c = tid + u * 256;
        sln[c] = (st[u] - mu) * inv * lnw[c] + lnb[c];
    }
    __syncthreads();
    const float4* w4 = (const float4*)(woq + (size_t)tid * 512);
    float acc = 0.f;
#pragma unroll 4
    for (int i = 0; i < 128; ++i) {
        float4 wvv = w4[i];
        float4 sv = *(const float4*)&sln[i * 4];
        acc = fmaf(wvv.x, sv.x, acc);
        acc = fmaf(wvv.y, sv.y, acc);
        acc = fmaf(wvv.z, sv.z, acc);
        acc = fmaf(wvv.w, sv.w, acc);
    }
    outq[(size_t)bk * 256 + tid] = acc;
}

// ---------------------------------------------------------------- launcher
extern "C" void kernel_launch(void* const* d_in, const int* in_sizes, int n_in,
                              void* d_out, int out_size, void* d_ws, size_t ws_size,
                              hipStream_t stream) {
    const float* in_key      = (const float*)d_in[0];
    const float* in_query    = (const float*)d_in[1];
    const float* key_xyz     = (const float*)d_in[2];
    const float* query_xyz   = (const float*)d_in[3];
    const float* query_size  = (const float*)d_in[4];
    const float* query_angle = (const float*)d_in[5];
    const float* Wkey        = (const float*)d_in[6];
    const float* conv_w      = (const float*)d_in[7];
    const float* conv_b      = (const float*)d_in[8];
    const float* convb_w     = (const float*)d_in[9];
    const float* convb_b     = (const float*)d_in[10];
    const float* Wq          = (const float*)d_in[11];
    const float* Wbc         = (const float*)d_in[12];
    const float* Wdt         = (const float*)d_in[13];
    const float* dt_bias     = (const float*)d_in[14];
    const float* A_log       = (const float*)d_in[15];
    const float* Dp          = (const float*)d_in[16];
    const float* Wok         = (const float*)d_in[17];
    const float* Woq         = (const float*)d_in[18];
    const float* key_norm_w  = (const float*)d_in[19];
    const float* ln_w        = (const float*)d_in[20];
    const float* ln_b        = (const float*)d_in[21];
    const float* cpb_w1      = (const float*)d_in[22];
    const float* cpb_b1      = (const float*)d_in[23];
    const float* cpb_w2      = (const float*)d_in[24];
    float* out = (float*)d_out;

    float* wsf = (float*)d_ws;
    float* zx    = wsf + 0;         // 2048*1034
    float* xf    = wsf + 2117632;   // 2048*514
    float* xb    = wsf + 3170304;   // 2048*514
    float* tbl   = wsf + 4222976;   // 4000
    float* cbuf  = wsf + 4226976;   // 2*1024*8
    float* Pbuf  = wsf + 4243360;   // 2*8*16*128
    float* dAa   = wsf + 5291936;   // 2*8*1024*128
    float* dBf   = wsf + 7389088;
    float* dBb   = wsf + 9486240;
    float* Cfb   = wsf + 11583392;  // 2*1024*128
    float* Cbb   = wsf + 11845536;
    float* h0b   = wsf + 12107680;  // 256*512
    float* yfb   = wsf + 12238752;  // 2048*512
    float* ybb   = wsf + 13287328;
    float* hfin  = wsf + 14335904;  // 2*2*8*64*128
    float* gated = wsf + 14598048;  // 2048*512
    float* Sbuf  = wsf + 15646624;  // 4,194,304 floats

    front_k<<<588, 256, 0, stream>>>(in_key, Wkey, zx, in_query, Wq, h0b,
                                     query_xyz, query_size, query_angle,
                                     cpb_w1, cpb_b1, cpb_w2, cbuf, tbl);
    dwconv_silu<<<dim3(2048, 3), 256, 0, stream>>>(zx, ZCOLS, 512, conv_w, conv_b, xf);
    dwconv_silu<<<dim3(2048, 3), 256, 0, stream>>>(xf, CC, 0, convb_w, convb_b, xb);
    geo_k<<<2048, 128, 0, stream>>>(key_xyz, cbuf, tbl, zx, xf, xb,
                                    Wbc, Wdt, dt_bias, A_log,
                                    dAa, dBf, dBb, Cfb, Cbb);
    scan_part6<<<512, 256, 0, stream>>>(dAa, dBf, dBb, Cfb, Cbb, xf, xb,
                                        Sbuf, Pbuf, yfb, ybb);
    scan_combine<<<128, 256, 0, stream>>>(h0b, Sbuf, Pbuf, hfin);
    scan_corr<<<512, 256, 0, stream>>>(dAa, Cfb, Cbb, Sbuf, yfb, ybb);
    gated_k<<<2048, 256, 0, stream>>>(yfb, ybb, xf, zx, Dp, key_norm_w, gated);
    final_k<<<384, 256, 0, stream>>>(gated, Wok, out, hfin, ln_w, ln_b, Woq,
                                     out + 524288);
}

// Round 15
// 193.936 us; speedup vs baseline: 1.1328x; 1.0438x over previous
//
#include <hip/hip_runtime.h>
#include <math.h>

#define B_ 2
#define L_ 1024
#define K_ 128
#define DM 256
#define DI 512
#define NH 8
#define HD 64
#define CC 514
#define ZCOLS 1034
#define NC 16
#define TC 64

// ---------------------------------------------------------------- utilities
__device__ __forceinline__ float wave_sum(float v) {
    v += __shfl_xor(v, 1);  v += __shfl_xor(v, 2);  v += __shfl_xor(v, 4);
    v += __shfl_xor(v, 8);  v += __shfl_xor(v, 16); v += __shfl_xor(v, 32);
    return v;
}

// sum across each 16-lane DPP row via row_ror — VALU pipe, NOT the DS pipe.
__device__ __forceinline__ float dpp_row_reduce16(float v) {
    int t;
    t = __builtin_amdgcn_update_dpp(0, __float_as_int(v), 0x128, 0xF, 0xF, true); // row_ror:8
    v += __int_as_float(t);
    t = __builtin_amdgcn_update_dpp(0, __float_as_int(v), 0x124, 0xF, 0xF, true); // row_ror:4
    v += __int_as_float(t);
    t = __builtin_amdgcn_update_dpp(0, __float_as_int(v), 0x122, 0xF, 0xF, true); // row_ror:2
    v += __int_as_float(t);
    t = __builtin_amdgcn_update_dpp(0, __float_as_int(v), 0x121, 0xF, 0xF, true); // row_ror:1
    v += __int_as_float(t);
    return v;
}

__device__ __forceinline__ float silu_f(float x) {
    return x / (1.f + expf(-x));
}

// ---------------------------------------------------------------- pipelined NT GEMM (device body)
// C[M][N] = sum_k A[M][K] * B[N][K]; one barrier per k-tile (staging writes go to
// the OTHER LDS buffer, so no pre-write barrier needed).
__device__ void gemm_dev(const float* __restrict__ A, const float* __restrict__ Bm,
                         float* __restrict__ C, int M, int N, int K, int bm, int bn) {
    __shared__ float As[2][16][68];
    __shared__ float Bs[2][16][68];
    const int tid = threadIdx.x;
    const int sr = tid >> 2;          // stage row 0..63
    const int sk = (tid & 3) * 4;     // stage k 0,4,8,12
    const int tx = tid & 15, ty = tid >> 4;
    const int NT = K >> 4;
    const float* Arow = A + (size_t)(bm + sr) * K + sk;
    const float* Brow = Bm + (size_t)(bn + sr) * K + sk;
    const bool bok = (bn + sr) < N;

    float4 av = *(const float4*)Arow;
    float4 bv = bok ? *(const float4*)Brow : make_float4(0.f, 0.f, 0.f, 0.f);
    As[0][sk + 0][sr] = av.x; As[0][sk + 1][sr] = av.y;
    As[0][sk + 2][sr] = av.z; As[0][sk + 3][sr] = av.w;
    Bs[0][sk + 0][sr] = bv.x; Bs[0][sk + 1][sr] = bv.y;
    Bs[0][sk + 2][sr] = bv.z; Bs[0][sk + 3][sr] = bv.w;
    __syncthreads();

    float acc[4][4] = {};
    for (int t = 0; t < NT; ++t) {
        if (t + 1 < NT) {             // issue next tile's loads early
            av = *(const float4*)(Arow + (t + 1) * 16);
            bv = bok ? *(const float4*)(Brow + (t + 1) * 16) : make_float4(0.f, 0.f, 0.f, 0.f);
        }
        const int bi = t & 1;
#pragma unroll
        for (int kk = 0; kk < 16; ++kk) {
            float4 a = *(const float4*)&As[bi][kk][ty * 4];
            float4 b = *(const float4*)&Bs[bi][kk][tx * 4];
            acc[0][0] = fmaf(a.x, b.x, acc[0][0]); acc[0][1] = fmaf(a.x, b.y, acc[0][1]);
            acc[0][2] = fmaf(a.x, b.z, acc[0][2]); acc[0][3] = fmaf(a.x, b.w, acc[0][3]);
            acc[1][0] = fmaf(a.y, b.x, acc[1][0]); acc[1][1] = fmaf(a.y, b.y, acc[1][1]);
            acc[1][2] = fmaf(a.y, b.z, acc[1][2]); acc[1][3] = fmaf(a.y, b.w, acc[1][3]);
            acc[2][0] = fmaf(a.z, b.x, acc[2][0]); acc[2][1] = fmaf(a.z, b.y, acc[2][1]);
            acc[2][2] = fmaf(a.z, b.z, acc[2][2]); acc[2][3] = fmaf(a.z, b.w, acc[2][3]);
            acc[3][0] = fmaf(a.w, b.x, acc[3][0]); acc[3][1] = fmaf(a.w, b.y, acc[3][1]);
            acc[3][2] = fmaf(a.w, b.z, acc[3][2]); acc[3][3] = fmaf(a.w, b.w, acc[3][3]);
        }
        if (t + 1 < NT) {             // write OTHER buffer; safe before barrier
            const int ni = (t + 1) & 1;
            As[ni][sk + 0][sr] = av.x; As[ni][sk + 1][sr] = av.y;
            As[ni][sk + 2][sr] = av.z; As[ni][sk + 3][sr] = av.w;
            Bs[ni][sk + 0][sr] = bv.x; Bs[ni][sk + 1][sr] = bv.y;
            Bs[ni][sk + 2][sr] = bv.z; Bs[ni][sk + 3][sr] = bv.w;
        }
        __syncthreads();              // single barrier per tile
    }
    // epilogue: float2 stores (N=1034 rows are only 8B-aligned)
#pragma unroll
    for (int i = 0; i < 4; ++i) {
        int m = bm + ty * 4 + i;
        int n0 = bn + tx * 4;
        if (n0 + 3 < N) {
            float* cp = &C[(size_t)m * N + n0];
            *(float2*)cp = make_float2(acc[i][0], acc[i][1]);
            *(float2*)(cp + 2) = make_float2(acc[i][2], acc[i][3]);
        } else {
#pragma unroll
            for (int j = 0; j < 4; ++j)
                if (n0 + j < N) C[(size_t)m * N + n0 + j] = acc[i][j];
        }
    }
}

// ---------------------------------------------------------------- front: zx GEMM + h0 GEMM + setup
__global__ __launch_bounds__(256, 4) void front_k(
    const float* __restrict__ in_key, const float* __restrict__ Wkey, float* __restrict__ zx,
    const float* __restrict__ in_query, const float* __restrict__ Wq, float* __restrict__ h0b,
    const float* __restrict__ qxyz, const float* __restrict__ qsize,
    const float* __restrict__ qang, const float* __restrict__ w1,
    const float* __restrict__ b1, const float* __restrict__ w2,
    float* __restrict__ cb, float* __restrict__ tbl) {
    int bid = blockIdx.x, tid = threadIdx.x;
    if (bid < 544) {
        gemm_dev(in_key, Wkey, zx, 2048, ZCOLS, 256, (bid & 31) * 64, (bid >> 5) * 64);
    } else if (bid < 576) {
        int r = bid - 544;
        gemm_dev(in_query, Wq, h0b, 256, 512, 256, (r & 3) * 64, (r >> 2) * 64);
    } else if (bid < 584) {
        int idx = (bid - 576) * 256 + tid;    // < 2048 = B_*K_*8
        int b = idx >> 10;
        int q = idx & 1023;
        int k = q >> 3;
        int c = q & 7;
        const float sx[8] = {1, 1, -1, -1, 1, 1, -1, -1};
        const float sy[8] = {1, 1, 1, 1, -1, -1, -1, -1};
        const float sz[8] = {1, -1, -1, 1, 1, -1, -1, 1};
        float cx = qxyz[(b * K_ + k) * 3 + 0];
        float cy = qxyz[(b * K_ + k) * 3 + 1];
        float cz = qxyz[(b * K_ + k) * 3 + 2];
        float lv = qsize[(b * K_ + k) * 3 + 0];
        float wv = qsize[(b * K_ + k) * 3 + 1];
        float hv = qsize[(b * K_ + k) * 3 + 2];
        float ang = qang[b * K_ + k];
        float ca = cosf(ang), sa = sinf(ang);
        float ccx = cx, ccy = -cz, ccz = cy;
        float l0 = lv * sx[c] * 0.5f;
        float l1 = hv * sy[c] * 0.5f;
        float l2 = wv * sz[c] * 0.5f;
        float m0 = ca * l0 + sa * l2 + ccx;
        float m1 = l1 + ccy;
        float m2 = -sa * l0 + ca * l2 + ccz;
        // rotation for the distance transform uses angle[b, q % K] (jnp.tile semantics)
        float angr = qang[b * K_ + (q & (K_ - 1))];
        float4* o = (float4*)(cb + (size_t)idx * 8);
        o[0] = make_float4(m0, m2, -m1, cosf(angr));
        o[1] = make_float4(sinf(angr), 0.f, 0.f, 0.f);
    } else {
        int p = (bid - 584) * 256 + tid;
        if (p >= 1000) return;
        int i = p / 100, j = (p / 10) % 10, k = p % 10;
        float c0 = (8.f / 9.f) * i - 4.f;
        float c1 = (8.f / 9.f) * j - 4.f;
        float c2 = (8.f / 9.f) * k - 4.f;
        float a0 = 0.f, a1 = 0.f, a2 = 0.f, a3 = 0.f;
        for (int m = 0; m < 128; ++m) {
            float t = fmaf(c0, w1[m * 3 + 0], fmaf(c1, w1[m * 3 + 1], fmaf(c2, w1[m * 3 + 2], b1[m])));
            t = fmaxf(t, 0.f);
            a0 = fmaf(t, w2[m], a0);
            a1 = fmaf(t, w2[128 + m], a1);
            a2 = fmaf(t, w2[256 + m], a2);
            a3 = fmaf(t, w2[384 + m], a3);
        }
        tbl[p * 4 + 0] = a0; tbl[p * 4 + 1] = a1;
        tbl[p * 4 + 2] = a2; tbl[p * 4 + 3] = a3;
    }
}

// ---------------------------------------------------------------- depthwise conv7 + silu (2 rows/block)
// grid (1024, 3): block handles rows (2*bid, 2*bid+1) — same batch (L even).
// Shared loads: L[i] = row0 tap i; row1 tap j uses L[j+1]. OOB loads zeroed (== skip).
__global__ void dwconv_silu(const float* __restrict__ xin, int in_stride, int in_off,
                            const float* __restrict__ w, const float* __restrict__ bias,
                            float* __restrict__ out) {
    int c = blockIdx.y * blockDim.x + threadIdx.x;
    if (c >= CC) return;
    int row0 = blockIdx.x * 2;            // b*L + l, l even
    int l0 = row0 & (L_ - 1);
    const float* xr = xin + (size_t)row0 * in_stride + in_off + c;
    float Lv[8];
#pragma unroll
    for (int i = 0; i < 8; ++i) {
        int ll = l0 + i - 3;
        Lv[i] = (ll >= 0 && ll < L_) ? xr[(ptrdiff_t)(i - 3) * in_stride] : 0.f;
    }
    float acc0 = bias[c], acc1 = bias[c];
#pragma unroll
    for (int j = 0; j < 7; ++j) {
        float wj = w[c * 7 + j];
        acc0 = fmaf(Lv[j], wj, acc0);
        acc1 = fmaf(Lv[j + 1], wj, acc1);
    }
    out[(size_t)row0 * CC + c] = silu_f(acc0);
    out[(size_t)(row0 + 1) * CC + c] = silu_f(acc1);
}

// ---------------------------------------------------------------- fused dist + dA/dB/C
__global__ __launch_bounds__(128) void geo_k(
    const float* __restrict__ kxyz, const float* __restrict__ cb,
    const float* __restrict__ tbl, const float* __restrict__ zx,
    const float* __restrict__ xf, const float* __restrict__ xb,
    const float* __restrict__ wbc, const float* __restrict__ wdt,
    const float* __restrict__ dtb, const float* __restrict__ alog,
    float* __restrict__ dA, float* __restrict__ dBf, float* __restrict__ dBb,
    float* __restrict__ Cf, float* __restrict__ Cb) {
    __shared__ float t_s[4000];
    int row = blockIdx.x;                 // b*L + l
    int b = row >> 10;
    int l = row & 1023;
    int k = threadIdx.x;
    for (int i = threadIdx.x; i < 4000; i += 128) t_s[i] = tbl[i];
    __syncthreads();
    float kx = kxyz[(size_t)row * 3 + 0];
    float ky = kxyz[(size_t)row * 3 + 1];
    float kz = kxyz[(size_t)row * 3 + 2];
    float acc0 = 0.f, acc1 = 0.f, acc2 = 0.f, acc3 = 0.f;
#pragma unroll
    for (int c = 0; c < 8; ++c) {
        int q = k * 8 + c;
        const float4* p = (const float4*)(cb + (size_t)(b * 1024 + q) * 8);
        float4 v0 = p[0], v1 = p[1];
        float d0 = v0.x - kx, d1 = v0.y - ky, d2 = v0.z - kz;
        float rc = v0.w, rs = v1.x;
        float e0 = d0, e1 = -d2, e2 = d1;
        float f0 = rc * e0 - rs * e2;
        float f1 = e1;
        float f2 = rs * e0 + rc * e2;
        float g0 = f0, g1 = f2, g2 = -f1;
        g0 = copysignf(log2f(fabsf(g0) * 512.f + 1.f) * (1.f / 12.f), g0);
        g1 = copysignf(log2f(fabsf(g1) * 512.f + 1.f) * (1.f / 12.f), g1);
        g2 = copysignf(log2f(fabsf(g2) * 512.f + 1.f) * (1.f / 12.f), g2);
        // table axis0 <- g2, axis1 <- g1, axis2 <- g0
        float iq = 5.f * g2 + 4.5f;
        float jq = 5.f * g1 + 4.5f;
        float kq = 5.f * g0 + 4.5f;
        float i0f = floorf(iq), j0f = floorf(jq), k0f = floorf(kq);
        float wi = iq - i0f, wj = jq - j0f, wk = kq - k0f;
        int i0 = (int)i0f, j0 = (int)j0f, k0 = (int)k0f;
#pragma unroll
        for (int a = 0; a < 2; ++a) {
#pragma unroll
            for (int bb = 0; bb < 2; ++bb) {
#pragma unroll
                for (int cc = 0; cc < 2; ++cc) {
                    int ii = i0 + a, jj = j0 + bb, kk = k0 + cc;
                    if ((unsigned)ii < 10u && (unsigned)jj < 10u && (unsigned)kk < 10u) {
                        float wgt = (a ? wi : 1.f - wi) * (bb ? wj : 1.f - wj) * (cc ? wk : 1.f - wk);
                        const float* tp = &t_s[((ii * 10 + jj) * 10 + kk) * 4];
                        acc0 = fmaf(wgt, tp[0], acc0);
                        acc1 = fmaf(wgt, tp[1], acc1);
                        acc2 = fmaf(wgt, tp[2], acc2);
                        acc3 = fmaf(wgt, tp[3], acc3);
                    }
                }
            }
        }
    }
    // ---- fused precomp tail
    float B0 = acc0 * wbc[0] + acc1 * wbc[1] + acc2 * wbc[2] + acc3 * wbc[3];
    float C0 = acc0 * wbc[4] + acc1 * wbc[5] + acc2 * wbc[6] + acc3 * wbc[7];
    float bbf = xf[(size_t)row * CC + 512], cbf = xf[(size_t)row * CC + 513];
    float bbb = xb[(size_t)row * CC + 512], cbb = xb[(size_t)row * CC + 513];
    Cf[(size_t)row * K_ + k] = C0 + cbf;
    Cb[(size_t)row * K_ + k] = C0 + cbb;
    float Bf = B0 + bbf, Bb = B0 + bbb;
#pragma unroll
    for (int hh = 0; hh < NH; ++hh) {
        float s = acc0 * wdt[hh * 4 + 0] + acc1 * wdt[hh * 4 + 1] +
                  acc2 * wdt[hh * 4 + 2] + acc3 * wdt[hh * 4 + 3];
        s += zx[(size_t)row * ZCOLS + 1026 + hh] + dtb[hh];
        float dtv = (s > 20.f) ? s : log1pf(expf(s));
        float Av = -expf(alog[hh]);
        size_t o = ((size_t)(b * NH + hh) * L_ + l) * K_ + k;
        dA[o] = expf(dtv * Av);
        dBf[o] = dtv * Bf;
        dBb[o] = dtv * Bb;
    }
}

// ---------------------------------------------------------------- chunked ISSM scan, LDS-fed
// block = 256 thr (4 waves) = one (dir,b,hh,chunk); lane owns 8 k x 4 d.
// dir==0 blocks also carry the chunk cumprod P. One barrier per 8-step tile.
// Pipeline: a/b looked-ahead 2 steps (h-critical path), c/x 1 step — the 1-step
// scheme left a/b exposed to queued-LDS latency (~300cy > one step's ~250cy VALU).
__global__ __launch_bounds__(256) void scan_part6(
    const float* __restrict__ dA, const float* __restrict__ dBf, const float* __restrict__ dBb,
    const float* __restrict__ Cf, const float* __restrict__ Cb,
    const float* __restrict__ xf, const float* __restrict__ xb,
    float* __restrict__ Sbuf, float* __restrict__ Pbuf,
    float* __restrict__ yf, float* __restrict__ yb) {
    __shared__ float lds[2][3584];
    int bid = blockIdx.x;
    int c = bid & 15;
    int hh = (bid >> 4) & 7;
    int b = (bid >> 7) & 1;
    int dir = bid >> 8;
    int tid = threadIdx.x;             // 0..255
    int lane = tid & 63;
    int w = tid >> 6;                  // 0..3
    int dg = lane >> 4, kg = lane & 15;
    int dloc = w * 4 + dg;             // 0..15; lane owns d = dloc + 16*{0,1,2,3}
    int klo = kg * 4, khi = 64 + kg * 4;

    const float* Bsrc = dir ? dBb : dBf;
    const float* Csrc = dir ? Cb : Cf;
    const float* Xsrc = dir ? xb : xf;
    float* Ydst = dir ? yb : yf;
    int t0 = dir ? (L_ - 1 - c * TC) : c * TC;
    int stp = dir ? -1 : 1;

    const float* Abase = dA + ((size_t)(b * NH + hh) * L_) * K_;
    const float* Bbase = Bsrc + ((size_t)(b * NH + hh) * L_) * K_;
    const float* Cbase = Csrc + ((size_t)b * L_) * K_;
    const float* Xbase = Xsrc + ((size_t)b * L_) * CC + hh * HD;

    const bool hasx = (tid < 128);

    auto gaddr = [&](int v, int tb) -> const float* {
        if (v < 768) {
            int r = (v >> 5) & 7;
            int c4 = v & 31;
            int l = t0 + stp * (tb + r);
            const float* base = (v < 256) ? Abase : ((v < 512) ? Bbase : Cbase);
            return base + (size_t)l * K_ + c4 * 4;
        } else {
            int vv = v - 768;
            int r = vv >> 4, c4 = vv & 15;
            int l = t0 + stp * (tb + r);
            return Xbase + (size_t)l * CC + c4 * 4;
        }
    };

    float hA[8] = {0, 0, 0, 0, 0, 0, 0, 0};
    float hB[8] = {0, 0, 0, 0, 0, 0, 0, 0};
    float hC[8] = {0, 0, 0, 0, 0, 0, 0, 0};
    float hD[8] = {0, 0, 0, 0, 0, 0, 0, 0};
    float cum[8] = {1, 1, 1, 1, 1, 1, 1, 1};

    // prologue: stage tile 0 into buf 0
    float4 rA = *(const float4*)gaddr(tid, 0);
    float4 rB = *(const float4*)gaddr(256 + tid, 0);
    float4 rC = *(const float4*)gaddr(512 + tid, 0);
    float4 rX = hasx ? *(const float4*)gaddr(768 + tid, 0) : make_float4(0, 0, 0, 0);
    *(float4*)&lds[0][4 * tid] = rA;
    *(float4*)&lds[0][1024 + 4 * tid] = rB;
    *(float4*)&lds[0][2048 + 4 * tid] = rC;
    if (hasx) *(float4*)&lds[0][3072 + 4 * tid] = rX;
    __syncthreads();

    float* pY = Ydst + ((size_t)(b * L_ + t0)) * DI + hh * HD + dloc;
    const ptrdiff_t dY = (ptrdiff_t)stp * DI;

    for (int it = 0; it < TC / 8; ++it) {
        int tb = it * 8;
        if (it < TC / 8 - 1) {           // issue next tile's global loads early
            rA = *(const float4*)gaddr(tid, tb + 8);
            rB = *(const float4*)gaddr(256 + tid, tb + 8);
            rC = *(const float4*)gaddr(512 + tid, tb + 8);
            if (hasx) rX = *(const float4*)gaddr(768 + tid, tb + 8);
        }
        const float* Lb = lds[it & 1];
        // tile prologue: st=0 full operands + st=1 a/b
        float4 aC0 = *(const float4*)&Lb[klo];
        float4 aC1 = *(const float4*)&Lb[khi];
        float4 bC0 = *(const float4*)&Lb[1024 + klo];
        float4 bC1 = *(const float4*)&Lb[1024 + khi];
        float4 cC0 = *(const float4*)&Lb[2048 + klo];
        float4 cC1 = *(const float4*)&Lb[2048 + khi];
        float x0 = Lb[3072 + dloc];
        float x1 = Lb[3072 + 16 + dloc];
        float x2 = Lb[3072 + 32 + dloc];
        float x3 = Lb[3072 + 48 + dloc];
        float4 aN0 = *(const float4*)&Lb[128 + klo];
        float4 aN1 = *(const float4*)&Lb[128 + khi];
        float4 bN0 = *(const float4*)&Lb[1024 + 128 + klo];
        float4 bN1 = *(const float4*)&Lb[1024 + 128 + khi];
#pragma unroll
        for (int st = 0; st < 8; ++st) {
            float4 aF0, aF1, bF0, bF1, cN0, cN1;
            float nx0 = 0.f, nx1 = 0.f, nx2 = 0.f, nx3 = 0.f;
            if (st < 6) {                // a/b for st+2 (h-critical, deepest lookahead)
                int o = (st + 2) * 128;
                aF0 = *(const float4*)&Lb[o + klo];
                aF1 = *(const float4*)&Lb[o + khi];
                bF0 = *(const float4*)&Lb[1024 + o + klo];
                bF1 = *(const float4*)&Lb[1024 + o + khi];
            }
            if (st < 7) {                // c/x for st+1
                int o = (st + 1) * 128;
                cN0 = *(const float4*)&Lb[2048 + o + klo];
                cN1 = *(const float4*)&Lb[2048 + o + khi];
                int xo = 3072 + (st + 1) * 64 + dloc;
                nx0 = Lb[xo]; nx1 = Lb[xo + 16]; nx2 = Lb[xo + 32]; nx3 = Lb[xo + 48];
            }
            cum[0] *= aC0.x; cum[1] *= aC0.y; cum[2] *= aC0.z; cum[3] *= aC0.w;
            cum[4] *= aC1.x; cum[5] *= aC1.y; cum[6] *= aC1.z; cum[7] *= aC1.w;
            float u0, u1, u2, u3;
            // d-block A (x0)
            hA[0] = fmaf(hA[0], aC0.x, x0 * bC0.x); u0 = hA[0] * cC0.x;
            hA[1] = fmaf(hA[1], aC0.y, x0 * bC0.y); u1 = hA[1] * cC0.y;
            hA[2] = fmaf(hA[2], aC0.z, x0 * bC0.z); u2 = hA[2] * cC0.z;
            hA[3] = fmaf(hA[3], aC0.w, x0 * bC0.w); u3 = hA[3] * cC0.w;
            hA[4] = fmaf(hA[4], aC1.x, x0 * bC1.x); u0 = fmaf(hA[4], cC1.x, u0);
            hA[5] = fmaf(hA[5], aC1.y, x0 * bC1.y); u1 = fmaf(hA[5], cC1.y, u1);
            hA[6] = fmaf(hA[6], aC1.z, x0 * bC1.z); u2 = fmaf(hA[6], cC1.z, u2);
            hA[7] = fmaf(hA[7], aC1.w, x0 * bC1.w); u3 = fmaf(hA[7], cC1.w, u3);
            float rrA = dpp_row_reduce16((u0 + u1) + (u2 + u3));
            // d-block B (x1)
            hB[0] = fmaf(hB[0], aC0.x, x1 * bC0.x); u0 = hB[0] * cC0.x;
            hB[1] = fmaf(hB[1], aC0.y, x1 * bC0.y); u1 = hB[1] * cC0.y;
            hB[2] = fmaf(hB[2], aC0.z, x1 * bC0.z); u2 = hB[2] * cC0.z;
            hB[3] = fmaf(hB[3], aC0.w, x1 * bC0.w); u3 = hB[3] * cC0.w;
            hB[4] = fmaf(hB[4], aC1.x, x1 * bC1.x); u0 = fmaf(hB[4], cC1.x, u0);
            hB[5] = fmaf(hB[5], aC1.y, x1 * bC1.y); u1 = fmaf(hB[5], cC1.y, u1);
            hB[6] = fmaf(hB[6], aC1.z, x1 * bC1.z); u2 = fmaf(hB[6], cC1.z, u2);
            hB[7] = fmaf(hB[7], aC1.w, x1 * bC1.w); u3 = fmaf(hB[7], cC1.w, u3);
            float rrB = dpp_row_reduce16((u0 + u1) + (u2 + u3));
            // d-block C (x2)
            hC[0] = fmaf(hC[0], aC0.x, x2 * bC0.x); u0 = hC[0] * cC0.x;
            hC[1] = fmaf(hC[1], aC0.y, x2 * bC0.y); u1 = hC[1] * cC0.y;
            hC[2] = fmaf(hC[2], aC0.z, x2 * bC0.z); u2 = hC[2] * cC0.z;
            hC[3] = fmaf(hC[3], aC0.w, x2 * bC0.w); u3 = hC[3] * cC0.w;
            hC[4] = fmaf(hC[4], aC1.x, x2 * bC1.x); u0 = fmaf(hC[4], cC1.x, u0);
            hC[5] = fmaf(hC[5], aC1.y, x2 * bC1.y); u1 = fmaf(hC[5], cC1.y, u1);
            hC[6] = fmaf(hC[6], aC1.z, x2 * bC1.z); u2 = fmaf(hC[6], cC1.z, u2);
            hC[7] = fmaf(hC[7], aC1.w, x2 * bC1.w); u3 = fmaf(hC[7], cC1.w, u3);
            float rrC = dpp_row_reduce16((u0 + u1) + (u2 + u3));
            // d-block D (x3)
            hD[0] = fmaf(hD[0], aC0.x, x3 * bC0.x); u0 = hD[0] * cC0.x;
            hD[1] = fmaf(hD[1], aC0.y, x3 * bC0.y); u1 = hD[1] * cC0.y;
            hD[2] = fmaf(hD[2], aC0.z, x3 * bC0.z); u2 = hD[2] * cC0.z;
            hD[3] = fmaf(hD[3], aC0.w, x3 * bC0.w); u3 = hD[3] * cC0.w;
            hD[4] = fmaf(hD[4], aC1.x, x3 * bC1.x); u0 = fmaf(hD[4], cC1.x, u0);
            hD[5] = fmaf(hD[5], aC1.y, x3 * bC1.y); u1 = fmaf(hD[5], cC1.y, u1);
            hD[6] = fmaf(hD[6], aC1.z, x3 * bC1.z); u2 = fmaf(hD[6], cC1.z, u2);
            hD[7] = fmaf(hD[7], aC1.w, x3 * bC1.w); u3 = fmaf(hD[7], cC1.w, u3);
            float rrD = dpp_row_reduce16((u0 + u1) + (u2 + u3));
            if (kg == 0) { pY[0] = rrA; pY[16] = rrB; pY[32] = rrC; pY[48] = rrD; }
            pY += dY;
            if (st < 7) {                // rotate generations
                aC0 = aN0; aC1 = aN1; bC0 = bN0; bC1 = bN1;
                cC0 = cN0; cC1 = cN1;
                x0 = nx0; x1 = nx1; x2 = nx2; x3 = nx3;
                if (st < 6) { aN0 = aF0; aN1 = aF1; bN0 = bF0; bN1 = bF1; }
            }
        }
        if (it < TC / 8 - 1) {           // write OTHER buffer; safe before barrier
            *(float4*)&lds[(it + 1) & 1][4 * tid] = rA;
            *(float4*)&lds[(it + 1) & 1][1024 + 4 * tid] = rB;
            *(float4*)&lds[(it + 1) & 1][2048 + 4 * tid] = rC;
            if (hasx) *(float4*)&lds[(it + 1) & 1][3072 + 4 * tid] = rX;
        }
        __syncthreads();                 // single barrier per tile
    }

    int ibh = (dir * B_ + b) * NH + hh;
    {
        float* Sp = Sbuf + (((size_t)ibh * NC + c) * HD + dloc) * K_;
        *(float4*)(Sp + klo) = make_float4(hA[0], hA[1], hA[2], hA[3]);
        *(float4*)(Sp + khi) = make_float4(hA[4], hA[5], hA[6], hA[7]);
        Sp += (size_t)16 * K_;
        *(float4*)(Sp + klo) = make_float4(hB[0], hB[1], hB[2], hB[3]);
        *(float4*)(Sp + khi) = make_float4(hB[4], hB[5], hB[6], hB[7]);
        Sp += (size_t)16 * K_;
        *(float4*)(Sp + klo) = make_float4(hC[0], hC[1], hC[2], hC[3]);
        *(float4*)(Sp + khi) = make_float4(hC[4], hC[5], hC[6], hC[7]);
        Sp += (size_t)16 * K_;
        *(float4*)(Sp + klo) = make_float4(hD[0], hD[1], hD[2], hD[3]);
        *(float4*)(Sp + khi) = make_float4(hD[4], hD[5], hD[6], hD[7]);
    }
    if (dir == 0 && tid < 16) {          // w==0, dg==0, kg==tid: cum identical across d
        float* Pp = Pbuf + ((size_t)((b * NH + hh) * NC + c)) * K_;
        *(float4*)(Pp + klo) = make_float4(cum[0], cum[1], cum[2], cum[3]);
        *(float4*)(Pp + khi) = make_float4(cum[4], cum[5], cum[6], cum[7]);
    }
}

// phase 2: sequential combine across NC chunks; overwrites Sbuf with incoming state Hin;
// writes final state hfin. grid = 128 x 256
__global__ __launch_bounds__(256) void scan_combine(
    const float* __restrict__ h0buf, float* __restrict__ Sbuf,
    const float* __restrict__ Pbuf, float* __restrict__ hfin) {
    int bid = blockIdx.x;
    int dq = bid & 3;
    int hh = (bid >> 2) & 7;
    int b = (bid >> 5) & 1;
    int dir = bid >> 6;
    int tid = threadIdx.x;
    int w = tid >> 6;
    int lane = tid & 63;
    int dsl = dq * 4 + w;
    int dg = lane >> 4, kg = lane & 15;
    int d = dsl * 4 + dg;
    int k0 = kg * 8;

    float H[8];
#pragma unroll
    for (int j = 0; j < 8; ++j)
        H[j] = h0buf[(size_t)(b * K_ + k0 + j) * DI + hh * HD + d];

    int ibh = (dir * B_ + b) * NH + hh;
    for (int c = 0; c < NC; ++c) {
        float* Sp = Sbuf + (((size_t)ibh * NC + c) * HD + d) * K_ + k0;
        int cF = dir ? (NC - 1 - c) : c;   // P computed on fwd chunk row-sets
        const float* Pp = Pbuf + ((size_t)((b * NH + hh) * NC + cF)) * K_ + k0;
        float4 sA = *(const float4*)(Sp + 0);
        float4 sB = *(const float4*)(Sp + 4);
        float4 pA = *(const float4*)(Pp + 0);
        float4 pB = *(const float4*)(Pp + 4);
        // store incoming state for this chunk (overwrites S)
        *(float4*)(Sp + 0) = make_float4(H[0], H[1], H[2], H[3]);
        *(float4*)(Sp + 4) = make_float4(H[4], H[5], H[6], H[7]);
        H[0] = fmaf(H[0], pA.x, sA.x); H[1] = fmaf(H[1], pA.y, sA.y);
        H[2] = fmaf(H[2], pA.z, sA.z); H[3] = fmaf(H[3], pA.w, sA.w);
        H[4] = fmaf(H[4], pB.x, sB.x); H[5] = fmaf(H[5], pB.y, sB.y);
        H[6] = fmaf(H[6], pB.z, sB.z); H[7] = fmaf(H[7], pB.w, sB.w);
    }
    float* hf = hfin + ((((size_t)dir * B_ + b) * NH + hh) * HD + d) * K_ + k0;
    *(float4*)(hf + 0) = make_float4(H[0], H[1], H[2], H[3]);
    *(float4*)(hf + 4) = make_float4(H[4], H[5], H[6], H[7]);
}

// phase 3: y[t,d] += sum_k C[t,k]*cumA[t,k] * Hin[k,d]  (64x64x128 GEMM per instance)
#define CP 72
#define WSWZ(k) ((((k) >> 3) & 3) << 2)
__global__ __launch_bounds__(256) void scan_corr(
    const float* __restrict__ dA, const float* __restrict__ Cf, const float* __restrict__ Cb,
    const float* __restrict__ Sbuf, float* __restrict__ yf, float* __restrict__ yb) {
    __shared__ float Wl[128][CP];   // [k][t] (t XOR-swizzled by WSWZ(k))
    __shared__ float Hl[128][CP];   // [k][d]
    int iid = blockIdx.x;
    int c = iid & 15;
    int hh = (iid >> 4) & 7;
    int b = (iid >> 7) & 1;
    int dir = iid >> 8;
    int tid = threadIdx.x;
    const float* Csrc = dir ? Cb : Cf;

    // phase A: W[k][t] = C[l(t),k] * cumA(t,k), scan order
    if (tid < 128) {
        int k = tid;
        float cum = 1.f;
        const float* pA = dA + ((size_t)(b * NH + hh) * L_) * K_ + k;
        const float* pC = Csrc + ((size_t)b * L_) * K_ + k;
        int sw = WSWZ(k);
#pragma unroll 4
        for (int t = 0; t < TC; ++t) {
            int l = dir ? (L_ - 1 - (c * TC + t)) : (c * TC + t);
            cum *= pA[(size_t)l * K_];
            Wl[k][t ^ sw] = cum * pC[(size_t)l * K_];
        }
    }
    // phase B: Hin [k][d] (transposed stage from Sbuf [d][k])
    {
        int d = tid & 63, kq = tid >> 6;   // kq 0..3
        int ibh = (dir * B_ + b) * NH + hh;
        const float* Hp = Sbuf + (((size_t)ibh * NC + c) * HD + d) * K_;
#pragma unroll
        for (int i = 0; i < 8; ++i) {
            int q = kq * 8 + i;            // float4 index 0..31
            float4 v = *(const float4*)(Hp + q * 4);
            Hl[q * 4 + 0][d] = v.x; Hl[q * 4 + 1][d] = v.y;
            Hl[q * 4 + 2][d] = v.z; Hl[q * 4 + 3][d] = v.w;
        }
    }
    __syncthreads();
    // phase C: GEMM 64t x 64d x 128k
    int a = tid >> 4;            // t-quad 0..15
    int bc = tid & 15;           // d-quad 0..15
    int t0v = a * 4, d0v = bc * 4;
    float acc[4][4] = {};
    for (int k = 0; k < 128; ++k) {
        float4 w4 = *(const float4*)&Wl[k][t0v ^ WSWZ(k)];
        float4 h4 = *(const float4*)&Hl[k][d0v];
        acc[0][0] = fmaf(w4.x, h4.x, acc[0][0]); acc[0][1] = fmaf(w4.x, h4.y, acc[0][1]);
        acc[0][2] = fmaf(w4.x, h4.z, acc[0][2]); acc[0][3] = fmaf(w4.x, h4.w, acc[0][3]);
        acc[1][0] = fmaf(w4.y, h4.x, acc[1][0]); acc[1][1] = fmaf(w4.y, h4.y, acc[1][1]);
        acc[1][2] = fmaf(w4.y, h4.z, acc[1][2]); acc[1][3] = fmaf(w4.y, h4.w, acc[1][3]);
        acc[2][0] = fmaf(w4.z, h4.x, acc[2][0]); acc[2][1] = fmaf(w4.z, h4.y, acc[2][1]);
        acc[2][2] = fmaf(w4.z, h4.z, acc[2][2]); acc[2][3] = fmaf(w4.z, h4.w, acc[2][3]);
        acc[3][0] = fmaf(w4.w, h4.x, acc[3][0]); acc[3][1] = fmaf(w4.w, h4.y, acc[3][1]);
        acc[3][2] = fmaf(w4.w, h4.z, acc[3][2]); acc[3][3] = fmaf(w4.w, h4.w, acc[3][3]);
    }
    float* Ydst = dir ? yb : yf;
#pragma unroll
    for (int i = 0; i < 4; ++i) {
        int t = t0v + i;
        int l = dir ? (L_ - 1 - (c * TC + t)) : (c * TC + t);
        float* yp = Ydst + ((size_t)(b * L_ + l)) * DI + hh * HD + d0v;
        float4 old = *(float4*)yp;
        old.x += acc[i][0]; old.y += acc[i][1];
        old.z += acc[i][2]; old.w += acc[i][3];
        *(float4*)yp = old;
    }
}

// ---------------------------------------------------------------- gate + RMSNorm
__global__ __launch_bounds__(256) void gated_k(
    const float* __restrict__ yf, const float* __restrict__ yb,
    const float* __restrict__ xf, const float* __restrict__ zx,
    const float* __restrict__ Dp, const float* __restrict__ knw,
    float* __restrict__ gated) {
    __shared__ float sb[4];
    int row = blockIdx.x;
    int tid = threadIdx.x;
    float g[2];
    float ss = 0.f;
#pragma unroll
    for (int u = 0; u < 2; ++u) {
        int c = tid + u * 256;
        float yv = yf[(size_t)row * DI + c] + yb[(size_t)row * DI + c] +
                   Dp[c >> 6] * xf[(size_t)row * CC + c];
        float z = zx[(size_t)row * ZCOLS + c];
        float gv = yv * silu_f(z);
        g[u] = gv;
        ss = fmaf(gv, gv, ss);
    }
    float wsum = wave_sum(ss);
    if ((tid & 63) == 0) sb[tid >> 6] = wsum;
    __syncthreads();
    float tot = sb[0] + sb[1] + sb[2] + sb[3];
    float rms = rsqrtf(tot * (1.f / 512.f) + 1e-5f);
#pragma unroll
    for (int u = 0; u < 2; ++u) {
        int c = tid + u * 256;
        gated[(size_t)row * DI + c] = g[u] * rms * knw[c];
    }
}

// ---------------------------------------------------------------- final: out GEMM + query path
__global__ __launch_bounds__(256) void final_k(
    const float* __restrict__ gated, const float* __restrict__ Wok, float* __restrict__ out,
    const float* __restrict__ hfin, const float* __restrict__ lnw,
    const float* __restrict__ lnb, const float* __restrict__ woq,
    float* __restrict__ outq) {
    int bid = blockIdx.x, tid = threadIdx.x;
    if (bid < 128) {
        gemm_dev(gated, Wok, out, 2048, 256, 512, (bid & 31) * 64, (bid >> 5) * 64);
        return;
    }
    __shared__ float sln[512];
    __shared__ float sb1[4];
    __shared__ float sb2[4];
    int bk = bid - 128;                   // b*K_ + k
    int b = bk >> 7;
    int k = bk & 127;
    float st[2];
    float ssum = 0.f;
#pragma unroll
    for (int u = 0; u < 2; ++u) {
        int c = tid + u * 256;
        int hh = c >> 6, d = c & 63;
        size_t o0 = (((size_t)(0 * B_ + b) * NH + hh) * HD + d) * K_ + k;
        size_t o1 = (((size_t)(1 * B_ + b) * NH + hh) * HD + d) * K_ + k;
        st[u] = 0.5f * (hfin[o0] + hfin[o1]);
        ssum += st[u];
    }
    float wsum = wave_sum(ssum);
    if ((tid & 63) == 0) sb1[tid >> 6] = wsum;
    __syncthreads();
    float mu = (sb1[0] + sb1[1] + sb1[2] + sb1[3]) * (1.f / 512.f);
    float vs = 0.f;
#pragma unroll
    for (int u = 0; u < 2; ++u) {
        float t = st[u] - mu;
        vs = fmaf(t, t, vs);
    }
    float wv = wave_sum(vs);
    if ((tid & 63) == 0) sb2[tid >> 6] = wv;
    __syncthreads();
    float var = (sb2[0] + sb2[1] + sb2[2] + sb2[3]) * (1.f / 512.f);
    float inv = rsqrtf(var + 1e-5f);
#pragma unroll
    for (int u = 0; u < 2; ++u) {
        int c = tid + u * 256;
        sln[c] = (st[u] - mu) * inv * lnw[c] + lnb[c];
    }
    __syncthreads();
    const float4* w4 = (const float4*)(woq + (size_t)tid * 512);
    float acc = 0.f;
#pragma unroll 4
    for (int i = 0; i < 128; ++i) {
        float4 wvv = w4[i];
        float4 sv = *(const float4*)&sln[i * 4];
        acc = fmaf(wvv.x, sv.x, acc);
        acc = fmaf(wvv.y, sv.y, acc);
        acc = fmaf(wvv.z, sv.z, acc);
        acc = fmaf(wvv.w, sv.w, acc);
    }
    outq[(size_t)bk * 256 + tid] = acc;
}

// ---------------------------------------------------------------- launcher
extern "C" void kernel_launch(void* const* d_in, const int* in_sizes, int n_in,
                              void* d_out, int out_size, void* d_ws, size_t ws_size,
                              hipStream_t stream) {
    const float* in_key      = (const float*)d_in[0];
    const float* in_query    = (const float*)d_in[1];
    const float* key_xyz     = (const float*)d_in[2];
    const float* query_xyz   = (const float*)d_in[3];
    const float* query_size  = (const float*)d_in[4];
    const float* query_angle = (const float*)d_in[5];
    const float* Wkey        = (const float*)d_in[6];
    const float* conv_w      = (const float*)d_in[7];
    const float* conv_b      = (const float*)d_in[8];
    const float* convb_w     = (const float*)d_in[9];
    const float* convb_b     = (const float*)d_in[10];
    const float* Wq          = (const float*)d_in[11];
    const float* Wbc         = (const float*)d_in[12];
    const float* Wdt         = (const float*)d_in[13];
    const float* dt_bias     = (const float*)d_in[14];
    const float* A_log       = (const float*)d_in[15];
    const float* Dp          = (const float*)d_in[16];
    const float* Wok         = (const float*)d_in[17];
    const float* Woq         = (const float*)d_in[18];
    const float* key_norm_w  = (const float*)d_in[19];
    const float* ln_w        = (const float*)d_in[20];
    const float* ln_b        = (const float*)d_in[21];
    const float* cpb_w1      = (const float*)d_in[22];
    const float* cpb_b1      = (const float*)d_in[23];
    const float* cpb_w2      = (const float*)d_in[24];
    float* out = (float*)d_out;

    float* wsf = (float*)d_ws;
    float* zx    = wsf + 0;         // 2048*1034
    float* xf    = wsf + 2117632;   // 2048*514
    float* xb    = wsf + 3170304;   // 2048*514
    float* tbl   = wsf + 4222976;   // 4000
    float* cbuf  = wsf + 4226976;   // 2*1024*8
    float* Pbuf  = wsf + 4243360;   // 2*8*16*128
    float* dAa   = wsf + 5291936;   // 2*8*1024*128
    float* dBf   = wsf + 7389088;
    float* dBb   = wsf + 9486240;
    float* Cfb   = wsf + 11583392;  // 2*1024*128
    float* Cbb   = wsf + 11845536;
    float* h0b   = wsf + 12107680;  // 256*512
    float* yfb   = wsf + 12238752;  // 2048*512
    float* ybb   = wsf + 13287328;
    float* hfin  = wsf + 14335904;  // 2*2*8*64*128
    float* gated = wsf + 14598048;  // 2048*512
    float* Sbuf  = wsf + 15646624;  // 4,194,304 floats

    front_k<<<588, 256, 0, stream>>>(in_key, Wkey, zx, in_query, Wq, h0b,
                                     query_xyz, query_size, query_angle,
                                     cpb_w1, cpb_b1, cpb_w2, cbuf, tbl);
    dwconv_silu<<<dim3(1024, 3), 256, 0, stream>>>(zx, ZCOLS, 512, conv_w, conv_b, xf);
    dwconv_silu<<<dim3(1024, 3), 256, 0, stream>>>(xf, CC, 0, convb_w, convb_b, xb);
    geo_k<<<2048, 128, 0, stream>>>(key_xyz, cbuf, tbl, zx, xf, xb,
                                    Wbc, Wdt, dt_bias, A_log,
                                    dAa, dBf, dBb, Cfb, Cbb);
    scan_part6<<<512, 256, 0, stream>>>(dAa, dBf, dBb, Cfb, Cbb, xf, xb,
                                        Sbuf, Pbuf, yfb, ybb);
    scan_combine<<<128, 256, 0, stream>>>(h0b, Sbuf, Pbuf, hfin);
    scan_corr<<<512, 256, 0, stream>>>(dAa, Cfb, Cbb, Sbuf, yfb, ybb);
    gated_k<<<2048, 256, 0, stream>>>(yfb, ybb, xf, zx, Dp, key_norm_w, gated);
    final_k<<<384, 256, 0, stream>>>(gated, Wok, out, hfin, ln_w, ln_b, Woq,
                                     out + 524288);
}

// Round 16
// 179.419 us; speedup vs baseline: 1.2245x; 1.0809x over previous
//
#include <hip/hip_runtime.h>
#include <math.h>

#define B_ 2
#define L_ 1024
#define K_ 128
#define DM 256
#define DI 512
#define NH 8
#define HD 64
#define CC 514
#define ZCOLS 1034
#define NC 16
#define TC 64

typedef __attribute__((ext_vector_type(8))) short bf16x8;
typedef __attribute__((ext_vector_type(4))) float f32x4;

// ---------------------------------------------------------------- utilities
__device__ __forceinline__ float wave_sum(float v) {
    v += __shfl_xor(v, 1);  v += __shfl_xor(v, 2);  v += __shfl_xor(v, 4);
    v += __shfl_xor(v, 8);  v += __shfl_xor(v, 16); v += __shfl_xor(v, 32);
    return v;
}

// sum across each 16-lane DPP row via row_ror — VALU pipe, NOT the DS pipe.
__device__ __forceinline__ float dpp_row_reduce16(float v) {
    int t;
    t = __builtin_amdgcn_update_dpp(0, __float_as_int(v), 0x128, 0xF, 0xF, true); // row_ror:8
    v += __int_as_float(t);
    t = __builtin_amdgcn_update_dpp(0, __float_as_int(v), 0x124, 0xF, 0xF, true); // row_ror:4
    v += __int_as_float(t);
    t = __builtin_amdgcn_update_dpp(0, __float_as_int(v), 0x122, 0xF, 0xF, true); // row_ror:2
    v += __int_as_float(t);
    t = __builtin_amdgcn_update_dpp(0, __float_as_int(v), 0x121, 0xF, 0xF, true); // row_ror:1
    v += __int_as_float(t);
    return v;
}

__device__ __forceinline__ float silu_f(float x) {
    return x / (1.f + expf(-x));
}

__device__ __forceinline__ unsigned short f2bf(float f) {   // RNE f32->bf16
    unsigned u = __float_as_uint(f);
    u = (u + 0x7FFFu + ((u >> 16) & 1u)) >> 16;
    return (unsigned short)u;
}

// ---------------------------------------------------------------- bf16 conversion
// ikb: in_key (2048x256). wkb: Wkey rows padded to 1088 (rows >=1034 zero).
__global__ __launch_bounds__(256) void cvt_k(const float* __restrict__ ik,
                                             const float* __restrict__ wk,
                                             unsigned short* __restrict__ ikb,
                                             unsigned short* __restrict__ wkb) {
    int i = blockIdx.x * 256 + threadIdx.x;
    if (i < 131072) {                      // 2048*256/4
        float4 v = ((const float4*)ik)[i];
        ushort4 o;
        o.x = f2bf(v.x); o.y = f2bf(v.y); o.z = f2bf(v.z); o.w = f2bf(v.w);
        ((ushort4*)ikb)[i] = o;
    } else {
        int j = i - 131072;
        if (j >= 69632) return;            // 1088*256/4
        float4 v = (j < 66176) ? ((const float4*)wk)[j] : make_float4(0.f, 0.f, 0.f, 0.f);
        ushort4 o;
        o.x = f2bf(v.x); o.y = f2bf(v.y); o.z = f2bf(v.z); o.w = f2bf(v.w);
        ((ushort4*)wkb)[j] = o;
    }
}

// ---------------------------------------------------------------- pipelined NT GEMM (device body)
__device__ void gemm_dev(const float* __restrict__ A, const float* __restrict__ Bm,
                         float* __restrict__ C, int M, int N, int K, int bm, int bn) {
    __shared__ float As[2][16][68];
    __shared__ float Bs[2][16][68];
    const int tid = threadIdx.x;
    const int sr = tid >> 2;          // stage row 0..63
    const int sk = (tid & 3) * 4;     // stage k 0,4,8,12
    const int tx = tid & 15, ty = tid >> 4;
    const int NT = K >> 4;
    const float* Arow = A + (size_t)(bm + sr) * K + sk;
    const float* Brow = Bm + (size_t)(bn + sr) * K + sk;
    const bool bok = (bn + sr) < N;

    float4 av = *(const float4*)Arow;
    float4 bv = bok ? *(const float4*)Brow : make_float4(0.f, 0.f, 0.f, 0.f);
    As[0][sk + 0][sr] = av.x; As[0][sk + 1][sr] = av.y;
    As[0][sk + 2][sr] = av.z; As[0][sk + 3][sr] = av.w;
    Bs[0][sk + 0][sr] = bv.x; Bs[0][sk + 1][sr] = bv.y;
    Bs[0][sk + 2][sr] = bv.z; Bs[0][sk + 3][sr] = bv.w;
    __syncthreads();

    float acc[4][4] = {};
    for (int t = 0; t < NT; ++t) {
        if (t + 1 < NT) {             // issue next tile's loads early
            av = *(const float4*)(Arow + (t + 1) * 16);
            bv = bok ? *(const float4*)(Brow + (t + 1) * 16) : make_float4(0.f, 0.f, 0.f, 0.f);
        }
        const int bi = t & 1;
#pragma unroll
        for (int kk = 0; kk < 16; ++kk) {
            float4 a = *(const float4*)&As[bi][kk][ty * 4];
            float4 b = *(const float4*)&Bs[bi][kk][tx * 4];
            acc[0][0] = fmaf(a.x, b.x, acc[0][0]); acc[0][1] = fmaf(a.x, b.y, acc[0][1]);
            acc[0][2] = fmaf(a.x, b.z, acc[0][2]); acc[0][3] = fmaf(a.x, b.w, acc[0][3]);
            acc[1][0] = fmaf(a.y, b.x, acc[1][0]); acc[1][1] = fmaf(a.y, b.y, acc[1][1]);
            acc[1][2] = fmaf(a.y, b.z, acc[1][2]); acc[1][3] = fmaf(a.y, b.w, acc[1][3]);
            acc[2][0] = fmaf(a.z, b.x, acc[2][0]); acc[2][1] = fmaf(a.z, b.y, acc[2][1]);
            acc[2][2] = fmaf(a.z, b.z, acc[2][2]); acc[2][3] = fmaf(a.z, b.w, acc[2][3]);
            acc[3][0] = fmaf(a.w, b.x, acc[3][0]); acc[3][1] = fmaf(a.w, b.y, acc[3][1]);
            acc[3][2] = fmaf(a.w, b.z, acc[3][2]); acc[3][3] = fmaf(a.w, b.w, acc[3][3]);
        }
        if (t + 1 < NT) {             // write OTHER buffer; safe before barrier
            const int ni = (t + 1) & 1;
            As[ni][sk + 0][sr] = av.x; As[ni][sk + 1][sr] = av.y;
            As[ni][sk + 2][sr] = av.z; As[ni][sk + 3][sr] = av.w;
            Bs[ni][sk + 0][sr] = bv.x; Bs[ni][sk + 1][sr] = bv.y;
            Bs[ni][sk + 2][sr] = bv.z; Bs[ni][sk + 3][sr] = bv.w;
        }
        __syncthreads();              // single barrier per tile
    }
    // epilogue: float2 stores (N=1034 rows are only 8B-aligned)
#pragma unroll
    for (int i = 0; i < 4; ++i) {
        int m = bm + ty * 4 + i;
        int n0 = bn + tx * 4;
        if (n0 + 3 < N) {
            float* cp = &C[(size_t)m * N + n0];
            *(float2*)cp = make_float2(acc[i][0], acc[i][1]);
            *(float2*)(cp + 2) = make_float2(acc[i][2], acc[i][3]);
        } else {
#pragma unroll
            for (int j = 0; j < 4; ++j)
                if (n0 + j < N) C[(size_t)m * N + n0 + j] = acc[i][j];
        }
    }
}

// ---------------------------------------------------------------- front
// blocks 0..543:   zx (bf16 MFMA) — cols < 1026 only (dt cols stay f32)
// blocks 544..575: h0 = in_query @ Wq^T (f32)
// blocks 576..587: corners (8) + cpb table (4)
// blocks 588..651: zx dt cols 1026..1033 in f32 (exp-amplified path: keep full precision)
__global__ __launch_bounds__(256, 4) void front_k(
    const unsigned short* __restrict__ ikb, const unsigned short* __restrict__ wkb,
    const float* __restrict__ in_key, const float* __restrict__ Wkey,
    float* __restrict__ zx,
    const float* __restrict__ in_query, const float* __restrict__ Wq, float* __restrict__ h0b,
    const float* __restrict__ qxyz, const float* __restrict__ qsize,
    const float* __restrict__ qang, const float* __restrict__ w1,
    const float* __restrict__ b1, const float* __restrict__ w2,
    float* __restrict__ cb, float* __restrict__ tbl) {
    int bid = blockIdx.x, tid = threadIdx.x;
    if (bid < 544) {
        // bf16 MFMA zx GEMM: 64x64 tile, 4 waves x (2x2 16x16), K=256 in 8 steps.
        // A frag: row=lane&15, k=(lane>>4)*8+j; B frag symmetric (Wkey row = out col).
        int bm = (bid & 31) * 64, bn = (bid >> 5) * 64;
        int lane = tid & 63, wv = tid >> 6;
        int wm = wv >> 1, wn = wv & 1;
        int r = lane & 15, kg = lane >> 4;
        const unsigned short* A0 = ikb + (size_t)(bm + wm * 32 + r) * 256 + kg * 8;
        const unsigned short* A1 = A0 + 16 * 256;
        const unsigned short* B0 = wkb + (size_t)(bn + wn * 32 + r) * 256 + kg * 8;
        const unsigned short* B1 = B0 + 16 * 256;
        f32x4 acc00 = {0.f, 0.f, 0.f, 0.f}, acc01 = acc00, acc10 = acc00, acc11 = acc00;
#pragma unroll
        for (int k0 = 0; k0 < 256; k0 += 32) {
            bf16x8 a0 = *(const bf16x8*)(A0 + k0);
            bf16x8 a1 = *(const bf16x8*)(A1 + k0);
            bf16x8 b0 = *(const bf16x8*)(B0 + k0);
            bf16x8 b1 = *(const bf16x8*)(B1 + k0);
            acc00 = __builtin_amdgcn_mfma_f32_16x16x32_bf16(a0, b0, acc00, 0, 0, 0);
            acc01 = __builtin_amdgcn_mfma_f32_16x16x32_bf16(a0, b1, acc01, 0, 0, 0);
            acc10 = __builtin_amdgcn_mfma_f32_16x16x32_bf16(a1, b0, acc10, 0, 0, 0);
            acc11 = __builtin_amdgcn_mfma_f32_16x16x32_bf16(a1, b1, acc11, 0, 0, 0);
        }
        // C/D: col=lane&15, row=(lane>>4)*4+reg (verified layout)
        int mb = bm + wm * 32, nb = bn + wn * 32;
#pragma unroll
        for (int j = 0; j < 4; ++j) {
            int m0 = mb + kg * 4 + j;
            int n0 = nb + r;
            if (n0 < 1026)      zx[(size_t)m0 * ZCOLS + n0] = acc00[j];
            if (n0 + 16 < 1026) zx[(size_t)m0 * ZCOLS + n0 + 16] = acc01[j];
            int m1 = m0 + 16;
            if (n0 < 1026)      zx[(size_t)m1 * ZCOLS + n0] = acc10[j];
            if (n0 + 16 < 1026) zx[(size_t)m1 * ZCOLS + n0 + 16] = acc11[j];
        }
    } else if (bid < 576) {
        int rr = bid - 544;
        gemm_dev(in_query, Wq, h0b, 256, 512, 256, (rr & 3) * 64, (rr >> 2) * 64);
    } else if (bid < 584) {
        int idx = (bid - 576) * 256 + tid;    // < 2048 = B_*K_*8
        int b = idx >> 10;
        int q = idx & 1023;
        int k = q >> 3;
        int c = q & 7;
        const float sx[8] = {1, 1, -1, -1, 1, 1, -1, -1};
        const float sy[8] = {1, 1, 1, 1, -1, -1, -1, -1};
        const float sz[8] = {1, -1, -1, 1, 1, -1, -1, 1};
        float cx = qxyz[(b * K_ + k) * 3 + 0];
        float cy = qxyz[(b * K_ + k) * 3 + 1];
        float cz = qxyz[(b * K_ + k) * 3 + 2];
        float lv = qsize[(b * K_ + k) * 3 + 0];
        float wv2 = qsize[(b * K_ + k) * 3 + 1];
        float hv = qsize[(b * K_ + k) * 3 + 2];
        float ang = qang[b * K_ + k];
        float ca = cosf(ang), sa = sinf(ang);
        float ccx = cx, ccy = -cz, ccz = cy;
        float l0 = lv * sx[c] * 0.5f;
        float l1 = hv * sy[c] * 0.5f;
        float l2 = wv2 * sz[c] * 0.5f;
        float m0 = ca * l0 + sa * l2 + ccx;
        float m1 = l1 + ccy;
        float m2 = -sa * l0 + ca * l2 + ccz;
        // rotation for the distance transform uses angle[b, q % K] (jnp.tile semantics)
        float angr = qang[b * K_ + (q & (K_ - 1))];
        float4* o = (float4*)(cb + (size_t)idx * 8);
        o[0] = make_float4(m0, m2, -m1, cosf(angr));
        o[1] = make_float4(sinf(angr), 0.f, 0.f, 0.f);
    } else if (bid < 588) {
        int p = (bid - 584) * 256 + tid;
        if (p >= 1000) return;
        int i = p / 100, j = (p / 10) % 10, k = p % 10;
        float c0 = (8.f / 9.f) * i - 4.f;
        float c1 = (8.f / 9.f) * j - 4.f;
        float c2 = (8.f / 9.f) * k - 4.f;
        float a0 = 0.f, a1 = 0.f, a2 = 0.f, a3 = 0.f;
        for (int m = 0; m < 128; ++m) {
            float t = fmaf(c0, w1[m * 3 + 0], fmaf(c1, w1[m * 3 + 1], fmaf(c2, w1[m * 3 + 2], b1[m])));
            t = fmaxf(t, 0.f);
            a0 = fmaf(t, w2[m], a0);
            a1 = fmaf(t, w2[128 + m], a1);
            a2 = fmaf(t, w2[256 + m], a2);
            a3 = fmaf(t, w2[384 + m], a3);
        }
        tbl[p * 4 + 0] = a0; tbl[p * 4 + 1] = a1;
        tbl[p * 4 + 2] = a2; tbl[p * 4 + 3] = a3;
    } else {
        // f32 dt columns: zx[:,1026..1033] = in_key @ Wkey[1026..1033]^T
        int row = (bid - 588) * 32 + (tid >> 3);
        int colh = tid & 7;
        const float* arow = in_key + (size_t)row * 256;
        const float* wrow = Wkey + (size_t)(1026 + colh) * 256;
        float acc = 0.f;
#pragma unroll 8
        for (int k = 0; k < 256; k += 4) {
            float4 a = *(const float4*)(arow + k);
            float4 wv2 = *(const float4*)(wrow + k);
            acc = fmaf(a.x, wv2.x, fmaf(a.y, wv2.y, fmaf(a.z, wv2.z, fmaf(a.w, wv2.w, acc))));
        }
        zx[(size_t)row * ZCOLS + 1026 + colh] = acc;
    }
}

// ---------------------------------------------------------------- depthwise conv7 + silu (2 rows/block)
__global__ void dwconv_silu(const float* __restrict__ xin, int in_stride, int in_off,
                            const float* __restrict__ w, const float* __restrict__ bias,
                            float* __restrict__ out) {
    int c = blockIdx.y * blockDim.x + threadIdx.x;
    if (c >= CC) return;
    int row0 = blockIdx.x * 2;            // b*L + l, l even
    int l0 = row0 & (L_ - 1);
    const float* xr = xin + (size_t)row0 * in_stride + in_off + c;
    float Lv[8];
#pragma unroll
    for (int i = 0; i < 8; ++i) {
        int ll = l0 + i - 3;
        Lv[i] = (ll >= 0 && ll < L_) ? xr[(ptrdiff_t)(i - 3) * in_stride] : 0.f;
    }
    float acc0 = bias[c], acc1 = bias[c];
#pragma unroll
    for (int j = 0; j < 7; ++j) {
        float wj = w[c * 7 + j];
        acc0 = fmaf(Lv[j], wj, acc0);
        acc1 = fmaf(Lv[j + 1], wj, acc1);
    }
    out[(size_t)row0 * CC + c] = silu_f(acc0);
    out[(size_t)(row0 + 1) * CC + c] = silu_f(acc1);
}

// ---------------------------------------------------------------- fused dist + dA/dB/C
__global__ __launch_bounds__(128) void geo_k(
    const float* __restrict__ kxyz, const float* __restrict__ cb,
    const float* __restrict__ tbl, const float* __restrict__ zx,
    const float* __restrict__ xf, const float* __restrict__ xb,
    const float* __restrict__ wbc, const float* __restrict__ wdt,
    const float* __restrict__ dtb, const float* __restrict__ alog,
    float* __restrict__ dA, float* __restrict__ dBf, float* __restrict__ dBb,
    float* __restrict__ Cf, float* __restrict__ Cb) {
    __shared__ float t_s[4000];
    int row = blockIdx.x;                 // b*L + l
    int b = row >> 10;
    int l = row & 1023;
    int k = threadIdx.x;
    for (int i = threadIdx.x; i < 4000; i += 128) t_s[i] = tbl[i];
    __syncthreads();
    float kx = kxyz[(size_t)row * 3 + 0];
    float ky = kxyz[(size_t)row * 3 + 1];
    float kz = kxyz[(size_t)row * 3 + 2];
    float acc0 = 0.f, acc1 = 0.f, acc2 = 0.f, acc3 = 0.f;
#pragma unroll
    for (int c = 0; c < 8; ++c) {
        int q = k * 8 + c;
        const float4* p = (const float4*)(cb + (size_t)(b * 1024 + q) * 8);
        float4 v0 = p[0], v1 = p[1];
        float d0 = v0.x - kx, d1 = v0.y - ky, d2 = v0.z - kz;
        float rc = v0.w, rs = v1.x;
        float e0 = d0, e1 = -d2, e2 = d1;
        float f0 = rc * e0 - rs * e2;
        float f1 = e1;
        float f2 = rs * e0 + rc * e2;
        float g0 = f0, g1 = f2, g2 = -f1;
        g0 = copysignf(log2f(fabsf(g0) * 512.f + 1.f) * (1.f / 12.f), g0);
        g1 = copysignf(log2f(fabsf(g1) * 512.f + 1.f) * (1.f / 12.f), g1);
        g2 = copysignf(log2f(fabsf(g2) * 512.f + 1.f) * (1.f / 12.f), g2);
        // table axis0 <- g2, axis1 <- g1, axis2 <- g0
        float iq = 5.f * g2 + 4.5f;
        float jq = 5.f * g1 + 4.5f;
        float kq = 5.f * g0 + 4.5f;
        float i0f = floorf(iq), j0f = floorf(jq), k0f = floorf(kq);
        float wi = iq - i0f, wj = jq - j0f, wk = kq - k0f;
        int i0 = (int)i0f, j0 = (int)j0f, k0 = (int)k0f;
#pragma unroll
        for (int a = 0; a < 2; ++a) {
#pragma unroll
            for (int bb = 0; bb < 2; ++bb) {
#pragma unroll
                for (int cc = 0; cc < 2; ++cc) {
                    int ii = i0 + a, jj = j0 + bb, kk = k0 + cc;
                    if ((unsigned)ii < 10u && (unsigned)jj < 10u && (unsigned)kk < 10u) {
                        float wgt = (a ? wi : 1.f - wi) * (bb ? wj : 1.f - wj) * (cc ? wk : 1.f - wk);
                        const float* tp = &t_s[((ii * 10 + jj) * 10 + kk) * 4];
                        acc0 = fmaf(wgt, tp[0], acc0);
                        acc1 = fmaf(wgt, tp[1], acc1);
                        acc2 = fmaf(wgt, tp[2], acc2);
                        acc3 = fmaf(wgt, tp[3], acc3);
                    }
                }
            }
        }
    }
    // ---- fused precomp tail
    float B0 = acc0 * wbc[0] + acc1 * wbc[1] + acc2 * wbc[2] + acc3 * wbc[3];
    float C0 = acc0 * wbc[4] + acc1 * wbc[5] + acc2 * wbc[6] + acc3 * wbc[7];
    float bbf = xf[(size_t)row * CC + 512], cbf = xf[(size_t)row * CC + 513];
    float bbb = xb[(size_t)row * CC + 512], cbb = xb[(size_t)row * CC + 513];
    Cf[(size_t)row * K_ + k] = C0 + cbf;
    Cb[(size_t)row * K_ + k] = C0 + cbb;
    float Bf = B0 + bbf, Bb = B0 + bbb;
#pragma unroll
    for (int hh = 0; hh < NH; ++hh) {
        float s = acc0 * wdt[hh * 4 + 0] + acc1 * wdt[hh * 4 + 1] +
                  acc2 * wdt[hh * 4 + 2] + acc3 * wdt[hh * 4 + 3];
        s += zx[(size_t)row * ZCOLS + 1026 + hh] + dtb[hh];
        float dtv = (s > 20.f) ? s : log1pf(expf(s));
        float Av = -expf(alog[hh]);
        size_t o = ((size_t)(b * NH + hh) * L_ + l) * K_ + k;
        dA[o] = expf(dtv * Av);
        dBf[o] = dtv * Bf;
        dBb[o] = dtv * Bb;
    }
}

// ---------------------------------------------------------------- chunked ISSM scan, LDS-fed
__global__ __launch_bounds__(256) void scan_part6(
    const float* __restrict__ dA, const float* __restrict__ dBf, const float* __restrict__ dBb,
    const float* __restrict__ Cf, const float* __restrict__ Cb,
    const float* __restrict__ xf, const float* __restrict__ xb,
    float* __restrict__ Sbuf, float* __restrict__ Pbuf,
    float* __restrict__ yf, float* __restrict__ yb) {
    __shared__ float lds[2][3584];
    int bid = blockIdx.x;
    int c = bid & 15;
    int hh = (bid >> 4) & 7;
    int b = (bid >> 7) & 1;
    int dir = bid >> 8;
    int tid = threadIdx.x;             // 0..255
    int lane = tid & 63;
    int w = tid >> 6;                  // 0..3
    int dg = lane >> 4, kg = lane & 15;
    int dloc = w * 4 + dg;             // 0..15; lane owns d = dloc + 16*{0,1,2,3}
    int klo = kg * 4, khi = 64 + kg * 4;

    const float* Bsrc = dir ? dBb : dBf;
    const float* Csrc = dir ? Cb : Cf;
    const float* Xsrc = dir ? xb : xf;
    float* Ydst = dir ? yb : yf;
    int t0 = dir ? (L_ - 1 - c * TC) : c * TC;
    int stp = dir ? -1 : 1;

    const float* Abase = dA + ((size_t)(b * NH + hh) * L_) * K_;
    const float* Bbase = Bsrc + ((size_t)(b * NH + hh) * L_) * K_;
    const float* Cbase = Csrc + ((size_t)b * L_) * K_;
    const float* Xbase = Xsrc + ((size_t)b * L_) * CC + hh * HD;

    const bool hasx = (tid < 128);

    auto gaddr = [&](int v, int tb) -> const float* {
        if (v < 768) {
            int r = (v >> 5) & 7;
            int c4 = v & 31;
            int l = t0 + stp * (tb + r);
            const float* base = (v < 256) ? Abase : ((v < 512) ? Bbase : Cbase);
            return base + (size_t)l * K_ + c4 * 4;
        } else {
            int vv = v - 768;
            int r = vv >> 4, c4 = vv & 15;
            int l = t0 + stp * (tb + r);
            return Xbase + (size_t)l * CC + c4 * 4;
        }
    };

    float hA[8] = {0, 0, 0, 0, 0, 0, 0, 0};
    float hB[8] = {0, 0, 0, 0, 0, 0, 0, 0};
    float hC[8] = {0, 0, 0, 0, 0, 0, 0, 0};
    float hD[8] = {0, 0, 0, 0, 0, 0, 0, 0};
    float cum[8] = {1, 1, 1, 1, 1, 1, 1, 1};

    // prologue: stage tile 0 into buf 0
    float4 rA = *(const float4*)gaddr(tid, 0);
    float4 rB = *(const float4*)gaddr(256 + tid, 0);
    float4 rC = *(const float4*)gaddr(512 + tid, 0);
    float4 rX = hasx ? *(const float4*)gaddr(768 + tid, 0) : make_float4(0, 0, 0, 0);
    *(float4*)&lds[0][4 * tid] = rA;
    *(float4*)&lds[0][1024 + 4 * tid] = rB;
    *(float4*)&lds[0][2048 + 4 * tid] = rC;
    if (hasx) *(float4*)&lds[0][3072 + 4 * tid] = rX;
    __syncthreads();

    float* pY = Ydst + ((size_t)(b * L_ + t0)) * DI + hh * HD + dloc;
    const ptrdiff_t dY = (ptrdiff_t)stp * DI;

    for (int it = 0; it < TC / 8; ++it) {
        int tb = it * 8;
        if (it < TC / 8 - 1) {           // issue next tile's global loads early
            rA = *(const float4*)gaddr(tid, tb + 8);
            rB = *(const float4*)gaddr(256 + tid, tb + 8);
            rC = *(const float4*)gaddr(512 + tid, tb + 8);
            if (hasx) rX = *(const float4*)gaddr(768 + tid, tb + 8);
        }
        const float* Lb = lds[it & 1];
        // tile prologue: st=0 full operands + st=1 a/b
        float4 aC0 = *(const float4*)&Lb[klo];
        float4 aC1 = *(const float4*)&Lb[khi];
        float4 bC0 = *(const float4*)&Lb[1024 + klo];
        float4 bC1 = *(const float4*)&Lb[1024 + khi];
        float4 cC0 = *(const float4*)&Lb[2048 + klo];
        float4 cC1 = *(const float4*)&Lb[2048 + khi];
        float x0 = Lb[3072 + dloc];
        float x1 = Lb[3072 + 16 + dloc];
        float x2 = Lb[3072 + 32 + dloc];
        float x3 = Lb[3072 + 48 + dloc];
        float4 aN0 = *(const float4*)&Lb[128 + klo];
        float4 aN1 = *(const float4*)&Lb[128 + khi];
        float4 bN0 = *(const float4*)&Lb[1024 + 128 + klo];
        float4 bN1 = *(const float4*)&Lb[1024 + 128 + khi];
#pragma unroll
        for (int st = 0; st < 8; ++st) {
            float4 aF0, aF1, bF0, bF1, cN0, cN1;
            float nx0 = 0.f, nx1 = 0.f, nx2 = 0.f, nx3 = 0.f;
            if (st < 6) {                // a/b for st+2 (h-critical, deepest lookahead)
                int o = (st + 2) * 128;
                aF0 = *(const float4*)&Lb[o + klo];
                aF1 = *(const float4*)&Lb[o + khi];
                bF0 = *(const float4*)&Lb[1024 + o + klo];
                bF1 = *(const float4*)&Lb[1024 + o + khi];
            }
            if (st < 7) {                // c/x for st+1
                int o = (st + 1) * 128;
                cN0 = *(const float4*)&Lb[2048 + o + klo];
                cN1 = *(const float4*)&Lb[2048 + o + khi];
                int xo = 3072 + (st + 1) * 64 + dloc;
                nx0 = Lb[xo]; nx1 = Lb[xo + 16]; nx2 = Lb[xo + 32]; nx3 = Lb[xo + 48];
            }
            cum[0] *= aC0.x; cum[1] *= aC0.y; cum[2] *= aC0.z; cum[3] *= aC0.w;
            cum[4] *= aC1.x; cum[5] *= aC1.y; cum[6] *= aC1.z; cum[7] *= aC1.w;
            float u0, u1, u2, u3;
            // d-block A (x0)
            hA[0] = fmaf(hA[0], aC0.x, x0 * bC0.x); u0 = hA[0] * cC0.x;
            hA[1] = fmaf(hA[1], aC0.y, x0 * bC0.y); u1 = hA[1] * cC0.y;
            hA[2] = fmaf(hA[2], aC0.z, x0 * bC0.z); u2 = hA[2] * cC0.z;
            hA[3] = fmaf(hA[3], aC0.w, x0 * bC0.w); u3 = hA[3] * cC0.w;
            hA[4] = fmaf(hA[4], aC1.x, x0 * bC1.x); u0 = fmaf(hA[4], cC1.x, u0);
            hA[5] = fmaf(hA[5], aC1.y, x0 * bC1.y); u1 = fmaf(hA[5], cC1.y, u1);
            hA[6] = fmaf(hA[6], aC1.z, x0 * bC1.z); u2 = fmaf(hA[6], cC1.z, u2);
            hA[7] = fmaf(hA[7], aC1.w, x0 * bC1.w); u3 = fmaf(hA[7], cC1.w, u3);
            float rrA = dpp_row_reduce16((u0 + u1) + (u2 + u3));
            // d-block B (x1)
            hB[0] = fmaf(hB[0], aC0.x, x1 * bC0.x); u0 = hB[0] * cC0.x;
            hB[1] = fmaf(hB[1], aC0.y, x1 * bC0.y); u1 = hB[1] * cC0.y;
            hB[2] = fmaf(hB[2], aC0.z, x1 * bC0.z); u2 = hB[2] * cC0.z;
            hB[3] = fmaf(hB[3], aC0.w, x1 * bC0.w); u3 = hB[3] * cC0.w;
            hB[4] = fmaf(hB[4], aC1.x, x1 * bC1.x); u0 = fmaf(hB[4], cC1.x, u0);
            hB[5] = fmaf(hB[5], aC1.y, x1 * bC1.y); u1 = fmaf(hB[5], cC1.y, u1);
            hB[6] = fmaf(hB[6], aC1.z, x1 * bC1.z); u2 = fmaf(hB[6], cC1.z, u2);
            hB[7] = fmaf(hB[7], aC1.w, x1 * bC1.w); u3 = fmaf(hB[7], cC1.w, u3);
            float rrB = dpp_row_reduce16((u0 + u1) + (u2 + u3));
            // d-block C (x2)
            hC[0] = fmaf(hC[0], aC0.x, x2 * bC0.x); u0 = hC[0] * cC0.x;
            hC[1] = fmaf(hC[1], aC0.y, x2 * bC0.y); u1 = hC[1] * cC0.y;
            hC[2] = fmaf(hC[2], aC0.z, x2 * bC0.z); u2 = hC[2] * cC0.z;
            hC[3] = fmaf(hC[3], aC0.w, x2 * bC0.w); u3 = hC[3] * cC0.w;
            hC[4] = fmaf(hC[4], aC1.x, x2 * bC1.x); u0 = fmaf(hC[4], cC1.x, u0);
            hC[5] = fmaf(hC[5], aC1.y, x2 * bC1.y); u1 = fmaf(hC[5], cC1.y, u1);
            hC[6] = fmaf(hC[6], aC1.z, x2 * bC1.z); u2 = fmaf(hC[6], cC1.z, u2);
            hC[7] = fmaf(hC[7], aC1.w, x2 * bC1.w); u3 = fmaf(hC[7], cC1.w, u3);
            float rrC = dpp_row_reduce16((u0 + u1) + (u2 + u3));
            // d-block D (x3)
            hD[0] = fmaf(hD[0], aC0.x, x3 * bC0.x); u0 = hD[0] * cC0.x;
            hD[1] = fmaf(hD[1], aC0.y, x3 * bC0.y); u1 = hD[1] * cC0.y;
            hD[2] = fmaf(hD[2], aC0.z, x3 * bC0.z); u2 = hD[2] * cC0.z;
            hD[3] = fmaf(hD[3], aC0.w, x3 * bC0.w); u3 = hD[3] * cC0.w;
            hD[4] = fmaf(hD[4], aC1.x, x3 * bC1.x); u0 = fmaf(hD[4], cC1.x, u0);
            hD[5] = fmaf(hD[5], aC1.y, x3 * bC1.y); u1 = fmaf(hD[5], cC1.y, u1);
            hD[6] = fmaf(hD[6], aC1.z, x3 * bC1.z); u2 = fmaf(hD[6], cC1.z, u2);
            hD[7] = fmaf(hD[7], aC1.w, x3 * bC1.w); u3 = fmaf(hD[7], cC1.w, u3);
            float rrD = dpp_row_reduce16((u0 + u1) + (u2 + u3));
            if (kg == 0) { pY[0] = rrA; pY[16] = rrB; pY[32] = rrC; pY[48] = rrD; }
            pY += dY;
            if (st < 7) {                // rotate generations
                aC0 = aN0; aC1 = aN1; bC0 = bN0; bC1 = bN1;
                cC0 = cN0; cC1 = cN1;
                x0 = nx0; x1 = nx1; x2 = nx2; x3 = nx3;
                if (st < 6) { aN0 = aF0; aN1 = aF1; bN0 = bF0; bN1 = bF1; }
            }
        }
        if (it < TC / 8 - 1) {           // write OTHER buffer; safe before barrier
            *(float4*)&lds[(it + 1) & 1][4 * tid] = rA;
            *(float4*)&lds[(it + 1) & 1][1024 + 4 * tid] = rB;
            *(float4*)&lds[(it + 1) & 1][2048 + 4 * tid] = rC;
            if (hasx) *(float4*)&lds[(it + 1) & 1][3072 + 4 * tid] = rX;
        }
        __syncthreads();                 // single barrier per tile
    }

    int ibh = (dir * B_ + b) * NH + hh;
    {
        float* Sp = Sbuf + (((size_t)ibh * NC + c) * HD + dloc) * K_;
        *(float4*)(Sp + klo) = make_float4(hA[0], hA[1], hA[2], hA[3]);
        *(float4*)(Sp + khi) = make_float4(hA[4], hA[5], hA[6], hA[7]);
        Sp += (size_t)16 * K_;
        *(float4*)(Sp + klo) = make_float4(hB[0], hB[1], hB[2], hB[3]);
        *(float4*)(Sp + khi) = make_float4(hB[4], hB[5], hB[6], hB[7]);
        Sp += (size_t)16 * K_;
        *(float4*)(Sp + klo) = make_float4(hC[0], hC[1], hC[2], hC[3]);
        *(float4*)(Sp + khi) = make_float4(hC[4], hC[5], hC[6], hC[7]);
        Sp += (size_t)16 * K_;
        *(float4*)(Sp + klo) = make_float4(hD[0], hD[1], hD[2], hD[3]);
        *(float4*)(Sp + khi) = make_float4(hD[4], hD[5], hD[6], hD[7]);
    }
    if (dir == 0 && tid < 16) {          // w==0, dg==0, kg==tid: cum identical across d
        float* Pp = Pbuf + ((size_t)((b * NH + hh) * NC + c)) * K_;
        *(float4*)(Pp + klo) = make_float4(cum[0], cum[1], cum[2], cum[3]);
        *(float4*)(Pp + khi) = make_float4(cum[4], cum[5], cum[6], cum[7]);
    }
}

// phase 2: sequential combine across NC chunks
__global__ __launch_bounds__(256) void scan_combine(
    const float* __restrict__ h0buf, float* __restrict__ Sbuf,
    const float* __restrict__ Pbuf, float* __restrict__ hfin) {
    int bid = blockIdx.x;
    int dq = bid & 3;
    int hh = (bid >> 2) & 7;
    int b = (bid >> 5) & 1;
    int dir = bid >> 6;
    int tid = threadIdx.x;
    int w = tid >> 6;
    int lane = tid & 63;
    int dsl = dq * 4 + w;
    int dg = lane >> 4, kg = lane & 15;
    int d = dsl * 4 + dg;
    int k0 = kg * 8;

    float H[8];
#pragma unroll
    for (int j = 0; j < 8; ++j)
        H[j] = h0buf[(size_t)(b * K_ + k0 + j) * DI + hh * HD + d];

    int ibh = (dir * B_ + b) * NH + hh;
    for (int c = 0; c < NC; ++c) {
        float* Sp = Sbuf + (((size_t)ibh * NC + c) * HD + d) * K_ + k0;
        int cF = dir ? (NC - 1 - c) : c;   // P computed on fwd chunk row-sets
        const float* Pp = Pbuf + ((size_t)((b * NH + hh) * NC + cF)) * K_ + k0;
        float4 sA = *(const float4*)(Sp + 0);
        float4 sB = *(const float4*)(Sp + 4);
        float4 pA = *(const float4*)(Pp + 0);
        float4 pB = *(const float4*)(Pp + 4);
        // store incoming state for this chunk (overwrites S)
        *(float4*)(Sp + 0) = make_float4(H[0], H[1], H[2], H[3]);
        *(float4*)(Sp + 4) = make_float4(H[4], H[5], H[6], H[7]);
        H[0] = fmaf(H[0], pA.x, sA.x); H[1] = fmaf(H[1], pA.y, sA.y);
        H[2] = fmaf(H[2], pA.z, sA.z); H[3] = fmaf(H[3], pA.w, sA.w);
        H[4] = fmaf(H[4], pB.x, sB.x); H[5] = fmaf(H[5], pB.y, sB.y);
        H[6] = fmaf(H[6], pB.z, sB.z); H[7] = fmaf(H[7], pB.w, sB.w);
    }
    float* hf = hfin + ((((size_t)dir * B_ + b) * NH + hh) * HD + d) * K_ + k0;
    *(float4*)(hf + 0) = make_float4(H[0], H[1], H[2], H[3]);
    *(float4*)(hf + 4) = make_float4(H[4], H[5], H[6], H[7]);
}

// phase 3: y[t,d] += sum_k C[t,k]*cumA[t,k] * Hin[k,d]
#define CP 72
#define WSWZ(k) ((((k) >> 3) & 3) << 2)
__global__ __launch_bounds__(256) void scan_corr(
    const float* __restrict__ dA, const float* __restrict__ Cf, const float* __restrict__ Cb,
    const float* __restrict__ Sbuf, float* __restrict__ yf, float* __restrict__ yb) {
    __shared__ float Wl[128][CP];   // [k][t] (t XOR-swizzled by WSWZ(k))
    __shared__ float Hl[128][CP];   // [k][d]
    int iid = blockIdx.x;
    int c = iid & 15;
    int hh = (iid >> 4) & 7;
    int b = (iid >> 7) & 1;
    int dir = iid >> 8;
    int tid = threadIdx.x;
    const float* Csrc = dir ? Cb : Cf;

    // phase A: W[k][t] = C[l(t),k] * cumA(t,k), scan order
    if (tid < 128) {
        int k = tid;
        float cum = 1.f;
        const float* pA = dA + ((size_t)(b * NH + hh) * L_) * K_ + k;
        const float* pC = Csrc + ((size_t)b * L_) * K_ + k;
        int sw = WSWZ(k);
#pragma unroll 4
        for (int t = 0; t < TC; ++t) {
            int l = dir ? (L_ - 1 - (c * TC + t)) : (c * TC + t);
            cum *= pA[(size_t)l * K_];
            Wl[k][t ^ sw] = cum * pC[(size_t)l * K_];
        }
    }
    // phase B: Hin [k][d] (transposed stage from Sbuf [d][k])
    {
        int d = tid & 63, kq = tid >> 6;   // kq 0..3
        int ibh = (dir * B_ + b) * NH + hh;
        const float* Hp = Sbuf + (((size_t)ibh * NC + c) * HD + d) * K_;
#pragma unroll
        for (int i = 0; i < 8; ++i) {
            int q = kq * 8 + i;            // float4 index 0..31
            float4 v = *(const float4*)(Hp + q * 4);
            Hl[q * 4 + 0][d] = v.x; Hl[q * 4 + 1][d] = v.y;
            Hl[q * 4 + 2][d] = v.z; Hl[q * 4 + 3][d] = v.w;
        }
    }
    __syncthreads();
    // phase C: GEMM 64t x 64d x 128k
    int a = tid >> 4;            // t-quad 0..15
    int bc = tid & 15;           // d-quad 0..15
    int t0v = a * 4, d0v = bc * 4;
    float acc[4][4] = {};
    for (int k = 0; k < 128; ++k) {
        float4 w4 = *(const float4*)&Wl[k][t0v ^ WSWZ(k)];
        float4 h4 = *(const float4*)&Hl[k][d0v];
        acc[0][0] = fmaf(w4.x, h4.x, acc[0][0]); acc[0][1] = fmaf(w4.x, h4.y, acc[0][1]);
        acc[0][2] = fmaf(w4.x, h4.z, acc[0][2]); acc[0][3] = fmaf(w4.x, h4.w, acc[0][3]);
        acc[1][0] = fmaf(w4.y, h4.x, acc[1][0]); acc[1][1] = fmaf(w4.y, h4.y, acc[1][1]);
        acc[1][2] = fmaf(w4.y, h4.z, acc[1][2]); acc[1][3] = fmaf(w4.y, h4.w, acc[1][3]);
        acc[2][0] = fmaf(w4.z, h4.x, acc[2][0]); acc[2][1] = fmaf(w4.z, h4.y, acc[2][1]);
        acc[2][2] = fmaf(w4.z, h4.z, acc[2][2]); acc[2][3] = fmaf(w4.z, h4.w, acc[2][3]);
        acc[3][0] = fmaf(w4.w, h4.x, acc[3][0]); acc[3][1] = fmaf(w4.w, h4.y, acc[3][1]);
        acc[3][2] = fmaf(w4.w, h4.z, acc[3][2]); acc[3][3] = fmaf(w4.w, h4.w, acc[3][3]);
    }
    float* Ydst = dir ? yb : yf;
#pragma unroll
    for (int i = 0; i < 4; ++i) {
        int t = t0v + i;
        int l = dir ? (L_ - 1 - (c * TC + t)) : (c * TC + t);
        float* yp = Ydst + ((size_t)(b * L_ + l)) * DI + hh * HD + d0v;
        float4 old = *(float4*)yp;
        old.x += acc[i][0]; old.y += acc[i][1];
        old.z += acc[i][2]; old.w += acc[i][3];
        *(float4*)yp = old;
    }
}

// ---------------------------------------------------------------- gate + RMSNorm
__global__ __launch_bounds__(256) void gated_k(
    const float* __restrict__ yf, const float* __restrict__ yb,
    const float* __restrict__ xf, const float* __restrict__ zx,
    const float* __restrict__ Dp, const float* __restrict__ knw,
    float* __restrict__ gated) {
    __shared__ float sb[4];
    int row = blockIdx.x;
    int tid = threadIdx.x;
    float g[2];
    float ss = 0.f;
#pragma unroll
    for (int u = 0; u < 2; ++u) {
        int c = tid + u * 256;
        float yv = yf[(size_t)row * DI + c] + yb[(size_t)row * DI + c] +
                   Dp[c >> 6] * xf[(size_t)row * CC + c];
        float z = zx[(size_t)row * ZCOLS + c];
        float gv = yv * silu_f(z);
        g[u] = gv;
        ss = fmaf(gv, gv, ss);
    }
    float wsum = wave_sum(ss);
    if ((tid & 63) == 0) sb[tid >> 6] = wsum;
    __syncthreads();
    float tot = sb[0] + sb[1] + sb[2] + sb[3];
    float rms = rsqrtf(tot * (1.f / 512.f) + 1e-5f);
#pragma unroll
    for (int u = 0; u < 2; ++u) {
        int c = tid + u * 256;
        gated[(size_t)row * DI + c] = g[u] * rms * knw[c];
    }
}

// ---------------------------------------------------------------- final: out GEMM + query path
__global__ __launch_bounds__(256) void final_k(
    const float* __restrict__ gated, const float* __restrict__ Wok, float* __restrict__ out,
    const float* __restrict__ hfin, const float* __restrict__ lnw,
    const float* __restrict__ lnb, const float* __restrict__ woq,
    float* __restrict__ outq) {
    int bid = blockIdx.x, tid = threadIdx.x;
    if (bid < 128) {
        gemm_dev(gated, Wok, out, 2048, 256, 512, (bid & 31) * 64, (bid >> 5) * 64);
        return;
    }
    __shared__ float sln[512];
    __shared__ float sb1[4];
    __shared__ float sb2[4];
    int bk = bid - 128;                   // b*K_ + k
    int b = bk >> 7;
    int k = bk & 127;
    float st[2];
    float ssum = 0.f;
#pragma unroll
    for (int u = 0; u < 2; ++u) {
        int c = tid + u * 256;
        int hh = c >> 6, d = c & 63;
        size_t o0 = (((size_t)(0 * B_ + b) * NH + hh) * HD + d) * K_ + k;
        size_t o1 = (((size_t)(1 * B_ + b) * NH + hh) * HD + d) * K_ + k;
        st[u] = 0.5f * (hfin[o0] + hfin[o1]);
        ssum += st[u];
    }
    float wsum = wave_sum(ssum);
    if ((tid & 63) == 0) sb1[tid >> 6] = wsum;
    __syncthreads();
    float mu = (sb1[0] + sb1[1] + sb1[2] + sb1[3]) * (1.f / 512.f);
    float vs = 0.f;
#pragma unroll
    for (int u = 0; u < 2; ++u) {
        float t = st[u] - mu;
        vs = fmaf(t, t, vs);
    }
    float wv = wave_sum(vs);
    if ((tid & 63) == 0) sb2[tid >> 6] = wv;
    __syncthreads();
    float var = (sb2[0] + sb2[1] + sb2[2] + sb2[3]) * (1.f / 512.f);
    float inv = rsqrtf(var + 1e-5f);
#pragma unroll
    for (int u = 0; u < 2; ++u) {
        int c = tid + u * 256;
        sln[c] = (st[u] - mu) * inv * lnw[c] + lnb[c];
    }
    __syncthreads();
    const float4* w4 = (const float4*)(woq + (size_t)tid * 512);
    float acc = 0.f;
#pragma unroll 4
    for (int i = 0; i < 128; ++i) {
        float4 wvv = w4[i];
        float4 sv = *(const float4*)&sln[i * 4];
        acc = fmaf(wvv.x, sv.x, acc);
        acc = fmaf(wvv.y, sv.y, acc);
        acc = fmaf(wvv.z, sv.z, acc);
        acc = fmaf(wvv.w, sv.w, acc);
    }
    outq[(size_t)bk * 256 + tid] = acc;
}

// ---------------------------------------------------------------- launcher
extern "C" void kernel_launch(void* const* d_in, const int* in_sizes, int n_in,
                              void* d_out, int out_size, void* d_ws, size_t ws_size,
                              hipStream_t stream) {
    const float* in_key      = (const float*)d_in[0];
    const float* in_query    = (const float*)d_in[1];
    const float* key_xyz     = (const float*)d_in[2];
    const float* query_xyz   = (const float*)d_in[3];
    const float* query_size  = (const float*)d_in[4];
    const float* query_angle = (const float*)d_in[5];
    const float* Wkey        = (const float*)d_in[6];
    const float* conv_w      = (const float*)d_in[7];
    const float* conv_b      = (const float*)d_in[8];
    const float* convb_w     = (const float*)d_in[9];
    const float* convb_b     = (const float*)d_in[10];
    const float* Wq          = (const float*)d_in[11];
    const float* Wbc         = (const float*)d_in[12];
    const float* Wdt         = (const float*)d_in[13];
    const float* dt_bias     = (const float*)d_in[14];
    const float* A_log       = (const float*)d_in[15];
    const float* Dp          = (const float*)d_in[16];
    const float* Wok         = (const float*)d_in[17];
    const float* Woq         = (const float*)d_in[18];
    const float* key_norm_w  = (const float*)d_in[19];
    const float* ln_w        = (const float*)d_in[20];
    const float* ln_b        = (const float*)d_in[21];
    const float* cpb_w1      = (const float*)d_in[22];
    const float* cpb_b1      = (const float*)d_in[23];
    const float* cpb_w2      = (const float*)d_in[24];
    float* out = (float*)d_out;

    float* wsf = (float*)d_ws;
    float* zx    = wsf + 0;         // 2048*1034
    float* xf    = wsf + 2117632;   // 2048*514
    float* xb    = wsf + 3170304;   // 2048*514
    float* tbl   = wsf + 4222976;   // 4000
    float* cbuf  = wsf + 4226976;   // 2*1024*8
    float* Pbuf  = wsf + 4243360;   // 2*8*16*128
    float* dAa   = wsf + 5291936;   // 2*8*1024*128
    float* dBf   = wsf + 7389088;
    float* dBb   = wsf + 9486240;
    float* Cfb   = wsf + 11583392;  // 2*1024*128
    float* Cbb   = wsf + 11845536;
    float* h0b   = wsf + 12107680;  // 256*512
    float* yfb   = wsf + 12238752;  // 2048*512
    float* ybb   = wsf + 13287328;
    float* hfin  = wsf + 14335904;  // 2*2*8*64*128
    float* gated = wsf + 14598048;  // 2048*512
    float* Sbuf  = wsf + 15646624;  // 4,194,304 floats
    unsigned short* ikb = (unsigned short*)(wsf + 19840928);  // 2048*256 bf16
    unsigned short* wkb = (unsigned short*)(wsf + 20103072);  // 1088*256 bf16 (padded)

    cvt_k<<<784, 256, 0, stream>>>(in_key, Wkey, ikb, wkb);
    front_k<<<652, 256, 0, stream>>>(ikb, wkb, in_key, Wkey, zx, in_query, Wq, h0b,
                                     query_xyz, query_size, query_angle,
                                     cpb_w1, cpb_b1, cpb_w2, cbuf, tbl);
    dwconv_silu<<<dim3(1024, 3), 256, 0, stream>>>(zx, ZCOLS, 512, conv_w, conv_b, xf);
    dwconv_silu<<<dim3(1024, 3), 256, 0, stream>>>(xf, CC, 0, convb_w, convb_b, xb);
    geo_k<<<2048, 128, 0, stream>>>(key_xyz, cbuf, tbl, zx, xf, xb,
                                    Wbc, Wdt, dt_bias, A_log,
                                    dAa, dBf, dBb, Cfb, Cbb);
    scan_part6<<<512, 256, 0, stream>>>(dAa, dBf, dBb, Cfb, Cbb, xf, xb,
                                        Sbuf, Pbuf, yfb, ybb);
    scan_combine<<<128, 256, 0, stream>>>(h0b, Sbuf, Pbuf, hfin);
    scan_corr<<<512, 256, 0, stream>>>(dAa, Cfb, Cbb, Sbuf, yfb, ybb);
    gated_k<<<2048, 256, 0, stream>>>(yfb, ybb, xf, zx, Dp, key_norm_w, gated);
    final_k<<<384, 256, 0, stream>>>(gated, Wok, out, hfin, ln_w, ln_b, Woq,
                                     out + 524288);
}

// Round 17
// 164.203 us; speedup vs baseline: 1.3380x; 1.0927x over previous
//
#include <hip/hip_runtime.h>
#include <math.h>

#define B_ 2
#define L_ 1024
#define K_ 128
#define DM 256
#define DI 512
#define NH 8
#define HD 64
#define CC 514
#define ZCOLS 1034
#define NC 16
#define TC 64

typedef __attribute__((ext_vector_type(8))) short bf16x8;
typedef __attribute__((ext_vector_type(4))) float f32x4;

// ---------------------------------------------------------------- utilities
__device__ __forceinline__ float wave_sum(float v) {
    v += __shfl_xor(v, 1);  v += __shfl_xor(v, 2);  v += __shfl_xor(v, 4);
    v += __shfl_xor(v, 8);  v += __shfl_xor(v, 16); v += __shfl_xor(v, 32);
    return v;
}

// sum across each 16-lane DPP row via row_ror — VALU pipe, NOT the DS pipe.
__device__ __forceinline__ float dpp_row_reduce16(float v) {
    int t;
    t = __builtin_amdgcn_update_dpp(0, __float_as_int(v), 0x128, 0xF, 0xF, true); // row_ror:8
    v += __int_as_float(t);
    t = __builtin_amdgcn_update_dpp(0, __float_as_int(v), 0x124, 0xF, 0xF, true); // row_ror:4
    v += __int_as_float(t);
    t = __builtin_amdgcn_update_dpp(0, __float_as_int(v), 0x122, 0xF, 0xF, true); // row_ror:2
    v += __int_as_float(t);
    t = __builtin_amdgcn_update_dpp(0, __float_as_int(v), 0x121, 0xF, 0xF, true); // row_ror:1
    v += __int_as_float(t);
    return v;
}

__device__ __forceinline__ float silu_f(float x) {
    return x / (1.f + expf(-x));
}

__device__ __forceinline__ unsigned short f2bf(float f) {   // RNE f32->bf16
    unsigned u = __float_as_uint(f);
    u = (u + 0x7FFFu + ((u >> 16) & 1u)) >> 16;
    return (unsigned short)u;
}

// ---------------------------------------------------------------- bf16 conversion
// f4 ranges: [0,131072) ik | [131072,200704) wk (1088 rows, pad 0) |
//            [200704,217088) iq | [217088,249856) wq | [249856,282624) wok
__global__ __launch_bounds__(256) void cvt_k(
    const float* __restrict__ ik, const float* __restrict__ wk,
    const float* __restrict__ iq, const float* __restrict__ wq,
    const float* __restrict__ wok,
    unsigned short* __restrict__ ikb, unsigned short* __restrict__ wkb,
    unsigned short* __restrict__ iqb, unsigned short* __restrict__ wqb,
    unsigned short* __restrict__ wokb) {
    int i = blockIdx.x * 256 + threadIdx.x;
    float4 v;
    ushort4* dst;
    if (i < 131072) {
        v = ((const float4*)ik)[i];
        dst = ((ushort4*)ikb) + i;
    } else if (i < 200704) {
        int j = i - 131072;
        v = (j < 66176) ? ((const float4*)wk)[j] : make_float4(0.f, 0.f, 0.f, 0.f);
        dst = ((ushort4*)wkb) + j;
    } else if (i < 217088) {
        int j = i - 200704;
        v = ((const float4*)iq)[j];
        dst = ((ushort4*)iqb) + j;
    } else if (i < 249856) {
        int j = i - 217088;
        v = ((const float4*)wq)[j];
        dst = ((ushort4*)wqb) + j;
    } else if (i < 282624) {
        int j = i - 249856;
        v = ((const float4*)wok)[j];
        dst = ((ushort4*)wokb) + j;
    } else return;
    ushort4 o;
    o.x = f2bf(v.x); o.y = f2bf(v.y); o.z = f2bf(v.z); o.w = f2bf(v.w);
    *dst = o;
}

// ---------------------------------------------------------------- bf16 MFMA GEMM (device body)
// C[m][n] (+ldc) = A[m][:K] . B[n][:K], 64x64 tile at (bm,bn); 4 waves x (2x2 16x16).
// A/B frag: row=lane&15, k=(lane>>4)*8+j. C/D: col=lane&15, row=(lane>>4)*4+reg.
__device__ __forceinline__ void mfma_dev(
    const unsigned short* __restrict__ A, const unsigned short* __restrict__ B,
    float* __restrict__ C, int ldc, int K, int bm, int bn, int nmax) {
    int tid = threadIdx.x;
    int lane = tid & 63, wv = tid >> 6;
    int wm = wv >> 1, wn = wv & 1;
    int r = lane & 15, kg = lane >> 4;
    const unsigned short* A0 = A + (size_t)(bm + wm * 32 + r) * K + kg * 8;
    const unsigned short* A1 = A0 + 16 * K;
    const unsigned short* B0 = B + (size_t)(bn + wn * 32 + r) * K + kg * 8;
    const unsigned short* B1 = B0 + 16 * K;
    f32x4 acc00 = {0.f, 0.f, 0.f, 0.f}, acc01 = acc00, acc10 = acc00, acc11 = acc00;
#pragma unroll 4
    for (int k0 = 0; k0 < K; k0 += 32) {
        bf16x8 a0 = *(const bf16x8*)(A0 + k0);
        bf16x8 a1 = *(const bf16x8*)(A1 + k0);
        bf16x8 b0 = *(const bf16x8*)(B0 + k0);
        bf16x8 b1 = *(const bf16x8*)(B1 + k0);
        acc00 = __builtin_amdgcn_mfma_f32_16x16x32_bf16(a0, b0, acc00, 0, 0, 0);
        acc01 = __builtin_amdgcn_mfma_f32_16x16x32_bf16(a0, b1, acc01, 0, 0, 0);
        acc10 = __builtin_amdgcn_mfma_f32_16x16x32_bf16(a1, b0, acc10, 0, 0, 0);
        acc11 = __builtin_amdgcn_mfma_f32_16x16x32_bf16(a1, b1, acc11, 0, 0, 0);
    }
    int mb = bm + wm * 32, nb = bn + wn * 32;
#pragma unroll
    for (int j = 0; j < 4; ++j) {
        int m0 = mb + kg * 4 + j;
        int n0 = nb + r;
        if (n0 < nmax)      C[(size_t)m0 * ldc + n0] = acc00[j];
        if (n0 + 16 < nmax) C[(size_t)m0 * ldc + n0 + 16] = acc01[j];
        int m1 = m0 + 16;
        if (n0 < nmax)      C[(size_t)m1 * ldc + n0] = acc10[j];
        if (n0 + 16 < nmax) C[(size_t)m1 * ldc + n0 + 16] = acc11[j];
    }
}

// ---------------------------------------------------------------- front
// blocks 0..543:   zx (bf16 MFMA) — cols < 1026 (dt cols stay f32)
// blocks 544..575: h0 (bf16 MFMA) = in_query @ Wq^T (256x512x256)
// blocks 576..587: corners (8) + cpb table (4)
// blocks 588..651: zx dt cols 1026..1033 in f32 (exp-amplified path: full precision)
__global__ __launch_bounds__(256, 4) void front_k(
    const unsigned short* __restrict__ ikb, const unsigned short* __restrict__ wkb,
    const unsigned short* __restrict__ iqb, const unsigned short* __restrict__ wqb,
    const float* __restrict__ in_key, const float* __restrict__ Wkey,
    float* __restrict__ zx, float* __restrict__ h0b,
    const float* __restrict__ qxyz, const float* __restrict__ qsize,
    const float* __restrict__ qang, const float* __restrict__ w1,
    const float* __restrict__ b1, const float* __restrict__ w2,
    float* __restrict__ cb, float* __restrict__ tbl) {
    int bid = blockIdx.x, tid = threadIdx.x;
    if (bid < 544) {
        mfma_dev(ikb, wkb, zx, ZCOLS, 256, (bid & 31) * 64, (bid >> 5) * 64, 1026);
    } else if (bid < 576) {
        int rr = bid - 544;
        mfma_dev(iqb, wqb, h0b, 512, 256, (rr & 3) * 64, (rr >> 2) * 64, 512);
    } else if (bid < 584) {
        int idx = (bid - 576) * 256 + tid;    // < 2048 = B_*K_*8
        int b = idx >> 10;
        int q = idx & 1023;
        int k = q >> 3;
        int c = q & 7;
        const float sx[8] = {1, 1, -1, -1, 1, 1, -1, -1};
        const float sy[8] = {1, 1, 1, 1, -1, -1, -1, -1};
        const float sz[8] = {1, -1, -1, 1, 1, -1, -1, 1};
        float cx = qxyz[(b * K_ + k) * 3 + 0];
        float cy = qxyz[(b * K_ + k) * 3 + 1];
        float cz = qxyz[(b * K_ + k) * 3 + 2];
        float lv = qsize[(b * K_ + k) * 3 + 0];
        float wv2 = qsize[(b * K_ + k) * 3 + 1];
        float hv = qsize[(b * K_ + k) * 3 + 2];
        float ang = qang[b * K_ + k];
        float ca = cosf(ang), sa = sinf(ang);
        float ccx = cx, ccy = -cz, ccz = cy;
        float l0 = lv * sx[c] * 0.5f;
        float l1 = hv * sy[c] * 0.5f;
        float l2 = wv2 * sz[c] * 0.5f;
        float m0 = ca * l0 + sa * l2 + ccx;
        float m1 = l1 + ccy;
        float m2 = -sa * l0 + ca * l2 + ccz;
        // rotation for the distance transform uses angle[b, q % K] (jnp.tile semantics)
        float angr = qang[b * K_ + (q & (K_ - 1))];
        float4* o = (float4*)(cb + (size_t)idx * 8);
        o[0] = make_float4(m0, m2, -m1, cosf(angr));
        o[1] = make_float4(sinf(angr), 0.f, 0.f, 0.f);
    } else if (bid < 588) {
        int p = (bid - 584) * 256 + tid;
        if (p >= 1000) return;
        int i = p / 100, j = (p / 10) % 10, k = p % 10;
        float c0 = (8.f / 9.f) * i - 4.f;
        float c1 = (8.f / 9.f) * j - 4.f;
        float c2 = (8.f / 9.f) * k - 4.f;
        float a0 = 0.f, a1 = 0.f, a2 = 0.f, a3 = 0.f;
        for (int m = 0; m < 128; ++m) {
            float t = fmaf(c0, w1[m * 3 + 0], fmaf(c1, w1[m * 3 + 1], fmaf(c2, w1[m * 3 + 2], b1[m])));
            t = fmaxf(t, 0.f);
            a0 = fmaf(t, w2[m], a0);
            a1 = fmaf(t, w2[128 + m], a1);
            a2 = fmaf(t, w2[256 + m], a2);
            a3 = fmaf(t, w2[384 + m], a3);
        }
        tbl[p * 4 + 0] = a0; tbl[p * 4 + 1] = a1;
        tbl[p * 4 + 2] = a2; tbl[p * 4 + 3] = a3;
    } else {
        // f32 dt columns: zx[:,1026..1033] = in_key @ Wkey[1026..1033]^T
        int row = (bid - 588) * 32 + (tid >> 3);
        int colh = tid & 7;
        const float* arow = in_key + (size_t)row * 256;
        const float* wrow = Wkey + (size_t)(1026 + colh) * 256;
        float acc = 0.f;
#pragma unroll 8
        for (int k = 0; k < 256; k += 4) {
            float4 a = *(const float4*)(arow + k);
            float4 wv2 = *(const float4*)(wrow + k);
            acc = fmaf(a.x, wv2.x, fmaf(a.y, wv2.y, fmaf(a.z, wv2.z, fmaf(a.w, wv2.w, acc))));
        }
        zx[(size_t)row * ZCOLS + 1026 + colh] = acc;
    }
}

// ---------------------------------------------------------------- depthwise conv7 + silu (2 rows/block)
__global__ void dwconv_silu(const float* __restrict__ xin, int in_stride, int in_off,
                            const float* __restrict__ w, const float* __restrict__ bias,
                            float* __restrict__ out) {
    int c = blockIdx.y * blockDim.x + threadIdx.x;
    if (c >= CC) return;
    int row0 = blockIdx.x * 2;            // b*L + l, l even
    int l0 = row0 & (L_ - 1);
    const float* xr = xin + (size_t)row0 * in_stride + in_off + c;
    float Lv[8];
#pragma unroll
    for (int i = 0; i < 8; ++i) {
        int ll = l0 + i - 3;
        Lv[i] = (ll >= 0 && ll < L_) ? xr[(ptrdiff_t)(i - 3) * in_stride] : 0.f;
    }
    float acc0 = bias[c], acc1 = bias[c];
#pragma unroll
    for (int j = 0; j < 7; ++j) {
        float wj = w[c * 7 + j];
        acc0 = fmaf(Lv[j], wj, acc0);
        acc1 = fmaf(Lv[j + 1], wj, acc1);
    }
    out[(size_t)row0 * CC + c] = silu_f(acc0);
    out[(size_t)(row0 + 1) * CC + c] = silu_f(acc1);
}

// ---------------------------------------------------------------- fused dist + dA/dB/C
__global__ __launch_bounds__(128) void geo_k(
    const float* __restrict__ kxyz, const float* __restrict__ cb,
    const float* __restrict__ tbl, const float* __restrict__ zx,
    const float* __restrict__ xf, const float* __restrict__ xb,
    const float* __restrict__ wbc, const float* __restrict__ wdt,
    const float* __restrict__ dtb, const float* __restrict__ alog,
    float* __restrict__ dA, float* __restrict__ dBf, float* __restrict__ dBb,
    float* __restrict__ Cf, float* __restrict__ Cb) {
    __shared__ float t_s[4000];
    int row = blockIdx.x;                 // b*L + l
    int b = row >> 10;
    int l = row & 1023;
    int k = threadIdx.x;
    for (int i = threadIdx.x; i < 4000; i += 128) t_s[i] = tbl[i];
    __syncthreads();
    float kx = kxyz[(size_t)row * 3 + 0];
    float ky = kxyz[(size_t)row * 3 + 1];
    float kz = kxyz[(size_t)row * 3 + 2];
    float acc0 = 0.f, acc1 = 0.f, acc2 = 0.f, acc3 = 0.f;
#pragma unroll
    for (int c = 0; c < 8; ++c) {
        int q = k * 8 + c;
        const float4* p = (const float4*)(cb + (size_t)(b * 1024 + q) * 8);
        float4 v0 = p[0], v1 = p[1];
        float d0 = v0.x - kx, d1 = v0.y - ky, d2 = v0.z - kz;
        float rc = v0.w, rs = v1.x;
        float e0 = d0, e1 = -d2, e2 = d1;
        float f0 = rc * e0 - rs * e2;
        float f1 = e1;
        float f2 = rs * e0 + rc * e2;
        float g0 = f0, g1 = f2, g2 = -f1;
        g0 = copysignf(log2f(fabsf(g0) * 512.f + 1.f) * (1.f / 12.f), g0);
        g1 = copysignf(log2f(fabsf(g1) * 512.f + 1.f) * (1.f / 12.f), g1);
        g2 = copysignf(log2f(fabsf(g2) * 512.f + 1.f) * (1.f / 12.f), g2);
        // table axis0 <- g2, axis1 <- g1, axis2 <- g0
        float iq = 5.f * g2 + 4.5f;
        float jq = 5.f * g1 + 4.5f;
        float kq = 5.f * g0 + 4.5f;
        float i0f = floorf(iq), j0f = floorf(jq), k0f = floorf(kq);
        float wi = iq - i0f, wj = jq - j0f, wk = kq - k0f;
        int i0 = (int)i0f, j0 = (int)j0f, k0 = (int)k0f;
#pragma unroll
        for (int a = 0; a < 2; ++a) {
#pragma unroll
            for (int bb = 0; bb < 2; ++bb) {
#pragma unroll
                for (int cc = 0; cc < 2; ++cc) {
                    int ii = i0 + a, jj = j0 + bb, kk = k0 + cc;
                    if ((unsigned)ii < 10u && (unsigned)jj < 10u && (unsigned)kk < 10u) {
                        float wgt = (a ? wi : 1.f - wi) * (bb ? wj : 1.f - wj) * (cc ? wk : 1.f - wk);
                        const float* tp = &t_s[((ii * 10 + jj) * 10 + kk) * 4];
                        acc0 = fmaf(wgt, tp[0], acc0);
                        acc1 = fmaf(wgt, tp[1], acc1);
                        acc2 = fmaf(wgt, tp[2], acc2);
                        acc3 = fmaf(wgt, tp[3], acc3);
                    }
                }
            }
        }
    }
    // ---- fused precomp tail
    float B0 = acc0 * wbc[0] + acc1 * wbc[1] + acc2 * wbc[2] + acc3 * wbc[3];
    float C0 = acc0 * wbc[4] + acc1 * wbc[5] + acc2 * wbc[6] + acc3 * wbc[7];
    float bbf = xf[(size_t)row * CC + 512], cbf = xf[(size_t)row * CC + 513];
    float bbb = xb[(size_t)row * CC + 512], cbb = xb[(size_t)row * CC + 513];
    Cf[(size_t)row * K_ + k] = C0 + cbf;
    Cb[(size_t)row * K_ + k] = C0 + cbb;
    float Bf = B0 + bbf, Bb = B0 + bbb;
#pragma unroll
    for (int hh = 0; hh < NH; ++hh) {
        float s = acc0 * wdt[hh * 4 + 0] + acc1 * wdt[hh * 4 + 1] +
                  acc2 * wdt[hh * 4 + 2] + acc3 * wdt[hh * 4 + 3];
        s += zx[(size_t)row * ZCOLS + 1026 + hh] + dtb[hh];
        float dtv = (s > 20.f) ? s : log1pf(expf(s));
        float Av = -expf(alog[hh]);
        size_t o = ((size_t)(b * NH + hh) * L_ + l) * K_ + k;
        dA[o] = expf(dtv * Av);
        dBf[o] = dtv * Bf;
        dBb[o] = dtv * Bb;
    }
}

// ---------------------------------------------------------------- chunked ISSM scan, LDS-fed
__global__ __launch_bounds__(256) void scan_part6(
    const float* __restrict__ dA, const float* __restrict__ dBf, const float* __restrict__ dBb,
    const float* __restrict__ Cf, const float* __restrict__ Cb,
    const float* __restrict__ xf, const float* __restrict__ xb,
    float* __restrict__ Sbuf, float* __restrict__ Pbuf,
    float* __restrict__ yf, float* __restrict__ yb) {
    __shared__ float lds[2][3584];
    int bid = blockIdx.x;
    int c = bid & 15;
    int hh = (bid >> 4) & 7;
    int b = (bid >> 7) & 1;
    int dir = bid >> 8;
    int tid = threadIdx.x;             // 0..255
    int lane = tid & 63;
    int w = tid >> 6;                  // 0..3
    int dg = lane >> 4, kg = lane & 15;
    int dloc = w * 4 + dg;             // 0..15; lane owns d = dloc + 16*{0,1,2,3}
    int klo = kg * 4, khi = 64 + kg * 4;

    const float* Bsrc = dir ? dBb : dBf;
    const float* Csrc = dir ? Cb : Cf;
    const float* Xsrc = dir ? xb : xf;
    float* Ydst = dir ? yb : yf;
    int t0 = dir ? (L_ - 1 - c * TC) : c * TC;
    int stp = dir ? -1 : 1;

    const float* Abase = dA + ((size_t)(b * NH + hh) * L_) * K_;
    const float* Bbase = Bsrc + ((size_t)(b * NH + hh) * L_) * K_;
    const float* Cbase = Csrc + ((size_t)b * L_) * K_;
    const float* Xbase = Xsrc + ((size_t)b * L_) * CC + hh * HD;

    const bool hasx = (tid < 128);

    auto gaddr = [&](int v, int tb) -> const float* {
        if (v < 768) {
            int r = (v >> 5) & 7;
            int c4 = v & 31;
            int l = t0 + stp * (tb + r);
            const float* base = (v < 256) ? Abase : ((v < 512) ? Bbase : Cbase);
            return base + (size_t)l * K_ + c4 * 4;
        } else {
            int vv = v - 768;
            int r = vv >> 4, c4 = vv & 15;
            int l = t0 + stp * (tb + r);
            return Xbase + (size_t)l * CC + c4 * 4;
        }
    };

    float hA[8] = {0, 0, 0, 0, 0, 0, 0, 0};
    float hB[8] = {0, 0, 0, 0, 0, 0, 0, 0};
    float hC[8] = {0, 0, 0, 0, 0, 0, 0, 0};
    float hD[8] = {0, 0, 0, 0, 0, 0, 0, 0};
    float cum[8] = {1, 1, 1, 1, 1, 1, 1, 1};

    // prologue: stage tile 0 into buf 0
    float4 rA = *(const float4*)gaddr(tid, 0);
    float4 rB = *(const float4*)gaddr(256 + tid, 0);
    float4 rC = *(const float4*)gaddr(512 + tid, 0);
    float4 rX = hasx ? *(const float4*)gaddr(768 + tid, 0) : make_float4(0, 0, 0, 0);
    *(float4*)&lds[0][4 * tid] = rA;
    *(float4*)&lds[0][1024 + 4 * tid] = rB;
    *(float4*)&lds[0][2048 + 4 * tid] = rC;
    if (hasx) *(float4*)&lds[0][3072 + 4 * tid] = rX;
    __syncthreads();

    float* pY = Ydst + ((size_t)(b * L_ + t0)) * DI + hh * HD + dloc;
    const ptrdiff_t dY = (ptrdiff_t)stp * DI;

    for (int it = 0; it < TC / 8; ++it) {
        int tb = it * 8;
        if (it < TC / 8 - 1) {           // issue next tile's global loads early
            rA = *(const float4*)gaddr(tid, tb + 8);
            rB = *(const float4*)gaddr(256 + tid, tb + 8);
            rC = *(const float4*)gaddr(512 + tid, tb + 8);
            if (hasx) rX = *(const float4*)gaddr(768 + tid, tb + 8);
        }
        const float* Lb = lds[it & 1];
        // tile prologue: st=0 full operands + st=1 a/b
        float4 aC0 = *(const float4*)&Lb[klo];
        float4 aC1 = *(const float4*)&Lb[khi];
        float4 bC0 = *(const float4*)&Lb[1024 + klo];
        float4 bC1 = *(const float4*)&Lb[1024 + khi];
        float4 cC0 = *(const float4*)&Lb[2048 + klo];
        float4 cC1 = *(const float4*)&Lb[2048 + khi];
        float x0 = Lb[3072 + dloc];
        float x1 = Lb[3072 + 16 + dloc];
        float x2 = Lb[3072 + 32 + dloc];
        float x3 = Lb[3072 + 48 + dloc];
        float4 aN0 = *(const float4*)&Lb[128 + klo];
        float4 aN1 = *(const float4*)&Lb[128 + khi];
        float4 bN0 = *(const float4*)&Lb[1024 + 128 + klo];
        float4 bN1 = *(const float4*)&Lb[1024 + 128 + khi];
#pragma unroll
        for (int st = 0; st < 8; ++st) {
            float4 aF0, aF1, bF0, bF1, cN0, cN1;
            float nx0 = 0.f, nx1 = 0.f, nx2 = 0.f, nx3 = 0.f;
            if (st < 6) {                // a/b for st+2 (h-critical, deepest lookahead)
                int o = (st + 2) * 128;
                aF0 = *(const float4*)&Lb[o + klo];
                aF1 = *(const float4*)&Lb[o + khi];
                bF0 = *(const float4*)&Lb[1024 + o + klo];
                bF1 = *(const float4*)&Lb[1024 + o + khi];
            }
            if (st < 7) {                // c/x for st+1
                int o = (st + 1) * 128;
                cN0 = *(const float4*)&Lb[2048 + o + klo];
                cN1 = *(const float4*)&Lb[2048 + o + khi];
                int xo = 3072 + (st + 1) * 64 + dloc;
                nx0 = Lb[xo]; nx1 = Lb[xo + 16]; nx2 = Lb[xo + 32]; nx3 = Lb[xo + 48];
            }
            cum[0] *= aC0.x; cum[1] *= aC0.y; cum[2] *= aC0.z; cum[3] *= aC0.w;
            cum[4] *= aC1.x; cum[5] *= aC1.y; cum[6] *= aC1.z; cum[7] *= aC1.w;
            float u0, u1, u2, u3;
            // d-block A (x0)
            hA[0] = fmaf(hA[0], aC0.x, x0 * bC0.x); u0 = hA[0] * cC0.x;
            hA[1] = fmaf(hA[1], aC0.y, x0 * bC0.y); u1 = hA[1] * cC0.y;
            hA[2] = fmaf(hA[2], aC0.z, x0 * bC0.z); u2 = hA[2] * cC0.z;
            hA[3] = fmaf(hA[3], aC0.w, x0 * bC0.w); u3 = hA[3] * cC0.w;
            hA[4] = fmaf(hA[4], aC1.x, x0 * bC1.x); u0 = fmaf(hA[4], cC1.x, u0);
            hA[5] = fmaf(hA[5], aC1.y, x0 * bC1.y); u1 = fmaf(hA[5], cC1.y, u1);
            hA[6] = fmaf(hA[6], aC1.z, x0 * bC1.z); u2 = fmaf(hA[6], cC1.z, u2);
            hA[7] = fmaf(hA[7], aC1.w, x0 * bC1.w); u3 = fmaf(hA[7], cC1.w, u3);
            float rrA = dpp_row_reduce16((u0 + u1) + (u2 + u3));
            // d-block B (x1)
            hB[0] = fmaf(hB[0], aC0.x, x1 * bC0.x); u0 = hB[0] * cC0.x;
            hB[1] = fmaf(hB[1], aC0.y, x1 * bC0.y); u1 = hB[1] * cC0.y;
            hB[2] = fmaf(hB[2], aC0.z, x1 * bC0.z); u2 = hB[2] * cC0.z;
            hB[3] = fmaf(hB[3], aC0.w, x1 * bC0.w); u3 = hB[3] * cC0.w;
            hB[4] = fmaf(hB[4], aC1.x, x1 * bC1.x); u0 = fmaf(hB[4], cC1.x, u0);
            hB[5] = fmaf(hB[5], aC1.y, x1 * bC1.y); u1 = fmaf(hB[5], cC1.y, u1);
            hB[6] = fmaf(hB[6], aC1.z, x1 * bC1.z); u2 = fmaf(hB[6], cC1.z, u2);
            hB[7] = fmaf(hB[7], aC1.w, x1 * bC1.w); u3 = fmaf(hB[7], cC1.w, u3);
            float rrB = dpp_row_reduce16((u0 + u1) + (u2 + u3));
            // d-block C (x2)
            hC[0] = fmaf(hC[0], aC0.x, x2 * bC0.x); u0 = hC[0] * cC0.x;
            hC[1] = fmaf(hC[1], aC0.y, x2 * bC0.y); u1 = hC[1] * cC0.y;
            hC[2] = fmaf(hC[2], aC0.z, x2 * bC0.z); u2 = hC[2] * cC0.z;
            hC[3] = fmaf(hC[3], aC0.w, x2 * bC0.w); u3 = hC[3] * cC0.w;
            hC[4] = fmaf(hC[4], aC1.x, x2 * bC1.x); u0 = fmaf(hC[4], cC1.x, u0);
            hC[5] = fmaf(hC[5], aC1.y, x2 * bC1.y); u1 = fmaf(hC[5], cC1.y, u1);
            hC[6] = fmaf(hC[6], aC1.z, x2 * bC1.z); u2 = fmaf(hC[6], cC1.z, u2);
            hC[7] = fmaf(hC[7], aC1.w, x2 * bC1.w); u3 = fmaf(hC[7], cC1.w, u3);
            float rrC = dpp_row_reduce16((u0 + u1) + (u2 + u3));
            // d-block D (x3)
            hD[0] = fmaf(hD[0], aC0.x, x3 * bC0.x); u0 = hD[0] * cC0.x;
            hD[1] = fmaf(hD[1], aC0.y, x3 * bC0.y); u1 = hD[1] * cC0.y;
            hD[2] = fmaf(hD[2], aC0.z, x3 * bC0.z); u2 = hD[2] * cC0.z;
            hD[3] = fmaf(hD[3], aC0.w, x3 * bC0.w); u3 = hD[3] * cC0.w;
            hD[4] = fmaf(hD[4], aC1.x, x3 * bC1.x); u0 = fmaf(hD[4], cC1.x, u0);
            hD[5] = fmaf(hD[5], aC1.y, x3 * bC1.y); u1 = fmaf(hD[5], cC1.y, u1);
            hD[6] = fmaf(hD[6], aC1.z, x3 * bC1.z); u2 = fmaf(hD[6], cC1.z, u2);
            hD[7] = fmaf(hD[7], aC1.w, x3 * bC1.w); u3 = fmaf(hD[7], cC1.w, u3);
            float rrD = dpp_row_reduce16((u0 + u1) + (u2 + u3));
            if (kg == 0) { pY[0] = rrA; pY[16] = rrB; pY[32] = rrC; pY[48] = rrD; }
            pY += dY;
            if (st < 7) {                // rotate generations
                aC0 = aN0; aC1 = aN1; bC0 = bN0; bC1 = bN1;
                cC0 = cN0; cC1 = cN1;
                x0 = nx0; x1 = nx1; x2 = nx2; x3 = nx3;
                if (st < 6) { aN0 = aF0; aN1 = aF1; bN0 = bF0; bN1 = bF1; }
            }
        }
        if (it < TC / 8 - 1) {           // write OTHER buffer; safe before barrier
            *(float4*)&lds[(it + 1) & 1][4 * tid] = rA;
            *(float4*)&lds[(it + 1) & 1][1024 + 4 * tid] = rB;
            *(float4*)&lds[(it + 1) & 1][2048 + 4 * tid] = rC;
            if (hasx) *(float4*)&lds[(it + 1) & 1][3072 + 4 * tid] = rX;
        }
        __syncthreads();                 // single barrier per tile
    }

    int ibh = (dir * B_ + b) * NH + hh;
    {
        float* Sp = Sbuf + (((size_t)ibh * NC + c) * HD + dloc) * K_;
        *(float4*)(Sp + klo) = make_float4(hA[0], hA[1], hA[2], hA[3]);
        *(float4*)(Sp + khi) = make_float4(hA[4], hA[5], hA[6], hA[7]);
        Sp += (size_t)16 * K_;
        *(float4*)(Sp + klo) = make_float4(hB[0], hB[1], hB[2], hB[3]);
        *(float4*)(Sp + khi) = make_float4(hB[4], hB[5], hB[6], hB[7]);
        Sp += (size_t)16 * K_;
        *(float4*)(Sp + klo) = make_float4(hC[0], hC[1], hC[2], hC[3]);
        *(float4*)(Sp + khi) = make_float4(hC[4], hC[5], hC[6], hC[7]);
        Sp += (size_t)16 * K_;
        *(float4*)(Sp + klo) = make_float4(hD[0], hD[1], hD[2], hD[3]);
        *(float4*)(Sp + khi) = make_float4(hD[4], hD[5], hD[6], hD[7]);
    }
    if (dir == 0 && tid < 16) {          // w==0, dg==0, kg==tid: cum identical across d
        float* Pp = Pbuf + ((size_t)((b * NH + hh) * NC + c)) * K_;
        *(float4*)(Pp + klo) = make_float4(cum[0], cum[1], cum[2], cum[3]);
        *(float4*)(Pp + khi) = make_float4(cum[4], cum[5], cum[6], cum[7]);
    }
}

// phase 2: sequential combine across NC chunks
__global__ __launch_bounds__(256) void scan_combine(
    const float* __restrict__ h0buf, float* __restrict__ Sbuf,
    const float* __restrict__ Pbuf, float* __restrict__ hfin) {
    int bid = blockIdx.x;
    int dq = bid & 3;
    int hh = (bid >> 2) & 7;
    int b = (bid >> 5) & 1;
    int dir = bid >> 6;
    int tid = threadIdx.x;
    int w = tid >> 6;
    int lane = tid & 63;
    int dsl = dq * 4 + w;
    int dg = lane >> 4, kg = lane & 15;
    int d = dsl * 4 + dg;
    int k0 = kg * 8;

    float H[8];
#pragma unroll
    for (int j = 0; j < 8; ++j)
        H[j] = h0buf[(size_t)(b * K_ + k0 + j) * DI + hh * HD + d];

    int ibh = (dir * B_ + b) * NH + hh;
    for (int c = 0; c < NC; ++c) {
        float* Sp = Sbuf + (((size_t)ibh * NC + c) * HD + d) * K_ + k0;
        int cF = dir ? (NC - 1 - c) : c;   // P computed on fwd chunk row-sets
        const float* Pp = Pbuf + ((size_t)((b * NH + hh) * NC + cF)) * K_ + k0;
        float4 sA = *(const float4*)(Sp + 0);
        float4 sB = *(const float4*)(Sp + 4);
        float4 pA = *(const float4*)(Pp + 0);
        float4 pB = *(const float4*)(Pp + 4);
        // store incoming state for this chunk (overwrites S)
        *(float4*)(Sp + 0) = make_float4(H[0], H[1], H[2], H[3]);
        *(float4*)(Sp + 4) = make_float4(H[4], H[5], H[6], H[7]);
        H[0] = fmaf(H[0], pA.x, sA.x); H[1] = fmaf(H[1], pA.y, sA.y);
        H[2] = fmaf(H[2], pA.z, sA.z); H[3] = fmaf(H[3], pA.w, sA.w);
        H[4] = fmaf(H[4], pB.x, sB.x); H[5] = fmaf(H[5], pB.y, sB.y);
        H[6] = fmaf(H[6], pB.z, sB.z); H[7] = fmaf(H[7], pB.w, sB.w);
    }
    float* hf = hfin + ((((size_t)dir * B_ + b) * NH + hh) * HD + d) * K_ + k0;
    *(float4*)(hf + 0) = make_float4(H[0], H[1], H[2], H[3]);
    *(float4*)(hf + 4) = make_float4(H[4], H[5], H[6], H[7]);
}

// phase 3: y[t,d] += sum_k C[t,k]*cumA[t,k] * Hin[k,d]
#define CP 72
#define WSWZ(k) ((((k) >> 3) & 3) << 2)
__global__ __launch_bounds__(256) void scan_corr(
    const float* __restrict__ dA, const float* __restrict__ Cf, const float* __restrict__ Cb,
    const float* __restrict__ Sbuf, float* __restrict__ yf, float* __restrict__ yb) {
    __shared__ float Wl[128][CP];   // [k][t] (t XOR-swizzled by WSWZ(k))
    __shared__ float Hl[128][CP];   // [k][d]
    int iid = blockIdx.x;
    int c = iid & 15;
    int hh = (iid >> 4) & 7;
    int b = (iid >> 7) & 1;
    int dir = iid >> 8;
    int tid = threadIdx.x;
    const float* Csrc = dir ? Cb : Cf;

    // phase A: W[k][t] = C[l(t),k] * cumA(t,k), scan order
    if (tid < 128) {
        int k = tid;
        float cum = 1.f;
        const float* pA = dA + ((size_t)(b * NH + hh) * L_) * K_ + k;
        const float* pC = Csrc + ((size_t)b * L_) * K_ + k;
        int sw = WSWZ(k);
#pragma unroll 4
        for (int t = 0; t < TC; ++t) {
            int l = dir ? (L_ - 1 - (c * TC + t)) : (c * TC + t);
            cum *= pA[(size_t)l * K_];
            Wl[k][t ^ sw] = cum * pC[(size_t)l * K_];
        }
    }
    // phase B: Hin [k][d] (transposed stage from Sbuf [d][k])
    {
        int d = tid & 63, kq = tid >> 6;   // kq 0..3
        int ibh = (dir * B_ + b) * NH + hh;
        const float* Hp = Sbuf + (((size_t)ibh * NC + c) * HD + d) * K_;
#pragma unroll
        for (int i = 0; i < 8; ++i) {
            int q = kq * 8 + i;            // float4 index 0..31
            float4 v = *(const float4*)(Hp + q * 4);
            Hl[q * 4 + 0][d] = v.x; Hl[q * 4 + 1][d] = v.y;
            Hl[q * 4 + 2][d] = v.z; Hl[q * 4 + 3][d] = v.w;
        }
    }
    __syncthreads();
    // phase C: GEMM 64t x 64d x 128k
    int a = tid >> 4;            // t-quad 0..15
    int bc = tid & 15;           // d-quad 0..15
    int t0v = a * 4, d0v = bc * 4;
    float acc[4][4] = {};
    for (int k = 0; k < 128; ++k) {
        float4 w4 = *(const float4*)&Wl[k][t0v ^ WSWZ(k)];
        float4 h4 = *(const float4*)&Hl[k][d0v];
        acc[0][0] = fmaf(w4.x, h4.x, acc[0][0]); acc[0][1] = fmaf(w4.x, h4.y, acc[0][1]);
        acc[0][2] = fmaf(w4.x, h4.z, acc[0][2]); acc[0][3] = fmaf(w4.x, h4.w, acc[0][3]);
        acc[1][0] = fmaf(w4.y, h4.x, acc[1][0]); acc[1][1] = fmaf(w4.y, h4.y, acc[1][1]);
        acc[1][2] = fmaf(w4.y, h4.z, acc[1][2]); acc[1][3] = fmaf(w4.y, h4.w, acc[1][3]);
        acc[2][0] = fmaf(w4.z, h4.x, acc[2][0]); acc[2][1] = fmaf(w4.z, h4.y, acc[2][1]);
        acc[2][2] = fmaf(w4.z, h4.z, acc[2][2]); acc[2][3] = fmaf(w4.z, h4.w, acc[2][3]);
        acc[3][0] = fmaf(w4.w, h4.x, acc[3][0]); acc[3][1] = fmaf(w4.w, h4.y, acc[3][1]);
        acc[3][2] = fmaf(w4.w, h4.z, acc[3][2]); acc[3][3] = fmaf(w4.w, h4.w, acc[3][3]);
    }
    float* Ydst = dir ? yb : yf;
#pragma unroll
    for (int i = 0; i < 4; ++i) {
        int t = t0v + i;
        int l = dir ? (L_ - 1 - (c * TC + t)) : (c * TC + t);
        float* yp = Ydst + ((size_t)(b * L_ + l)) * DI + hh * HD + d0v;
        float4 old = *(float4*)yp;
        old.x += acc[i][0]; old.y += acc[i][1];
        old.z += acc[i][2]; old.w += acc[i][3];
        *(float4*)yp = old;
    }
}

// ---------------------------------------------------------------- gate + RMSNorm (bf16 out)
__global__ __launch_bounds__(256) void gated_k(
    const float* __restrict__ yf, const float* __restrict__ yb,
    const float* __restrict__ xf, const float* __restrict__ zx,
    const float* __restrict__ Dp, const float* __restrict__ knw,
    unsigned short* __restrict__ gatedb) {
    __shared__ float sb[4];
    int row = blockIdx.x;
    int tid = threadIdx.x;
    float g[2];
    float ss = 0.f;
#pragma unroll
    for (int u = 0; u < 2; ++u) {
        int c = tid + u * 256;
        float yv = yf[(size_t)row * DI + c] + yb[(size_t)row * DI + c] +
                   Dp[c >> 6] * xf[(size_t)row * CC + c];
        float z = zx[(size_t)row * ZCOLS + c];
        float gv = yv * silu_f(z);
        g[u] = gv;
        ss = fmaf(gv, gv, ss);
    }
    float wsum = wave_sum(ss);
    if ((tid & 63) == 0) sb[tid >> 6] = wsum;
    __syncthreads();
    float tot = sb[0] + sb[1] + sb[2] + sb[3];
    float rms = rsqrtf(tot * (1.f / 512.f) + 1e-5f);
#pragma unroll
    for (int u = 0; u < 2; ++u) {
        int c = tid + u * 256;
        gatedb[(size_t)row * DI + c] = f2bf(g[u] * rms * knw[c]);
    }
}

// ---------------------------------------------------------------- final: bf16 MFMA out GEMM + query path
// blocks 0..127: out = gated @ Wok^T (2048x256x512, bf16 MFMA)
// blocks 128..383: query LN + GEMM (bk = bid-128)
__global__ __launch_bounds__(256) void final_k(
    const unsigned short* __restrict__ gatedb, const unsigned short* __restrict__ wokb,
    float* __restrict__ out,
    const float* __restrict__ hfin, const float* __restrict__ lnw,
    const float* __restrict__ lnb, const float* __restrict__ woq,
    float* __restrict__ outq) {
    int bid = blockIdx.x, tid = threadIdx.x;
    if (bid < 128) {
        mfma_dev(gatedb, wokb, out, 256, 512, (bid & 31) * 64, (bid >> 5) * 64, 256);
        return;
    }
    __shared__ float sln[512];
    __shared__ float sb1[4];
    __shared__ float sb2[4];
    int bk = bid - 128;                   // b*K_ + k
    int b = bk >> 7;
    int k = bk & 127;
    float st[2];
    float ssum = 0.f;
#pragma unroll
    for (int u = 0; u < 2; ++u) {
        int c = tid + u * 256;
        int hh = c >> 6, d = c & 63;
        size_t o0 = (((size_t)(0 * B_ + b) * NH + hh) * HD + d) * K_ + k;
        size_t o1 = (((size_t)(1 * B_ + b) * NH + hh) * HD + d) * K_ + k;
        st[u] = 0.5f * (hfin[o0] + hfin[o1]);
        ssum += st[u];
    }
    float wsum = wave_sum(ssum);
    if ((tid & 63) == 0) sb1[tid >> 6] = wsum;
    __syncthreads();
    float mu = (sb1[0] + sb1[1] + sb1[2] + sb1[3]) * (1.f / 512.f);
    float vs = 0.f;
#pragma unroll
    for (int u = 0; u < 2; ++u) {
        float t = st[u] - mu;
        vs = fmaf(t, t, vs);
    }
    float wv = wave_sum(vs);
    if ((tid & 63) == 0) sb2[tid >> 6] = wv;
    __syncthreads();
    float var = (sb2[0] + sb2[1] + sb2[2] + sb2[3]) * (1.f / 512.f);
    float inv = rsqrtf(var + 1e-5f);
#pragma unroll
    for (int u = 0; u < 2; ++u) {
        int c = tid + u * 256;
        sln[c] = (st[u] - mu) * inv * lnw[c] + lnb[c];
    }
    __syncthreads();
    const float4* w4 = (const float4*)(woq + (size_t)tid * 512);
    float acc = 0.f;
#pragma unroll 4
    for (int i = 0; i < 128; ++i) {
        float4 wvv = w4[i];
        float4 sv = *(const float4*)&sln[i * 4];
        acc = fmaf(wvv.x, sv.x, acc);
        acc = fmaf(wvv.y, sv.y, acc);
        acc = fmaf(wvv.z, sv.z, acc);
        acc = fmaf(wvv.w, sv.w, acc);
    }
    outq[(size_t)bk * 256 + tid] = acc;
}

// ---------------------------------------------------------------- launcher
extern "C" void kernel_launch(void* const* d_in, const int* in_sizes, int n_in,
                              void* d_out, int out_size, void* d_ws, size_t ws_size,
                              hipStream_t stream) {
    const float* in_key      = (const float*)d_in[0];
    const float* in_query    = (const float*)d_in[1];
    const float* key_xyz     = (const float*)d_in[2];
    const float* query_xyz   = (const float*)d_in[3];
    const float* query_size  = (const float*)d_in[4];
    const float* query_angle = (const float*)d_in[5];
    const float* Wkey        = (const float*)d_in[6];
    const float* conv_w      = (const float*)d_in[7];
    const float* conv_b      = (const float*)d_in[8];
    const float* convb_w     = (const float*)d_in[9];
    const float* convb_b     = (const float*)d_in[10];
    const float* Wq          = (const float*)d_in[11];
    const float* Wbc         = (const float*)d_in[12];
    const float* Wdt         = (const float*)d_in[13];
    const float* dt_bias     = (const float*)d_in[14];
    const float* A_log       = (const float*)d_in[15];
    const float* Dp          = (const float*)d_in[16];
    const float* Wok         = (const float*)d_in[17];
    const float* Woq         = (const float*)d_in[18];
    const float* key_norm_w  = (const float*)d_in[19];
    const float* ln_w        = (const float*)d_in[20];
    const float* ln_b        = (const float*)d_in[21];
    const float* cpb_w1      = (const float*)d_in[22];
    const float* cpb_b1      = (const float*)d_in[23];
    const float* cpb_w2      = (const float*)d_in[24];
    float* out = (float*)d_out;

    float* wsf = (float*)d_ws;
    float* zx    = wsf + 0;         // 2048*1034
    float* xf    = wsf + 2117632;   // 2048*514
    float* xb    = wsf + 3170304;   // 2048*514
    float* tbl   = wsf + 4222976;   // 4000
    float* cbuf  = wsf + 4226976;   // 2*1024*8
    float* Pbuf  = wsf + 4243360;   // 2*8*16*128
    float* dAa   = wsf + 5291936;   // 2*8*1024*128
    float* dBf   = wsf + 7389088;
    float* dBb   = wsf + 9486240;
    float* Cfb   = wsf + 11583392;  // 2*1024*128
    float* Cbb   = wsf + 11845536;
    float* h0b   = wsf + 12107680;  // 256*512
    float* yfb   = wsf + 12238752;  // 2048*512
    float* ybb   = wsf + 13287328;
    float* hfin  = wsf + 14335904;  // 2*2*8*64*128
    float* Sbuf  = wsf + 15646624;  // 4,194,304 floats
    unsigned short* ikb    = (unsigned short*)(wsf + 19840928);  // 2048*256
    unsigned short* wkb    = (unsigned short*)(wsf + 20103072);  // 1088*256 (pad)
    unsigned short* iqb    = (unsigned short*)(wsf + 20242336);  // 256*256
    unsigned short* wqb    = (unsigned short*)(wsf + 20275104);  // 512*256
    unsigned short* wokb   = (unsigned short*)(wsf + 20340640);  // 256*512
    unsigned short* gatedb = (unsigned short*)(wsf + 20406176);  // 2048*512

    cvt_k<<<1104, 256, 0, stream>>>(in_key, Wkey, in_query, Wq, Wok,
                                    ikb, wkb, iqb, wqb, wokb);
    front_k<<<652, 256, 0, stream>>>(ikb, wkb, iqb, wqb, in_key, Wkey, zx, h0b,
                                     query_xyz, query_size, query_angle,
                                     cpb_w1, cpb_b1, cpb_w2, cbuf, tbl);
    dwconv_silu<<<dim3(1024, 3), 256, 0, stream>>>(zx, ZCOLS, 512, conv_w, conv_b, xf);
    dwconv_silu<<<dim3(1024, 3), 256, 0, stream>>>(xf, CC, 0, convb_w, convb_b, xb);
    geo_k<<<2048, 128, 0, stream>>>(key_xyz, cbuf, tbl, zx, xf, xb,
                                    Wbc, Wdt, dt_bias, A_log,
                                    dAa, dBf, dBb, Cfb, Cbb);
    scan_part6<<<512, 256, 0, stream>>>(dAa, dBf, dBb, Cfb, Cbb, xf, xb,
                                        Sbuf, Pbuf, yfb, ybb);
    scan_combine<<<128, 256, 0, stream>>>(h0b, Sbuf, Pbuf, hfin);
    scan_corr<<<512, 256, 0, stream>>>(dAa, Cfb, Cbb, Sbuf, yfb, ybb);
    gated_k<<<2048, 256, 0, stream>>>(yfb, ybb, xf, zx, Dp, key_norm_w, gatedb);
    final_k<<<384, 256, 0, stream>>>(gatedb, wokb, out, hfin, ln_w, ln_b, Woq,
                                     out + 524288);
}